// Round 10
// baseline (12481.597 us; speedup 1.0000x reference)
//
#include <hip/hip_runtime.h>
#include <math.h>

#define BB 1024
#define NN 150
#define RTOT (BB*NN)
#define EE 128
#define FFD 512
#define NL 3

typedef unsigned short u16;
typedef unsigned int u32;
typedef _Float16 f16;
typedef _Float16 f16x4 __attribute__((ext_vector_type(4)));

__device__ __forceinline__ float fsig(float x){ return __builtin_amdgcn_rcpf(1.0f + __expf(-x)); }
__device__ __forceinline__ float ftanh(float x){ return 1.0f - 2.0f*__builtin_amdgcn_rcpf(1.0f + __expf(2.0f*x)); }

// ---- h storage accessors ----
__device__ __forceinline__ float4 h_load4(const float* p){ return *(const float4*)p; }
__device__ __forceinline__ float4 h_load4(const f16* p){
    f16x4 v = *(const f16x4*)p;
    return make_float4((float)v.x,(float)v.y,(float)v.z,(float)v.w);
}
__device__ __forceinline__ void h_store4(float* p, float4 v){ *(float4*)p = v; }
__device__ __forceinline__ void h_store4(f16* p, float4 v){
    f16x4 o; o.x=(f16)v.x; o.y=(f16)v.y; o.z=(f16)v.z; o.w=(f16)v.w;
    *(f16x4*)p = o;
}
__device__ __forceinline__ float h_load(const float* p){ return *p; }
__device__ __forceinline__ float h_load(const f16* p){ return (float)*p; }
__device__ __forceinline__ void h_store(float* p, float v){ *p = v; }
__device__ __forceinline__ void h_store(f16* p, float v){ *p = (f16)v; }

// ---------------- prep: weight transposes/packs ----------------
__global__ void k_prep2(const float* __restrict__ Wih, const float* __restrict__ Whh,
                        const float* __restrict__ pw1, const float* __restrict__ pw2,
                        const float* __restrict__ out_w,
                        float* __restrict__ wih_p, float* __restrict__ whh_p,
                        float* __restrict__ pw1T, float* __restrict__ pw2T,
                        float* __restrict__ owT){
    int idx = blockIdx.x*256 + threadIdx.x;   // 65536 total
    {
        int f4 = idx>>2, c = idx&3;
        int i = f4>>10, tt = f4&1023;
        int g = tt>>1, kh = tt&1;
        int col = kh*64 + i*4 + c;
        wih_p[idx] = Wih[(size_t)g*128 + col];
        whh_p[idx] = Whh[(size_t)g*128 + col];
    }
    if (idx < 16384){
        int e = idx>>7, e2 = idx&127;
        pw1T[e2*128+e] = pw1[idx];
        pw2T[e2*128+e] = pw2[idx];
    }
    if (idx < 49152){
        int l = idx>>14, r = (idx>>7)&127, d = idx&127;
        owT[(size_t)l*16384 + d*128 + r] = out_w[idx];
    }
}

// big-ws extra: wihT[e][g] for the G GEMM
__global__ void k_prep3(const float* __restrict__ Wih, float* __restrict__ wihT){
    int idx = blockIdx.x*256 + threadIdx.x;   // 65536
    int g = idx>>7, e = idx&127;
    wihT[(size_t)e*512 + g] = Wih[idx];
}

// ---------------- input 4-channel stats ----------------
__global__ void k_inp_stats(const float* __restrict__ inp, float* __restrict__ part){
    int t = threadIdx.x;
    int row = blockIdx.x*256 + t;
    float4 u = *(const float4*)(inp + (size_t)row*4);
    __shared__ float red[256][8];
    red[t][0]=u.x; red[t][1]=u.y; red[t][2]=u.z; red[t][3]=u.w;
    red[t][4]=u.x*u.x; red[t][5]=u.y*u.y; red[t][6]=u.z*u.z; red[t][7]=u.w*u.w;
    __syncthreads();
    for (int s=128;s>0;s>>=1){
        if (t<s){
            #pragma unroll
            for (int c=0;c<8;c++) red[t][c]+=red[t+s][c];
        }
        __syncthreads();
    }
    if (t<8) part[blockIdx.x*8+t] = red[0][t];
}

__global__ void k_inp_final(const float* __restrict__ part,
    const float* __restrict__ opg, const float* __restrict__ opb,
    const float* __restrict__ opW, const float* __restrict__ opB,
    const float* __restrict__ mtg, const float* __restrict__ mtb,
    const float* __restrict__ mtW, const float* __restrict__ mtB,
    float* __restrict__ cwcb){
    int t = threadIdx.x; // 128
    __shared__ float sc[4], oc[4];
    if (t<4){
        float s=0.0f,q=0.0f;
        for (int i=0;i<600;i++){ s+=part[i*8+t]; q+=part[i*8+4+t]; }
        float mean = s/(float)RTOT;
        float var  = q/(float)RTOT - mean*mean;
        float rstd = 1.0f/sqrtf(var+1e-5f);
        float g = (t<2)?opg[t]:mtg[t-2];
        float b = (t<2)?opb[t]:mtb[t-2];
        sc[t]=g*rstd; oc[t]=b-mean*g*rstd;
    }
    __syncthreads();
    float w0=opW[t*2], w1=opW[t*2+1];
    float w2=mtW[t*2], w3=mtW[t*2+1];
    float* o = cwcb + t*5;
    o[0]=sc[0]*w0; o[1]=sc[1]*w1; o[2]=sc[2]*w2; o[3]=sc[3]*w3;
    o[4]=opB[t]+mtB[t] + oc[0]*w0+oc[1]*w1+oc[2]*w2+oc[3]*w3;
}

// ---------------- embed + enc0 stats ----------------
template<typename HT>
__global__ void k_embed(const float* __restrict__ inp, const float* __restrict__ cwcb,
                        HT* __restrict__ h, float* __restrict__ part){
    int bx=blockIdx.x, t=threadIdx.x;
    int row0 = bx*64;
    __shared__ float xin[64][4];
    if (t<64){
        float4 u = *(const float4*)(inp + (size_t)(row0+t)*4);
        xin[t][0]=u.x; xin[t][1]=u.y; xin[t][2]=u.z; xin[t][3]=u.w;
    }
    int e=t&127, rh=t>>7;
    float c0=cwcb[e*5],c1=cwcb[e*5+1],c2=cwcb[e*5+2],c3=cwcb[e*5+3],cb=cwcb[e*5+4];
    __syncthreads();
    float s=0.0f,q=0.0f;
    for (int r=rh; r<64; r+=2){
        float x = cb + xin[r][0]*c0 + xin[r][1]*c1 + xin[r][2]*c2 + xin[r][3]*c3;
        h_store(h + (size_t)(row0+r)*EE + e, x);
        s+=x; q+=x*x;
    }
    __shared__ float rs[256], rq[256];
    rs[t]=s; rq[t]=q;
    __syncthreads();
    if (rh==0){
        part[(size_t)bx*256 + e]       = rs[t]+rs[t+128];
        part[(size_t)bx*256 + 128 + e] = rq[t]+rq[t+128];
    }
}

// ---------------- BN reduce cascade ----------------
__global__ void k_bn_mid(const float* __restrict__ part, int nblk, float* __restrict__ part2){
    int j=blockIdx.x, t=threadIdx.x;   // 60 blocks x 256
    float s=0.0f;
    for (int i=j;i<nblk;i+=60) s += part[(size_t)i*256+t];
    part2[j*256+t]=s;
}

__global__ void k_bn_fin(const float* __restrict__ part2,
                         const float* __restrict__ g, const float* __restrict__ b,
                         float* __restrict__ scale, float* __restrict__ shift){
    int t=threadIdx.x;  // 256
    float s=0.0f;
    for (int j=0;j<60;j++) s += part2[j*256+t];
    __shared__ float red[256];
    red[t]=s; __syncthreads();
    if (t<128){
        float ss=red[t], qq=red[128+t];
        float mean=ss/(float)RTOT, var=qq/(float)RTOT-mean*mean;
        float rstd=1.0f/sqrtf(var+1e-5f);
        float gg=g[t];
        scale[t]=gg*rstd; shift[t]=b[t]-mean*gg*rstd;
    }
}

// ---------------- fused MHA + out-proj + residual + bn1 stats ----------------
#define HS0   0
#define WS0   19800
#define QKV0  26136
#define OH0   33336
#define OWS0  35886
#define BIA0  37998
#define SMTOT 38046
#define PS0   QKV0
#define PQ0   (QKV0+3840)
#define RS0   OWS0
#define RQ0   (OWS0+256)

template<typename HT>
__launch_bounds__(512,1)
__global__ void k_mha(HT* __restrict__ h, const float* __restrict__ in_w,
                      const float* __restrict__ in_b, const float* __restrict__ owT,
                      const float* __restrict__ out_b, int l, float* __restrict__ part,
                      const float* __restrict__ scal, const float* __restrict__ shft){
    __shared__ float sm[SMTOT];
    int b = blockIdx.x, t = threadIdx.x;
    const size_t hbase = (size_t)b*NN*EE;

    for (int j=t; j<NN*32; j+=512){
        int r=j>>5, e4=(j&31)*4;
        float4 x = h_load4(h + hbase + (size_t)r*EE + e4);
        float4 sc4 = *(const float4*)(scal + e4);
        float4 sh4 = *(const float4*)(shft + e4);
        x.x = fmaf(x.x, sc4.x, sh4.x); x.y = fmaf(x.y, sc4.y, sh4.y);
        x.z = fmaf(x.z, sc4.z, sh4.z); x.w = fmaf(x.w, sc4.w, sh4.w);
        *(float4*)&sm[HS0 + r*132 + e4] = x;
    }
    float hacc[5][8];
    #pragma unroll
    for (int i=0;i<5;i++){
        #pragma unroll
        for (int k=0;k<8;k++) hacc[i][k]=0.0f;
    }

    const float* Wl = in_w + (size_t)l*384*EE;
    const float* Bl = in_b + (size_t)l*384;
    const float* OwTl = owT + (size_t)l*EE*EE;
    int nb = t/12, cb = t - nb*12;
    int wv_ = t>>6, lw = t&63;
    int g3 = lw/3, th3 = lw - g3*3;
    int rA = wv_*21 + g3;
    bool actA = (lw<63) && (rA<150);
    int nb5 = t>>4, ebx = t&15;

    for (int hd=0; hd<8; hd++){
        __syncthreads();
        for (int j=t; j<48*32; j+=512){
            int row=j>>5, e4=(j&31)*4;
            int which=row>>4, d=row&15;
            int grow = which*EE + hd*16 + d;
            float4 w4 = *(const float4*)(Wl + (size_t)grow*EE + e4);
            *(float4*)&sm[WS0 + row*132 + e4] = w4;
        }
        for (int j=t; j<16*32; j+=512){
            int d=j>>5, e4=(j&31)*4;
            float4 o4 = *(const float4*)(OwTl + (size_t)(hd*16+d)*EE + e4);
            *(float4*)&sm[OWS0 + d*132 + e4] = o4;
        }
        if (t<48){ int which=t>>4, d=t&15; sm[BIA0+t] = Bl[which*EE + hd*16 + d]; }
        __syncthreads();

        if (t<456){
            float acc[4][4];
            #pragma unroll
            for (int i=0;i<4;i++){
                #pragma unroll
                for (int j=0;j<4;j++) acc[i][j]=sm[BIA0+cb*4+j];
            }
            const float* hp0 = &sm[HS0 + nb*4*132];
            const float* wp0 = &sm[WS0 + cb*4*132];
            for (int e2=0;e2<64;e2++){
                float2 h0=*(const float2*)(hp0 + 2*e2);
                float2 h1=*(const float2*)(hp0 + 132 + 2*e2);
                float2 h2=*(const float2*)(hp0 + 264 + 2*e2);
                float2 h3=*(const float2*)(hp0 + 396 + 2*e2);
                float2 w0=*(const float2*)(wp0 + 2*e2);
                float2 w1=*(const float2*)(wp0 + 132 + 2*e2);
                float2 w2=*(const float2*)(wp0 + 264 + 2*e2);
                float2 w3=*(const float2*)(wp0 + 396 + 2*e2);
                acc[0][0]=fmaf(h0.y,w0.y,fmaf(h0.x,w0.x,acc[0][0]));
                acc[0][1]=fmaf(h0.y,w1.y,fmaf(h0.x,w1.x,acc[0][1]));
                acc[0][2]=fmaf(h0.y,w2.y,fmaf(h0.x,w2.x,acc[0][2]));
                acc[0][3]=fmaf(h0.y,w3.y,fmaf(h0.x,w3.x,acc[0][3]));
                acc[1][0]=fmaf(h1.y,w0.y,fmaf(h1.x,w0.x,acc[1][0]));
                acc[1][1]=fmaf(h1.y,w1.y,fmaf(h1.x,w1.x,acc[1][1]));
                acc[1][2]=fmaf(h1.y,w2.y,fmaf(h1.x,w2.x,acc[1][2]));
                acc[1][3]=fmaf(h1.y,w3.y,fmaf(h1.x,w3.x,acc[1][3]));
                acc[2][0]=fmaf(h2.y,w0.y,fmaf(h2.x,w0.x,acc[2][0]));
                acc[2][1]=fmaf(h2.y,w1.y,fmaf(h2.x,w1.x,acc[2][1]));
                acc[2][2]=fmaf(h2.y,w2.y,fmaf(h2.x,w2.x,acc[2][2]));
                acc[2][3]=fmaf(h2.y,w3.y,fmaf(h2.x,w3.x,acc[2][3]));
                acc[3][0]=fmaf(h3.y,w0.y,fmaf(h3.x,w0.x,acc[3][0]));
                acc[3][1]=fmaf(h3.y,w1.y,fmaf(h3.x,w1.x,acc[3][1]));
                acc[3][2]=fmaf(h3.y,w2.y,fmaf(h3.x,w2.x,acc[3][2]));
                acc[3][3]=fmaf(h3.y,w3.y,fmaf(h3.x,w3.x,acc[3][3]));
            }
            #pragma unroll
            for (int i=0;i<4;i++){
                int n=nb*4+i;
                if (n<150){
                    #pragma unroll
                    for (int j=0;j<4;j++){
                        int c=cb*4+j;
                        sm[QKV0 + (c>>4)*2400 + n*16 + (c&15)] = acc[i][j];
                    }
                }
            }
        }
        __syncthreads();

        {
            float o[16];
            #pragma unroll
            for (int i=0;i<16;i++) o[i]=0.0f;
            float ls=0.0f;
            if (actA){
                float4 q0=*(const float4*)&sm[QKV0 + rA*16 + 0];
                float4 q1=*(const float4*)&sm[QKV0 + rA*16 + 4];
                float4 q2=*(const float4*)&sm[QKV0 + rA*16 + 8];
                float4 q3=*(const float4*)&sm[QKV0 + rA*16 + 12];
                int k0=th3*50;
                for (int kk=k0; kk<k0+50; kk++){
                    const float* kb=&sm[QKV0+2400 + kk*16];
                    float4 ka=*(const float4*)kb;
                    float4 kb4=*(const float4*)(kb+4);
                    float4 kc=*(const float4*)(kb+8);
                    float4 kd=*(const float4*)(kb+12);
                    float s = q0.x*ka.x;
                    s=fmaf(q0.y,ka.y,s); s=fmaf(q0.z,ka.z,s); s=fmaf(q0.w,ka.w,s);
                    s=fmaf(q1.x,kb4.x,s); s=fmaf(q1.y,kb4.y,s); s=fmaf(q1.z,kb4.z,s); s=fmaf(q1.w,kb4.w,s);
                    s=fmaf(q2.x,kc.x,s); s=fmaf(q2.y,kc.y,s); s=fmaf(q2.z,kc.z,s); s=fmaf(q2.w,kc.w,s);
                    s=fmaf(q3.x,kd.x,s); s=fmaf(q3.y,kd.y,s); s=fmaf(q3.z,kd.z,s); s=fmaf(q3.w,kd.w,s);
                    float p=__expf(s*0.25f);
                    ls+=p;
                    const float* vb=&sm[QKV0+4800 + kk*16];
                    float4 va=*(const float4*)vb;
                    float4 v1=*(const float4*)(vb+4);
                    float4 v2=*(const float4*)(vb+8);
                    float4 v3=*(const float4*)(vb+12);
                    o[0]=fmaf(p,va.x,o[0]); o[1]=fmaf(p,va.y,o[1]); o[2]=fmaf(p,va.z,o[2]); o[3]=fmaf(p,va.w,o[3]);
                    o[4]=fmaf(p,v1.x,o[4]); o[5]=fmaf(p,v1.y,o[5]); o[6]=fmaf(p,v1.z,o[6]); o[7]=fmaf(p,v1.w,o[7]);
                    o[8]=fmaf(p,v2.x,o[8]); o[9]=fmaf(p,v2.y,o[9]); o[10]=fmaf(p,v2.z,o[10]); o[11]=fmaf(p,v2.w,o[11]);
                    o[12]=fmaf(p,v3.x,o[12]); o[13]=fmaf(p,v3.y,o[13]); o[14]=fmaf(p,v3.z,o[14]); o[15]=fmaf(p,v3.w,o[15]);
                }
            }
            float ls1=__shfl_down(ls,1), ls2=__shfl_down(ls,2);
            float oc[16];
            #pragma unroll
            for (int i=0;i<16;i++){
                float a1=__shfl_down(o[i],1), a2=__shfl_down(o[i],2);
                oc[i]=(o[i]+a1)+a2;
            }
            if (actA && th3==0){
                float inv = 1.0f/((ls+ls1)+ls2);
                #pragma unroll
                for (int d=0;d<16;d++) sm[OH0 + rA*17 + d] = oc[d]*inv;
            }
        }
        __syncthreads();

        if (t<480){
            #pragma unroll
            for (int d=0; d<16; d++){
                float4 w0=*(const float4*)&sm[OWS0 + d*132 + ebx*8];
                float4 w1=*(const float4*)&sm[OWS0 + d*132 + ebx*8 + 4];
                #pragma unroll
                for (int i=0;i<5;i++){
                    float ov = sm[OH0 + (nb5*5+i)*17 + d];
                    hacc[i][0]=fmaf(ov,w0.x,hacc[i][0]);
                    hacc[i][1]=fmaf(ov,w0.y,hacc[i][1]);
                    hacc[i][2]=fmaf(ov,w0.z,hacc[i][2]);
                    hacc[i][3]=fmaf(ov,w0.w,hacc[i][3]);
                    hacc[i][4]=fmaf(ov,w1.x,hacc[i][4]);
                    hacc[i][5]=fmaf(ov,w1.y,hacc[i][5]);
                    hacc[i][6]=fmaf(ov,w1.z,hacc[i][6]);
                    hacc[i][7]=fmaf(ov,w1.w,hacc[i][7]);
                }
            }
        }
    }
    __syncthreads();
    if (t<480){
        float ob[8];
        *(float4*)&ob[0] = *(const float4*)(out_b + l*EE + ebx*8);
        *(float4*)&ob[4] = *(const float4*)(out_b + l*EE + ebx*8 + 4);
        float cs[8], cq[8];
        #pragma unroll
        for (int k=0;k<8;k++){ cs[k]=0.0f; cq[k]=0.0f; }
        #pragma unroll
        for (int i=0;i<5;i++){
            int r=nb5*5+i;
            float x[8];
            #pragma unroll
            for (int k2=0;k2<4;k2++){
                float2 hv=*(const float2*)&sm[HS0 + r*132 + ebx*8 + 2*k2];
                x[2*k2]   = hv.x + ob[2*k2]   + hacc[i][2*k2];
                x[2*k2+1] = hv.y + ob[2*k2+1] + hacc[i][2*k2+1];
            }
            h_store4(h + hbase + (size_t)r*EE + ebx*8,     make_float4(x[0],x[1],x[2],x[3]));
            h_store4(h + hbase + (size_t)r*EE + ebx*8 + 4, make_float4(x[4],x[5],x[6],x[7]));
            #pragma unroll
            for (int k=0;k<8;k++){ cs[k]+=x[k]; cq[k]+=x[k]*x[k]; }
        }
        #pragma unroll
        for (int k=0;k<8;k++){
            sm[PS0 + nb5*128 + ebx*8 + k]=cs[k];
            sm[PQ0 + nb5*128 + ebx*8 + k]=cq[k];
        }
    }
    __syncthreads();
    if (t<256){
        int e=t&127, hf=t>>7;
        float s=0.0f,q=0.0f;
        for (int nb_=hf*15; nb_<hf*15+15; nb_++){
            s+=sm[PS0+nb_*128+e]; q+=sm[PQ0+nb_*128+e];
        }
        sm[RS0+t]=s; sm[RQ0+t]=q;
    }
    __syncthreads();
    if (t<128){
        part[(size_t)b*256 + t]       = sm[RS0+t]+sm[RS0+128+t];
        part[(size_t)b*256 + 128 + t] = sm[RQ0+t]+sm[RQ0+128+t];
    }
}

// ---------------- fused FFN + residual + bn2 stats ----------------
template<typename HT>
__global__ void k_ff(HT* __restrict__ h,
                     const float* __restrict__ w1, const float* __restrict__ b1,
                     const float* __restrict__ w2, const float* __restrict__ b2,
                     int l, float* __restrict__ part,
                     const float* __restrict__ scal, const float* __restrict__ shft){
    int bx=blockIdx.x, t=threadIdx.x;
    int row0=bx*16;
    __shared__ __align__(16) float xn[16][EE];
    __shared__ __align__(16) float f1[16][FFD];
    __shared__ float w2T[64][EE+1];
    const float* W1 = w1 + (size_t)l*FFD*EE;
    const float* W2 = w2 + (size_t)l*EE*FFD;
    for (int j=t;j<16*EE;j+=256){
        int r=j>>7,e=j&127;
        xn[r][e]=fmaf(h_load(h + (size_t)(row0+r)*EE+e), scal[e], shft[e]);
    }
    __syncthreads();
    for (int fi=0;fi<2;fi++){
        int f=t+fi*256;
        const float4* wr = (const float4*)(W1 + (size_t)f*EE);
        float bias = b1[l*FFD+f];
        float acc[16];
        #pragma unroll
        for (int r=0;r<16;r++) acc[r]=bias;
        for (int e4=0;e4<32;e4++){
            float4 w=wr[e4];
            #pragma unroll
            for (int r=0;r<16;r++){
                float4 x=*(const float4*)&xn[r][4*e4];
                acc[r] += x.x*w.x + x.y*w.y + x.z*w.z + x.w*w.w;
            }
        }
        #pragma unroll
        for (int r=0;r<16;r++) f1[r][f]=fmaxf(acc[r],0.0f);
    }
    int e=t&127, rh=t>>7;
    float acc2[8];
    #pragma unroll
    for (int i=0;i<8;i++) acc2[i]=0.0f;
    for (int fc=0; fc<FFD; fc+=64){
        __syncthreads();
        for (int j=t;j<64*EE;j+=256){ int e_=j>>6, fl=j&63; w2T[fl][e_]=W2[(size_t)e_*FFD+fc+fl]; }
        __syncthreads();
        for (int fl=0;fl<64;fl++){
            float w=w2T[fl][e];
            #pragma unroll
            for (int i=0;i<8;i++) acc2[i] = fmaf(f1[rh*8+i][fc+fl], w, acc2[i]);
        }
    }
    float bias = b2[l*EE+e];
    float s=0.0f,q=0.0f;
    #pragma unroll
    for (int i=0;i<8;i++){
        float x = xn[rh*8+i][e] + bias + acc2[i];
        h_store(h + (size_t)(row0+rh*8+i)*EE+e, x);
        s+=x; q+=x*x;
    }
    __shared__ float rs[256], rq[256];
    rs[t]=s; rq[t]=q; __syncthreads();
    if (rh==0){
        part[(size_t)bx*256+e]=rs[t]+rs[t+128];
        part[(size_t)bx*256+128+e]=rq[t]+rq[t+128];
    }
}

// ---------------- G_ih precompute ----------------
template<typename HT>
__launch_bounds__(512)
__global__ void k_gih(const HT* __restrict__ h, const float* __restrict__ wihT,
                      const float* __restrict__ scal, const float* __restrict__ shft,
                      float* __restrict__ G, int b0){
    __shared__ float xn[NN][132];
    int bl = blockIdx.x, t = threadIdx.x;
    const size_t hbase = (size_t)(b0+bl)*NN*EE;
    for (int j=t; j<NN*32; j+=512){
        int r=j>>5, e4=(j&31)*4;
        float4 x = h_load4(h + hbase + (size_t)r*EE + e4);
        float4 sc4=*(const float4*)(scal+e4), sh4=*(const float4*)(shft+e4);
        x.x=fmaf(x.x,sc4.x,sh4.x); x.y=fmaf(x.y,sc4.y,sh4.y);
        x.z=fmaf(x.z,sc4.z,sh4.z); x.w=fmaf(x.w,sc4.w,sh4.w);
        *(float4*)&xn[r][e4]=x;
    }
    __syncthreads();
    float* Gb = G + (size_t)bl*NN*512;
    const float* wcol = wihT + t;
    for (int nb=0; nb<10; nb++){
        float acc[15];
        #pragma unroll
        for (int j=0;j<15;j++) acc[j]=0.0f;
        #pragma unroll 4
        for (int e=0;e<128;e++){
            float w = wcol[(size_t)e*512];
            #pragma unroll
            for (int j=0;j<15;j++) acc[j]=fmaf(xn[nb*15+j][e], w, acc[j]);
        }
        #pragma unroll
        for (int j=0;j<15;j++) Gb[(size_t)(nb*15+j)*512+t]=acc[j];
    }
}

// ---------------- shared decoder LDS layout ----------------
#define EWQ    19200
#define DGTS   38400
#define D_DD   39424
#define D_HH   39680
#define D_HW2  39936
#define D_PVS  40192
#define D_SCS  40320
#define D_SHS  40448
#define D_TOT  40576

// ---------------- decoder v2i (fallback, ws mid) ----------------
template<typename HT>
__launch_bounds__(1024,4)
__global__ void k_decoder2(const HT* __restrict__ enc, const float* __restrict__ inp,
        const float* __restrict__ wih_p, const float* __restrict__ whh_p,
        const float* __restrict__ bih, const float* __restrict__ bhh,
        const float* __restrict__ pw1T, const float* __restrict__ pb1,
        const float* __restrict__ pw2T, const float* __restrict__ pb2,
        const float* __restrict__ pv, const float* __restrict__ pbv,
        const float* __restrict__ scal, const float* __restrict__ shft,
        float* __restrict__ out){
    __shared__ float smf[D_TOT];
    __shared__ unsigned char schna[608];
    const int t = threadIdx.x;
    const int q = t>>9, r = t&511;
    const int b0 = blockIdx.x*2;
    const HT* encq = enc + (size_t)(b0+q)*NN*EE;

    if (t<128){ smf[D_PVS+t]=pv[t]; smf[D_SCS+t]=scal[t]; smf[D_SHS+t]=shft[t]; }
    if (t<512) smf[D_DD+t]=0.0f;
    if (t<304){
        int qq=t/152, n=t-qq*152;
        schna[qq*304+n]=0;
        unsigned char nav=1;
        if (n<150) nav = (inp[((size_t)(b0+qq)*NN+n)*4+1] != 0.0f) ? 1 : 0;
        schna[qq*304+152+n]=nav;
    }
    const int g = t>>1, kh = t&1;
    const float bsum = bih[g] + bhh[g];
    const float pb2r = (t<256) ? pb2[t&127] : 0.0f;
    const float pbvr = pbv[0];

    float4 whr[16];
    {
        const float4* wp = (const float4*)whh_p + t;
        #pragma unroll
        for (int i=0;i<16;i++) whr[i] = wp[(size_t)i*1024];
    }
    __syncthreads();

    {
        const int e = r&127, ng = r>>7;
        const float pb1e = pb1[e];
        for (int n1 = ng; n1 < 150; n1 += 8){
            int n2 = n1+4;
            bool has2 = (n2<150);
            int n2c = has2 ? n2 : n1;
            float a1=0.0f, a2=0.0f;
            #pragma unroll 4
            for (int e2=0;e2<EE;e2++){
                float w = pw1T[e2*EE + e];
                float x1 = fmaf(smf[D_SCS+e2], h_load(encq + (size_t)n1*EE + e2), smf[D_SHS+e2]);
                float x2 = fmaf(smf[D_SCS+e2], h_load(encq + (size_t)n2c*EE + e2), smf[D_SHS+e2]);
                a1 = fmaf(x1, w, a1);
                a2 = fmaf(x2, w, a2);
            }
            smf[q*EWQ + n1*128 + (e ^ (n1&31))] = a1 + pb1e;
            if (has2) smf[q*EWQ + n2*128 + (e ^ (n2&31))] = a2 + pb1e;
        }
    }
    if (t<512){
        int qq=t>>8, rr=t&255, e=rr&127, hf=rr>>7;
        const HT* eb = enc + (size_t)(b0+qq)*NN*EE;
        float s=0.0f;
        for (int n=hf*75;n<hf*75+75;n++) s += h_load(eb + (size_t)n*EE+e);
        smf[DGTS + qq*256 + hf*128 + e] = s;
    }
    __syncthreads();
    float c_reg = 0.0f;
    if (t<256){
        int qq=t>>7, e=t&127;
        float mean = (smf[DGTS+qq*256+e]+smf[DGTS+qq*256+128+e])*(1.0f/150.0f);
        c_reg = fmaf(smf[D_SCS+e], mean, smf[D_SHS+e]);
    }
    __syncthreads();

    float llacc=0.0f;
    const float4* wip = (const float4*)wih_p + t;
    for (int step=0; step<NN; step++){
        {
            float a0=0.0f, a1=0.0f;
            const float* d0 = &smf[D_DD + kh*64];
            const float* d1 = &smf[D_DD + 128 + kh*64];
            const float* h0 = &smf[D_HH + kh*64];
            const float* h1 = &smf[D_HH + 128 + kh*64];
            #pragma unroll 8
            for (int i=0;i<16;i++){
                float4 wv = wip[(size_t)i*1024];
                float4 wh = whr[i];
                float4 x0 = *(const float4*)(d0 + 4*i);
                float4 x1 = *(const float4*)(d1 + 4*i);
                float4 y0 = *(const float4*)(h0 + 4*i);
                float4 y1 = *(const float4*)(h1 + 4*i);
                a0 = fmaf(wv.w,x0.w,fmaf(wv.z,x0.z,fmaf(wv.y,x0.y,fmaf(wv.x,x0.x,a0))));
                a0 = fmaf(wh.w,y0.w,fmaf(wh.z,y0.z,fmaf(wh.y,y0.y,fmaf(wh.x,y0.x,a0))));
                a1 = fmaf(wv.w,x1.w,fmaf(wv.z,x1.z,fmaf(wv.y,x1.y,fmaf(wv.x,x1.x,a1))));
                a1 = fmaf(wh.w,y1.w,fmaf(wh.z,y1.z,fmaf(wh.y,y1.y,fmaf(wh.x,y1.x,a1))));
            }
            a0 += __shfl_xor(a0,1);
            a1 += __shfl_xor(a1,1);
            if (kh==0){
                smf[DGTS + g]       = a0 + bsum;
                smf[DGTS + 512 + g] = a1 + bsum;
            }
        }
        __syncthreads();
        if (t<256){
            int qq=t>>7, e=t&127;
            const float* gt = &smf[DGTS + qq*512];
            float gi=fsig(gt[e]), gf=fsig(gt[128+e]), gg=ftanh(gt[256+e]), go=fsig(gt[384+e]);
            c_reg = gf*c_reg + gi*gg;
            smf[D_HH + qq*128 + e] = go*ftanh(c_reg);
        }
        __syncthreads();
        if (t<256){
            int qq=t>>7, e=t&127;
            float s2=0.0f;
            #pragma unroll 4
            for (int e2=0;e2<EE;e2++)
                s2 = fmaf(pw2T[e2*EE + e], smf[D_HH + qq*128 + e2], s2);
            smf[D_HW2 + qq*128 + e] = s2 + pb2r;
        }
        __syncthreads();
        {
            int half = r>>8, n = r&255;
            if (n<150){
                float p=0.0f;
                const float* ewn = &smf[q*EWQ + n*128];
                const float* hwq = &smf[D_HW2 + q*128];
                int sw = n&31;
                #pragma unroll 8
                for (int e2=0;e2<64;e2++){
                    int e = half*64+e2;
                    p = fmaf(ftanh(ewn[e ^ sw] + hwq[e]), smf[D_PVS+e], p);
                }
                smf[DGTS + (q*2+half)*152 + n] = p;
            }
        }
        __syncthreads();
        if (t<128){
            int qq=t>>6, l=t&63;
            const unsigned char* sc_ = &schna[qq*304];
            const float* pp = &smf[DGTS + qq*2*152];
            int n0=l, n1=l+64, n2=l+128;
            float a0 = pp[n0]+pp[152+n0]+pbvr;
            float a1 = pp[n1]+pp[152+n1]+pbvr;
            float v0 = (sc_[n0]|sc_[152+n0]) ? -10000.0f : a0;
            float v1 = (sc_[n1]|sc_[152+n1]) ? -10000.0f : a1;
            float v2 = -1e30f;
            if (n2<NN){
                float a2 = pp[n2]+pp[152+n2]+pbvr;
                v2 = (sc_[n2]|sc_[152+n2]) ? -10000.0f : a2;
            }
            float m=v0; int mi=n0;
            if (v1>m){ m=v1; mi=n1; }
            if (n2<NN && v2>m){ m=v2; mi=n2; }
            #pragma unroll
            for (int off=1; off<64; off<<=1){
                float om=__shfl_xor(m,off); int oi=__shfl_xor(mi,off);
                if (om>m || (om==m && oi<mi)){ m=om; mi=oi; }
            }
            float se = __expf(v0-m)+__expf(v1-m) + ((n2<NN)? __expf(v2-m):0.0f);
            #pragma unroll
            for (int off=1; off<64; off<<=1) se += __shfl_xor(se,off);
            const HT* eb = enc + (size_t)(b0+qq)*NN*EE;
            if (l==0){
                llacc -= logf(se);
                schna[qq*304+mi]=1;
                int nn2 = mi+1; if (nn2>NN-1) nn2=NN-1;
                schna[qq*304+152+nn2]=0;
                float4 rowv = *(const float4*)(inp + ((size_t)(b0+qq)*NN+mi)*4);
                *(float4*)(out + ((size_t)(b0+qq)*NN+step)*4) = rowv;
            }
            float eva = h_load(eb + (size_t)mi*EE + l);
            float evb = h_load(eb + (size_t)mi*EE + l + 64);
            smf[D_DD + qq*128 + l]      = fmaf(smf[D_SCS+l],    eva, smf[D_SHS+l]);
            smf[D_DD + qq*128 + l + 64] = fmaf(smf[D_SCS+l+64], evb, smf[D_SHS+l+64]);
        }
        __syncthreads();
    }
    if (t==0)  out[(size_t)BB*NN*4 + b0]   = llacc;
    if (t==64) out[(size_t)BB*NN*4 + b0+1] = llacc;
}

// ---------------- decoder G3: 512 threads, 2 batches, true register weights ----------------
#define H_GTS  38400
#define H_HH   39424
#define H_HW2  39680
#define H_PVS  39936
#define H_SCS  40064
#define H_SHS  40192
#define H_TOT  40320

template<typename HT>
__launch_bounds__(512,2)
__global__ void k_decoderG3(const HT* __restrict__ enc, const float* __restrict__ inp,
        const float* __restrict__ Whh, const float* __restrict__ Gih,
        const float* __restrict__ bih, const float* __restrict__ bhh,
        const float* __restrict__ pw1T, const float* __restrict__ pb1,
        const float* __restrict__ pw2T, const float* __restrict__ pb2,
        const float* __restrict__ pv, const float* __restrict__ pbv,
        const float* __restrict__ scal, const float* __restrict__ shft,
        float* __restrict__ out, int passb0){
    __shared__ float smf[H_TOT];
    __shared__ unsigned char schna[608];
    __shared__ int predS2[2];
    const int t = threadIdx.x;             // 512
    const int b0 = passb0 + blockIdx.x*2;

    if (t<128){ smf[H_PVS+t]=pv[t]; smf[H_SCS+t]=scal[t]; smf[H_SHS+t]=shft[t]; }
    if (t<256) smf[H_HH+t]=0.0f;
    if (t<304){
        int qq=t/152, n=t-qq*152;
        schna[qq*304+n]=0;
        unsigned char nav=1;
        if (n<150) nav = (inp[((size_t)(b0+qq)*NN+n)*4+1] != 0.0f) ? 1 : 0;
        schna[qq*304+152+n]=nav;
    }
    if (t<2) predS2[t]=-1;

    const float bsum = bih[t] + bhh[t];
    const float pb2r = (t<256) ? pb2[t&127] : 0.0f;
    const float pbvr = pbv[0];

    // register-resident Whh row t (128 VGPR) straight from raw Whh
    float4 whr[32];
    {
        const float4* wp = (const float4*)(Whh + (size_t)t*EE);
        #pragma unroll
        for (int i=0;i<32;i++) whr[i] = wp[i];
    }
    // register-resident pw2T K-quarter (32 VGPR)
    float pwr[32];
    {
        int e=t&127, k4=t>>7;
        const float* src = pw2T + (size_t)(k4*32)*EE + e;
        #pragma unroll
        for (int i=0;i<32;i++) pwr[i] = src[(size_t)i*EE];
    }
    __syncthreads();

    // ew = bn(enc) @ pw1^T + pb1 (XOR-swizzled), both batches
    {
        const int e = t&127, rg = t>>7;     // 4 row-groups
        const float pb1e = pb1[e];
        for (int qq=0; qq<2; qq++){
            const HT* encq = enc + (size_t)(b0+qq)*NN*EE;
            for (int n=rg; n<150; n+=4){
                float a=0.0f;
                #pragma unroll 4
                for (int e2=0;e2<EE;e2++){
                    float x = fmaf(smf[H_SCS+e2], h_load(encq + (size_t)n*EE + e2), smf[H_SHS+e2]);
                    a = fmaf(x, pw1T[e2*EE + e], a);
                }
                smf[qq*EWQ + n*128 + (e ^ (n&31))] = a + pb1e;
            }
        }
    }
    // c0 partials
    {
        int qq=t>>8, rr=t&255, e=rr&127, hf=rr>>7;
        const HT* eb = enc + (size_t)(b0+qq)*NN*EE;
        float s=0.0f;
        for (int n=hf*75;n<hf*75+75;n++) s += h_load(eb + (size_t)n*EE+e);
        smf[H_GTS + qq*256 + hf*128 + e] = s;
    }
    __syncthreads();
    float c_reg = 0.0f;
    if (t<256){
        int qq=t>>7, e=t&127;
        float mean = (smf[H_GTS+qq*256+e]+smf[H_GTS+qq*256+128+e])*(1.0f/150.0f);
        c_reg = fmaf(smf[H_SCS+e], mean, smf[H_SHS+e]);
    }
    __syncthreads();

    float llacc=0.0f;
    const float* Gb0 = Gih + (size_t)(blockIdx.x*2)*NN*512;
    const float* Gb1 = Gih + (size_t)(blockIdx.x*2+1)*NN*512;
    for (int step=0; step<NN; step++){
        // A. gate t for both batches: G-lookup + registered Whh x hh
        {
            int p0=predS2[0], p1=predS2[1];
            float a0 = bsum + ((p0>=0) ? Gb0[(size_t)p0*512 + t] : 0.0f);
            float a1 = bsum + ((p1>=0) ? Gb1[(size_t)p1*512 + t] : 0.0f);
            const float4* h0 = (const float4*)&smf[H_HH];
            const float4* h1 = (const float4*)&smf[H_HH + 128];
            #pragma unroll 8
            for (int i=0;i<32;i++){
                float4 w = whr[i];
                float4 y0 = h0[i];
                float4 y1 = h1[i];
                a0 = fmaf(w.w,y0.w,fmaf(w.z,y0.z,fmaf(w.y,y0.y,fmaf(w.x,y0.x,a0))));
                a1 = fmaf(w.w,y1.w,fmaf(w.z,y1.z,fmaf(w.y,y1.y,fmaf(w.x,y1.x,a1))));
            }
            smf[H_GTS + t]       = a0;
            smf[H_GTS + 512 + t] = a1;
        }
        __syncthreads();
        // B. LSTM cell
        if (t<256){
            int qq=t>>7, e=t&127;
            const float* gt=&smf[H_GTS+qq*512];
            float gi=fsig(gt[e]), gf=fsig(gt[128+e]), gg=ftanh(gt[256+e]), go=fsig(gt[384+e]);
            c_reg = gf*c_reg + gi*gg;
            smf[H_HH + qq*128 + e] = go*ftanh(c_reg);
        }
        __syncthreads();
        // C. hw2 partials from VGPR pw2T (both batches, quarter-K each)
        {
            int e=t&127, k4=t>>7;
            float p0s=0.0f, p1s=0.0f;
            const float* h0=&smf[H_HH + k4*32];
            const float* h1=&smf[H_HH + 128 + k4*32];
            #pragma unroll
            for (int i=0;i<32;i++){
                p0s=fmaf(pwr[i],h0[i],p0s);
                p1s=fmaf(pwr[i],h1[i],p1s);
            }
            smf[H_GTS + k4*128 + e]       = p0s;
            smf[H_GTS + 512 + k4*128 + e] = p1s;
        }
        __syncthreads();
        // C2. reduce 4 partials
        if (t<256){
            int qq=t>>7, e=t&127;
            const float* cp=&smf[H_GTS+qq*512];
            smf[H_HW2 + qq*128 + e] = ((cp[e]+cp[128+e])+(cp[256+e]+cp[384+e])) + pb2r;
        }
        __syncthreads();
        // D. pointer logits: (batch, half, n<128) over 512 threads + 88-thread tail
        {
            int qd = t>>8, half = (t>>7)&1, n = t&127;
            {
                float p=0.0f;
                const float* ewn = &smf[qd*EWQ + n*128];
                const float* hwq = &smf[H_HW2 + qd*128];
                int sw = n&31;
                #pragma unroll 8
                for (int e2=0;e2<64;e2++){
                    int e = half*64+e2;
                    p = fmaf(ftanh(ewn[e ^ sw] + hwq[e]), smf[H_PVS+e], p);
                }
                smf[H_GTS + (qd*2+half)*152 + n] = p;
            }
            if (t<88){
                int qd2 = t/44, rem = t - qd2*44;
                int half2 = rem/22, n2 = 128 + rem - half2*22;
                float p=0.0f;
                const float* ewn = &smf[qd2*EWQ + n2*128];
                const float* hwq = &smf[H_HW2 + qd2*128];
                int sw = n2&31;
                #pragma unroll 8
                for (int e2=0;e2<64;e2++){
                    int e = half2*64+e2;
                    p = fmaf(ftanh(ewn[e ^ sw] + hwq[e]), smf[H_PVS+e], p);
                }
                smf[H_GTS + (qd2*2+half2)*152 + n2] = p;
            }
        }
        __syncthreads();
        // E. argmax + lse + state update (2 waves)
        if (t<128){
            int qq=t>>6, l=t&63;
            const unsigned char* sc_ = &schna[qq*304];
            const float* pp = &smf[H_GTS + qq*2*152];
            int n0=l, n1=l+64, n2=l+128;
            float a0 = pp[n0]+pp[152+n0]+pbvr;
            float a1 = pp[n1]+pp[152+n1]+pbvr;
            float v0 = (sc_[n0]|sc_[152+n0]) ? -10000.0f : a0;
            float v1 = (sc_[n1]|sc_[152+n1]) ? -10000.0f : a1;
            float v2 = -1e30f;
            if (n2<NN){
                float a2 = pp[n2]+pp[152+n2]+pbvr;
                v2 = (sc_[n2]|sc_[152+n2]) ? -10000.0f : a2;
            }
            float m=v0; int mi=n0;
            if (v1>m){ m=v1; mi=n1; }
            if (n2<NN && v2>m){ m=v2; mi=n2; }
            #pragma unroll
            for (int off=1; off<64; off<<=1){
                float om=__shfl_xor(m,off); int oi=__shfl_xor(mi,off);
                if (om>m || (om==m && oi<mi)){ m=om; mi=oi; }
            }
            float se = __expf(v0-m)+__expf(v1-m) + ((n2<NN)? __expf(v2-m):0.0f);
            #pragma unroll
            for (int off=1; off<64; off<<=1) se += __shfl_xor(se,off);
            if (l==0){
                llacc -= logf(se);
                predS2[qq]=mi;
                schna[qq*304+mi]=1;
                int nn2 = mi+1; if (nn2>NN-1) nn2=NN-1;
                schna[qq*304+152+nn2]=0;
                float4 rowv = *(const float4*)(inp + ((size_t)(b0+qq)*NN+mi)*4);
                *(float4*)(out + ((size_t)(b0+qq)*NN+step)*4) = rowv;
            }
        }
        __syncthreads();
    }
    if (t==0)  out[(size_t)BB*NN*4 + b0]   = llacc;
    if (t==64) out[(size_t)BB*NN*4 + b0+1] = llacc;
}

// ---------------- host schedule ----------------
template<typename HT>
static void run_model(void* const* d_in, void* d_out, void* d_ws, bool big, hipStream_t stream){
    const float* inp   = (const float*)d_in[0];
    const float* opg   = (const float*)d_in[1];
    const float* opb   = (const float*)d_in[2];
    const float* opW   = (const float*)d_in[3];
    const float* opB   = (const float*)d_in[4];
    const float* mtg   = (const float*)d_in[5];
    const float* mtb   = (const float*)d_in[6];
    const float* mtW   = (const float*)d_in[7];
    const float* mtB   = (const float*)d_in[8];
    const float* e0g   = (const float*)d_in[9];
    const float* e0b   = (const float*)d_in[10];
    const float* in_w  = (const float*)d_in[11];
    const float* in_b  = (const float*)d_in[12];
    const float* out_w = (const float*)d_in[13];
    const float* out_b = (const float*)d_in[14];
    const float* bn1g  = (const float*)d_in[15];
    const float* bn1b  = (const float*)d_in[16];
    const float* ffw1  = (const float*)d_in[17];
    const float* ffb1  = (const float*)d_in[18];
    const float* ffw2  = (const float*)d_in[19];
    const float* ffb2  = (const float*)d_in[20];
    const float* bn2g  = (const float*)d_in[21];
    const float* bn2b  = (const float*)d_in[22];
    const float* Wih   = (const float*)d_in[23];
    const float* Whh   = (const float*)d_in[24];
    const float* bihp  = (const float*)d_in[25];
    const float* bhhp  = (const float*)d_in[26];
    const float* pw1   = (const float*)d_in[27];
    const float* pb1   = (const float*)d_in[28];
    const float* pw2   = (const float*)d_in[29];
    const float* pb2   = (const float*)d_in[30];
    const float* pv    = (const float*)d_in[31];
    const float* pbv   = (const float*)d_in[32];
    float* out = (float*)d_out;

    HT* h = (HT*)d_ws;
    float* Xf = (float*)((char*)d_ws + (size_t)RTOT*EE*sizeof(HT));
    float* part  = Xf;                    // 2457600
    float* cwcb  = Xf + 2457600;          // 640
    float* scal  = cwcb + 640;
    float* shft  = scal + 128;
    float* wih_p = shft + 128;            // 65536
    float* whh_p = wih_p + 65536;         // 65536
    float* pw1T  = whh_p + 65536;         // 16384
    float* pw2Tg = pw1T + 16384;          // 16384
    float* owT   = pw2Tg + 16384;         // 49152
    float* part2 = owT + 49152;           // 15360
    float* wihT  = part2 + 15360;         // 65536 (big only)
    float* G     = wihT + 65536;          // 39,321,600 (big only)

    k_prep2<<<256,256,0,stream>>>(Wih, Whh, pw1, pw2, out_w, wih_p, whh_p, pw1T, pw2Tg, owT);
    if (big) k_prep3<<<256,256,0,stream>>>(Wih, wihT);
    k_inp_stats<<<600,256,0,stream>>>(inp, part);
    k_inp_final<<<1,128,0,stream>>>(part, opg,opb,opW,opB, mtg,mtb,mtW,mtB, cwcb);
    k_embed<HT><<<2400,256,0,stream>>>(inp, cwcb, h, part);
    k_bn_mid<<<60,256,0,stream>>>(part, 2400, part2);
    k_bn_fin<<<1,256,0,stream>>>(part2, e0g, e0b, scal, shft);
    for (int l=0;l<NL;l++){
        k_mha<HT><<<1024,512,0,stream>>>(h, in_w, in_b, owT, out_b, l, part, scal, shft);
        k_bn_mid<<<60,256,0,stream>>>(part, 1024, part2);
        k_bn_fin<<<1,256,0,stream>>>(part2, bn1g + l*EE, bn1b + l*EE, scal, shft);
        k_ff<HT><<<9600,256,0,stream>>>(h, ffw1, ffb1, ffw2, ffb2, l, part, scal, shft);
        k_bn_mid<<<60,256,0,stream>>>(part, 9600, part2);
        k_bn_fin<<<1,256,0,stream>>>(part2, bn2g + l*EE, bn2b + l*EE, scal, shft);
    }
    if (big){
        for (int pass=0; pass<2; pass++){
            k_gih<HT><<<512,512,0,stream>>>(h, wihT, scal, shft, G, pass*512);
            k_decoderG3<HT><<<256,512,0,stream>>>(h, inp, Whh, G, bihp, bhhp,
                                                  pw1T, pb1, pw2Tg, pb2, pv, pbv,
                                                  scal, shft, out, pass*512);
        }
    } else {
        k_decoder2<HT><<<512,1024,0,stream>>>(h, inp, wih_p, whh_p, bihp, bhhp,
                                              pw1T, pb1, pw2Tg, pb2, pv, pbv,
                                              scal, shft, out);
    }
}

extern "C" void kernel_launch(void* const* d_in, const int* in_sizes, int n_in,
                              void* d_out, int out_size, void* d_ws, size_t ws_size,
                              hipStream_t stream){
    const size_t xf_floats = 2457600u + 640 + 128 + 128 + 65536 + 65536 + 16384 + 16384 + 49152 + 15360;
    const size_t need_A   = (size_t)RTOT*EE*4 + xf_floats*4ull;
    const size_t need_big = need_A + (size_t)(65536 + 39321600)*4ull;
    if (ws_size >= need_big){
        run_model<float>(d_in, d_out, d_ws, true, stream);
    } else if (ws_size >= need_A){
        run_model<float>(d_in, d_out, d_ws, false, stream);
    } else {
        run_model<f16>(d_in, d_out, d_ws, false, stream);
    }
    (void)in_sizes; (void)n_in; (void)out_size; (void)ws_size;
}

// Round 12
// 11663.407 us; speedup vs baseline: 1.0702x; 1.0702x over previous
//
#include <hip/hip_runtime.h>
#include <math.h>

#define BB 1024
#define NN 150
#define RTOT (BB*NN)
#define EE 128
#define FFD 512
#define NL 3

typedef unsigned short u16;
typedef unsigned int u32;
typedef _Float16 f16;
typedef _Float16 f16x4 __attribute__((ext_vector_type(4)));

__device__ __forceinline__ float fsig(float x){ return __builtin_amdgcn_rcpf(1.0f + __expf(-x)); }
__device__ __forceinline__ float ftanh(float x){ return 1.0f - 2.0f*__builtin_amdgcn_rcpf(1.0f + __expf(2.0f*x)); }

// ---- h storage accessors ----
__device__ __forceinline__ float4 h_load4(const float* p){ return *(const float4*)p; }
__device__ __forceinline__ float4 h_load4(const f16* p){
    f16x4 v = *(const f16x4*)p;
    return make_float4((float)v.x,(float)v.y,(float)v.z,(float)v.w);
}
__device__ __forceinline__ void h_store4(float* p, float4 v){ *(float4*)p = v; }
__device__ __forceinline__ void h_store4(f16* p, float4 v){
    f16x4 o; o.x=(f16)v.x; o.y=(f16)v.y; o.z=(f16)v.z; o.w=(f16)v.w;
    *(f16x4*)p = o;
}
__device__ __forceinline__ float h_load(const float* p){ return *p; }
__device__ __forceinline__ float h_load(const f16* p){ return (float)*p; }
__device__ __forceinline__ void h_store(float* p, float v){ *p = v; }
__device__ __forceinline__ void h_store(f16* p, float v){ *p = (f16)v; }

// ---------------- prep: weight transposes/packs ----------------
__global__ void k_prep2(const float* __restrict__ Wih, const float* __restrict__ Whh,
                        const float* __restrict__ pw1, const float* __restrict__ pw2,
                        const float* __restrict__ out_w,
                        float* __restrict__ wih_p, float* __restrict__ whh_p,
                        float* __restrict__ pw1T, float* __restrict__ pw2T,
                        float* __restrict__ owT){
    int idx = blockIdx.x*256 + threadIdx.x;   // 65536 total
    {
        int f4 = idx>>2, c = idx&3;
        int i = f4>>10, tt = f4&1023;
        int g = tt>>1, kh = tt&1;
        int col = kh*64 + i*4 + c;
        wih_p[idx] = Wih[(size_t)g*128 + col];
        whh_p[idx] = Whh[(size_t)g*128 + col];
    }
    if (idx < 16384){
        int e = idx>>7, e2 = idx&127;
        pw1T[e2*128+e] = pw1[idx];
        pw2T[e2*128+e] = pw2[idx];
    }
    if (idx < 49152){
        int l = idx>>14, r = (idx>>7)&127, d = idx&127;
        owT[(size_t)l*16384 + d*128 + r] = out_w[idx];
    }
}

// big-ws extra: wihT[e][g] for the G GEMM
__global__ void k_prep3(const float* __restrict__ Wih, float* __restrict__ wihT){
    int idx = blockIdx.x*256 + threadIdx.x;   // 65536
    int g = idx>>7, e = idx&127;
    wihT[(size_t)e*512 + g] = Wih[idx];
}

// ---------------- input 4-channel stats ----------------
__global__ void k_inp_stats(const float* __restrict__ inp, float* __restrict__ part){
    int t = threadIdx.x;
    int row = blockIdx.x*256 + t;
    float4 u = *(const float4*)(inp + (size_t)row*4);
    __shared__ float red[256][8];
    red[t][0]=u.x; red[t][1]=u.y; red[t][2]=u.z; red[t][3]=u.w;
    red[t][4]=u.x*u.x; red[t][5]=u.y*u.y; red[t][6]=u.z*u.z; red[t][7]=u.w*u.w;
    __syncthreads();
    for (int s=128;s>0;s>>=1){
        if (t<s){
            #pragma unroll
            for (int c=0;c<8;c++) red[t][c]+=red[t+s][c];
        }
        __syncthreads();
    }
    if (t<8) part[blockIdx.x*8+t] = red[0][t];
}

__global__ void k_inp_final(const float* __restrict__ part,
    const float* __restrict__ opg, const float* __restrict__ opb,
    const float* __restrict__ opW, const float* __restrict__ opB,
    const float* __restrict__ mtg, const float* __restrict__ mtb,
    const float* __restrict__ mtW, const float* __restrict__ mtB,
    float* __restrict__ cwcb){
    int t = threadIdx.x; // 128
    __shared__ float sc[4], oc[4];
    if (t<4){
        float s=0.0f,q=0.0f;
        for (int i=0;i<600;i++){ s+=part[i*8+t]; q+=part[i*8+4+t]; }
        float mean = s/(float)RTOT;
        float var  = q/(float)RTOT - mean*mean;
        float rstd = 1.0f/sqrtf(var+1e-5f);
        float g = (t<2)?opg[t]:mtg[t-2];
        float b = (t<2)?opb[t]:mtb[t-2];
        sc[t]=g*rstd; oc[t]=b-mean*g*rstd;
    }
    __syncthreads();
    float w0=opW[t*2], w1=opW[t*2+1];
    float w2=mtW[t*2], w3=mtW[t*2+1];
    float* o = cwcb + t*5;
    o[0]=sc[0]*w0; o[1]=sc[1]*w1; o[2]=sc[2]*w2; o[3]=sc[3]*w3;
    o[4]=opB[t]+mtB[t] + oc[0]*w0+oc[1]*w1+oc[2]*w2+oc[3]*w3;
}

// ---------------- embed + enc0 stats ----------------
template<typename HT>
__global__ void k_embed(const float* __restrict__ inp, const float* __restrict__ cwcb,
                        HT* __restrict__ h, float* __restrict__ part){
    int bx=blockIdx.x, t=threadIdx.x;
    int row0 = bx*64;
    __shared__ float xin[64][4];
    if (t<64){
        float4 u = *(const float4*)(inp + (size_t)(row0+t)*4);
        xin[t][0]=u.x; xin[t][1]=u.y; xin[t][2]=u.z; xin[t][3]=u.w;
    }
    int e=t&127, rh=t>>7;
    float c0=cwcb[e*5],c1=cwcb[e*5+1],c2=cwcb[e*5+2],c3=cwcb[e*5+3],cb=cwcb[e*5+4];
    __syncthreads();
    float s=0.0f,q=0.0f;
    for (int r=rh; r<64; r+=2){
        float x = cb + xin[r][0]*c0 + xin[r][1]*c1 + xin[r][2]*c2 + xin[r][3]*c3;
        h_store(h + (size_t)(row0+r)*EE + e, x);
        s+=x; q+=x*x;
    }
    __shared__ float rs[256], rq[256];
    rs[t]=s; rq[t]=q;
    __syncthreads();
    if (rh==0){
        part[(size_t)bx*256 + e]       = rs[t]+rs[t+128];
        part[(size_t)bx*256 + 128 + e] = rq[t]+rq[t+128];
    }
}

// ---------------- BN reduce cascade ----------------
__global__ void k_bn_mid(const float* __restrict__ part, int nblk, float* __restrict__ part2){
    int j=blockIdx.x, t=threadIdx.x;   // 60 blocks x 256
    float s=0.0f;
    for (int i=j;i<nblk;i+=60) s += part[(size_t)i*256+t];
    part2[j*256+t]=s;
}

__global__ void k_bn_fin(const float* __restrict__ part2,
                         const float* __restrict__ g, const float* __restrict__ b,
                         float* __restrict__ scale, float* __restrict__ shift){
    int t=threadIdx.x;  // 256
    float s=0.0f;
    for (int j=0;j<60;j++) s += part2[j*256+t];
    __shared__ float red[256];
    red[t]=s; __syncthreads();
    if (t<128){
        float ss=red[t], qq=red[128+t];
        float mean=ss/(float)RTOT, var=qq/(float)RTOT-mean*mean;
        float rstd=1.0f/sqrtf(var+1e-5f);
        float gg=g[t];
        scale[t]=gg*rstd; shift[t]=b[t]-mean*gg*rstd;
    }
}

// ---------------- fused MHA + out-proj + residual + bn1 stats ----------------
#define HS0   0
#define WS0   19800
#define QKV0  26136
#define OH0   33336
#define OWS0  35886
#define BIA0  37998
#define SMTOT 38046
#define PS0   QKV0
#define PQ0   (QKV0+3840)
#define RS0   OWS0
#define RQ0   (OWS0+256)

template<typename HT>
__launch_bounds__(512,1)
__global__ void k_mha(HT* __restrict__ h, const float* __restrict__ in_w,
                      const float* __restrict__ in_b, const float* __restrict__ owT,
                      const float* __restrict__ out_b, int l, float* __restrict__ part,
                      const float* __restrict__ scal, const float* __restrict__ shft){
    __shared__ float sm[SMTOT];
    int b = blockIdx.x, t = threadIdx.x;
    const size_t hbase = (size_t)b*NN*EE;

    for (int j=t; j<NN*32; j+=512){
        int r=j>>5, e4=(j&31)*4;
        float4 x = h_load4(h + hbase + (size_t)r*EE + e4);
        float4 sc4 = *(const float4*)(scal + e4);
        float4 sh4 = *(const float4*)(shft + e4);
        x.x = fmaf(x.x, sc4.x, sh4.x); x.y = fmaf(x.y, sc4.y, sh4.y);
        x.z = fmaf(x.z, sc4.z, sh4.z); x.w = fmaf(x.w, sc4.w, sh4.w);
        *(float4*)&sm[HS0 + r*132 + e4] = x;
    }
    float hacc[5][8];
    #pragma unroll
    for (int i=0;i<5;i++){
        #pragma unroll
        for (int k=0;k<8;k++) hacc[i][k]=0.0f;
    }

    const float* Wl = in_w + (size_t)l*384*EE;
    const float* Bl = in_b + (size_t)l*384;
    const float* OwTl = owT + (size_t)l*EE*EE;
    int nb = t/12, cb = t - nb*12;
    int wv_ = t>>6, lw = t&63;
    int g3 = lw/3, th3 = lw - g3*3;
    int rA = wv_*21 + g3;
    bool actA = (lw<63) && (rA<150);
    int nb5 = t>>4, ebx = t&15;

    for (int hd=0; hd<8; hd++){
        __syncthreads();
        for (int j=t; j<48*32; j+=512){
            int row=j>>5, e4=(j&31)*4;
            int which=row>>4, d=row&15;
            int grow = which*EE + hd*16 + d;
            float4 w4 = *(const float4*)(Wl + (size_t)grow*EE + e4);
            *(float4*)&sm[WS0 + row*132 + e4] = w4;
        }
        for (int j=t; j<16*32; j+=512){
            int d=j>>5, e4=(j&31)*4;
            float4 o4 = *(const float4*)(OwTl + (size_t)(hd*16+d)*EE + e4);
            *(float4*)&sm[OWS0 + d*132 + e4] = o4;
        }
        if (t<48){ int which=t>>4, d=t&15; sm[BIA0+t] = Bl[which*EE + hd*16 + d]; }
        __syncthreads();

        if (t<456){
            float acc[4][4];
            #pragma unroll
            for (int i=0;i<4;i++){
                #pragma unroll
                for (int j=0;j<4;j++) acc[i][j]=sm[BIA0+cb*4+j];
            }
            const float* hp0 = &sm[HS0 + nb*4*132];
            const float* wp0 = &sm[WS0 + cb*4*132];
            for (int e2=0;e2<64;e2++){
                float2 h0=*(const float2*)(hp0 + 2*e2);
                float2 h1=*(const float2*)(hp0 + 132 + 2*e2);
                float2 h2=*(const float2*)(hp0 + 264 + 2*e2);
                float2 h3=*(const float2*)(hp0 + 396 + 2*e2);
                float2 w0=*(const float2*)(wp0 + 2*e2);
                float2 w1=*(const float2*)(wp0 + 132 + 2*e2);
                float2 w2=*(const float2*)(wp0 + 264 + 2*e2);
                float2 w3=*(const float2*)(wp0 + 396 + 2*e2);
                acc[0][0]=fmaf(h0.y,w0.y,fmaf(h0.x,w0.x,acc[0][0]));
                acc[0][1]=fmaf(h0.y,w1.y,fmaf(h0.x,w1.x,acc[0][1]));
                acc[0][2]=fmaf(h0.y,w2.y,fmaf(h0.x,w2.x,acc[0][2]));
                acc[0][3]=fmaf(h0.y,w3.y,fmaf(h0.x,w3.x,acc[0][3]));
                acc[1][0]=fmaf(h1.y,w0.y,fmaf(h1.x,w0.x,acc[1][0]));
                acc[1][1]=fmaf(h1.y,w1.y,fmaf(h1.x,w1.x,acc[1][1]));
                acc[1][2]=fmaf(h1.y,w2.y,fmaf(h1.x,w2.x,acc[1][2]));
                acc[1][3]=fmaf(h1.y,w3.y,fmaf(h1.x,w3.x,acc[1][3]));
                acc[2][0]=fmaf(h2.y,w0.y,fmaf(h2.x,w0.x,acc[2][0]));
                acc[2][1]=fmaf(h2.y,w1.y,fmaf(h2.x,w1.x,acc[2][1]));
                acc[2][2]=fmaf(h2.y,w2.y,fmaf(h2.x,w2.x,acc[2][2]));
                acc[2][3]=fmaf(h2.y,w3.y,fmaf(h2.x,w3.x,acc[2][3]));
                acc[3][0]=fmaf(h3.y,w0.y,fmaf(h3.x,w0.x,acc[3][0]));
                acc[3][1]=fmaf(h3.y,w1.y,fmaf(h3.x,w1.x,acc[3][1]));
                acc[3][2]=fmaf(h3.y,w2.y,fmaf(h3.x,w2.x,acc[3][2]));
                acc[3][3]=fmaf(h3.y,w3.y,fmaf(h3.x,w3.x,acc[3][3]));
            }
            #pragma unroll
            for (int i=0;i<4;i++){
                int n=nb*4+i;
                if (n<150){
                    #pragma unroll
                    for (int j=0;j<4;j++){
                        int c=cb*4+j;
                        sm[QKV0 + (c>>4)*2400 + n*16 + (c&15)] = acc[i][j];
                    }
                }
            }
        }
        __syncthreads();

        {
            float o[16];
            #pragma unroll
            for (int i=0;i<16;i++) o[i]=0.0f;
            float ls=0.0f;
            if (actA){
                float4 q0=*(const float4*)&sm[QKV0 + rA*16 + 0];
                float4 q1=*(const float4*)&sm[QKV0 + rA*16 + 4];
                float4 q2=*(const float4*)&sm[QKV0 + rA*16 + 8];
                float4 q3=*(const float4*)&sm[QKV0 + rA*16 + 12];
                int k0=th3*50;
                for (int kk=k0; kk<k0+50; kk++){
                    const float* kb=&sm[QKV0+2400 + kk*16];
                    float4 ka=*(const float4*)kb;
                    float4 kb4=*(const float4*)(kb+4);
                    float4 kc=*(const float4*)(kb+8);
                    float4 kd=*(const float4*)(kb+12);
                    float s = q0.x*ka.x;
                    s=fmaf(q0.y,ka.y,s); s=fmaf(q0.z,ka.z,s); s=fmaf(q0.w,ka.w,s);
                    s=fmaf(q1.x,kb4.x,s); s=fmaf(q1.y,kb4.y,s); s=fmaf(q1.z,kb4.z,s); s=fmaf(q1.w,kb4.w,s);
                    s=fmaf(q2.x,kc.x,s); s=fmaf(q2.y,kc.y,s); s=fmaf(q2.z,kc.z,s); s=fmaf(q2.w,kc.w,s);
                    s=fmaf(q3.x,kd.x,s); s=fmaf(q3.y,kd.y,s); s=fmaf(q3.z,kd.z,s); s=fmaf(q3.w,kd.w,s);
                    float p=__expf(s*0.25f);
                    ls+=p;
                    const float* vb=&sm[QKV0+4800 + kk*16];
                    float4 va=*(const float4*)vb;
                    float4 v1=*(const float4*)(vb+4);
                    float4 v2=*(const float4*)(vb+8);
                    float4 v3=*(const float4*)(vb+12);
                    o[0]=fmaf(p,va.x,o[0]); o[1]=fmaf(p,va.y,o[1]); o[2]=fmaf(p,va.z,o[2]); o[3]=fmaf(p,va.w,o[3]);
                    o[4]=fmaf(p,v1.x,o[4]); o[5]=fmaf(p,v1.y,o[5]); o[6]=fmaf(p,v1.z,o[6]); o[7]=fmaf(p,v1.w,o[7]);
                    o[8]=fmaf(p,v2.x,o[8]); o[9]=fmaf(p,v2.y,o[9]); o[10]=fmaf(p,v2.z,o[10]); o[11]=fmaf(p,v2.w,o[11]);
                    o[12]=fmaf(p,v3.x,o[12]); o[13]=fmaf(p,v3.y,o[13]); o[14]=fmaf(p,v3.z,o[14]); o[15]=fmaf(p,v3.w,o[15]);
                }
            }
            float ls1=__shfl_down(ls,1), ls2=__shfl_down(ls,2);
            float oc[16];
            #pragma unroll
            for (int i=0;i<16;i++){
                float a1=__shfl_down(o[i],1), a2=__shfl_down(o[i],2);
                oc[i]=(o[i]+a1)+a2;
            }
            if (actA && th3==0){
                float inv = 1.0f/((ls+ls1)+ls2);
                #pragma unroll
                for (int d=0;d<16;d++) sm[OH0 + rA*17 + d] = oc[d]*inv;
            }
        }
        __syncthreads();

        if (t<480){
            #pragma unroll
            for (int d=0; d<16; d++){
                float4 w0=*(const float4*)&sm[OWS0 + d*132 + ebx*8];
                float4 w1=*(const float4*)&sm[OWS0 + d*132 + ebx*8 + 4];
                #pragma unroll
                for (int i=0;i<5;i++){
                    float ov = sm[OH0 + (nb5*5+i)*17 + d];
                    hacc[i][0]=fmaf(ov,w0.x,hacc[i][0]);
                    hacc[i][1]=fmaf(ov,w0.y,hacc[i][1]);
                    hacc[i][2]=fmaf(ov,w0.z,hacc[i][2]);
                    hacc[i][3]=fmaf(ov,w0.w,hacc[i][3]);
                    hacc[i][4]=fmaf(ov,w1.x,hacc[i][4]);
                    hacc[i][5]=fmaf(ov,w1.y,hacc[i][5]);
                    hacc[i][6]=fmaf(ov,w1.z,hacc[i][6]);
                    hacc[i][7]=fmaf(ov,w1.w,hacc[i][7]);
                }
            }
        }
    }
    __syncthreads();
    if (t<480){
        float ob[8];
        *(float4*)&ob[0] = *(const float4*)(out_b + l*EE + ebx*8);
        *(float4*)&ob[4] = *(const float4*)(out_b + l*EE + ebx*8 + 4);
        float cs[8], cq[8];
        #pragma unroll
        for (int k=0;k<8;k++){ cs[k]=0.0f; cq[k]=0.0f; }
        #pragma unroll
        for (int i=0;i<5;i++){
            int r=nb5*5+i;
            float x[8];
            #pragma unroll
            for (int k2=0;k2<4;k2++){
                float2 hv=*(const float2*)&sm[HS0 + r*132 + ebx*8 + 2*k2];
                x[2*k2]   = hv.x + ob[2*k2]   + hacc[i][2*k2];
                x[2*k2+1] = hv.y + ob[2*k2+1] + hacc[i][2*k2+1];
            }
            h_store4(h + hbase + (size_t)r*EE + ebx*8,     make_float4(x[0],x[1],x[2],x[3]));
            h_store4(h + hbase + (size_t)r*EE + ebx*8 + 4, make_float4(x[4],x[5],x[6],x[7]));
            #pragma unroll
            for (int k=0;k<8;k++){ cs[k]+=x[k]; cq[k]+=x[k]*x[k]; }
        }
        #pragma unroll
        for (int k=0;k<8;k++){
            sm[PS0 + nb5*128 + ebx*8 + k]=cs[k];
            sm[PQ0 + nb5*128 + ebx*8 + k]=cq[k];
        }
    }
    __syncthreads();
    if (t<256){
        int e=t&127, hf=t>>7;
        float s=0.0f,q=0.0f;
        for (int nb_=hf*15; nb_<hf*15+15; nb_++){
            s+=sm[PS0+nb_*128+e]; q+=sm[PQ0+nb_*128+e];
        }
        sm[RS0+t]=s; sm[RQ0+t]=q;
    }
    __syncthreads();
    if (t<128){
        part[(size_t)b*256 + t]       = sm[RS0+t]+sm[RS0+128+t];
        part[(size_t)b*256 + 128 + t] = sm[RQ0+t]+sm[RQ0+128+t];
    }
}

// ---------------- fused FFN + residual + bn2 stats ----------------
template<typename HT>
__global__ void k_ff(HT* __restrict__ h,
                     const float* __restrict__ w1, const float* __restrict__ b1,
                     const float* __restrict__ w2, const float* __restrict__ b2,
                     int l, float* __restrict__ part,
                     const float* __restrict__ scal, const float* __restrict__ shft){
    int bx=blockIdx.x, t=threadIdx.x;
    int row0=bx*16;
    __shared__ __align__(16) float xn[16][EE];
    __shared__ __align__(16) float f1[16][FFD];
    __shared__ float w2T[64][EE+1];
    const float* W1 = w1 + (size_t)l*FFD*EE;
    const float* W2 = w2 + (size_t)l*EE*FFD;
    for (int j=t;j<16*EE;j+=256){
        int r=j>>7,e=j&127;
        xn[r][e]=fmaf(h_load(h + (size_t)(row0+r)*EE+e), scal[e], shft[e]);
    }
    __syncthreads();
    for (int fi=0;fi<2;fi++){
        int f=t+fi*256;
        const float4* wr = (const float4*)(W1 + (size_t)f*EE);
        float bias = b1[l*FFD+f];
        float acc[16];
        #pragma unroll
        for (int r=0;r<16;r++) acc[r]=bias;
        for (int e4=0;e4<32;e4++){
            float4 w=wr[e4];
            #pragma unroll
            for (int r=0;r<16;r++){
                float4 x=*(const float4*)&xn[r][4*e4];
                acc[r] += x.x*w.x + x.y*w.y + x.z*w.z + x.w*w.w;
            }
        }
        #pragma unroll
        for (int r=0;r<16;r++) f1[r][f]=fmaxf(acc[r],0.0f);
    }
    int e=t&127, rh=t>>7;
    float acc2[8];
    #pragma unroll
    for (int i=0;i<8;i++) acc2[i]=0.0f;
    for (int fc=0; fc<FFD; fc+=64){
        __syncthreads();
        for (int j=t;j<64*EE;j+=256){ int e_=j>>6, fl=j&63; w2T[fl][e_]=W2[(size_t)e_*FFD+fc+fl]; }
        __syncthreads();
        for (int fl=0;fl<64;fl++){
            float w=w2T[fl][e];
            #pragma unroll
            for (int i=0;i<8;i++) acc2[i] = fmaf(f1[rh*8+i][fc+fl], w, acc2[i]);
        }
    }
    float bias = b2[l*EE+e];
    float s=0.0f,q=0.0f;
    #pragma unroll
    for (int i=0;i<8;i++){
        float x = xn[rh*8+i][e] + bias + acc2[i];
        h_store(h + (size_t)(row0+rh*8+i)*EE+e, x);
        s+=x; q+=x*x;
    }
    __shared__ float rs[256], rq[256];
    rs[t]=s; rq[t]=q; __syncthreads();
    if (rh==0){
        part[(size_t)bx*256+e]=rs[t]+rs[t+128];
        part[(size_t)bx*256+128+e]=rq[t]+rq[t+128];
    }
}

// ---------------- G_ih precompute ----------------
template<typename HT>
__launch_bounds__(512)
__global__ void k_gih(const HT* __restrict__ h, const float* __restrict__ wihT,
                      const float* __restrict__ scal, const float* __restrict__ shft,
                      float* __restrict__ G, int b0){
    __shared__ float xn[NN][132];
    int bl = blockIdx.x, t = threadIdx.x;
    const size_t hbase = (size_t)(b0+bl)*NN*EE;
    for (int j=t; j<NN*32; j+=512){
        int r=j>>5, e4=(j&31)*4;
        float4 x = h_load4(h + hbase + (size_t)r*EE + e4);
        float4 sc4=*(const float4*)(scal+e4), sh4=*(const float4*)(shft+e4);
        x.x=fmaf(x.x,sc4.x,sh4.x); x.y=fmaf(x.y,sc4.y,sh4.y);
        x.z=fmaf(x.z,sc4.z,sh4.z); x.w=fmaf(x.w,sc4.w,sh4.w);
        *(float4*)&xn[r][e4]=x;
    }
    __syncthreads();
    float* Gb = G + (size_t)bl*NN*512;
    const float* wcol = wihT + t;
    for (int nb=0; nb<10; nb++){
        float acc[15];
        #pragma unroll
        for (int j=0;j<15;j++) acc[j]=0.0f;
        #pragma unroll 4
        for (int e=0;e<128;e++){
            float w = wcol[(size_t)e*512];
            #pragma unroll
            for (int j=0;j<15;j++) acc[j]=fmaf(xn[nb*15+j][e], w, acc[j]);
        }
        #pragma unroll
        for (int j=0;j<15;j++) Gb[(size_t)(nb*15+j)*512+t]=acc[j];
    }
}

// ---------------- shared decoder LDS layout ----------------
#define EWQ    19200
#define DGTS   38400
#define D_DD   39424
#define D_HH   39680
#define D_HW2  39936
#define D_PVS  40192
#define D_SCS  40320
#define D_SHS  40448
#define D_TOT  40576

// ---------------- decoder v2i (fallback, ws mid) ----------------
template<typename HT>
__launch_bounds__(1024,4)
__global__ void k_decoder2(const HT* __restrict__ enc, const float* __restrict__ inp,
        const float* __restrict__ wih_p, const float* __restrict__ whh_p,
        const float* __restrict__ bih, const float* __restrict__ bhh,
        const float* __restrict__ pw1T, const float* __restrict__ pb1,
        const float* __restrict__ pw2T, const float* __restrict__ pb2,
        const float* __restrict__ pv, const float* __restrict__ pbv,
        const float* __restrict__ scal, const float* __restrict__ shft,
        float* __restrict__ out){
    __shared__ float smf[D_TOT];
    __shared__ unsigned char schna[608];
    const int t = threadIdx.x;
    const int q = t>>9, r = t&511;
    const int b0 = blockIdx.x*2;
    const HT* encq = enc + (size_t)(b0+q)*NN*EE;

    if (t<128){ smf[D_PVS+t]=pv[t]; smf[D_SCS+t]=scal[t]; smf[D_SHS+t]=shft[t]; }
    if (t<512) smf[D_DD+t]=0.0f;
    if (t<304){
        int qq=t/152, n=t-qq*152;
        schna[qq*304+n]=0;
        unsigned char nav=1;
        if (n<150) nav = (inp[((size_t)(b0+qq)*NN+n)*4+1] != 0.0f) ? 1 : 0;
        schna[qq*304+152+n]=nav;
    }
    const int g = t>>1, kh = t&1;
    const float bsum = bih[g] + bhh[g];
    const float pb2r = (t<256) ? pb2[t&127] : 0.0f;
    const float pbvr = pbv[0];

    float4 whr[16];
    {
        const float4* wp = (const float4*)whh_p + t;
        #pragma unroll
        for (int i=0;i<16;i++) whr[i] = wp[(size_t)i*1024];
    }
    __syncthreads();

    {
        const int e = r&127, ng = r>>7;
        const float pb1e = pb1[e];
        for (int n1 = ng; n1 < 150; n1 += 8){
            int n2 = n1+4;
            bool has2 = (n2<150);
            int n2c = has2 ? n2 : n1;
            float a1=0.0f, a2=0.0f;
            #pragma unroll 4
            for (int e2=0;e2<EE;e2++){
                float w = pw1T[e2*EE + e];
                float x1 = fmaf(smf[D_SCS+e2], h_load(encq + (size_t)n1*EE + e2), smf[D_SHS+e2]);
                float x2 = fmaf(smf[D_SCS+e2], h_load(encq + (size_t)n2c*EE + e2), smf[D_SHS+e2]);
                a1 = fmaf(x1, w, a1);
                a2 = fmaf(x2, w, a2);
            }
            smf[q*EWQ + n1*128 + (e ^ (n1&31))] = a1 + pb1e;
            if (has2) smf[q*EWQ + n2*128 + (e ^ (n2&31))] = a2 + pb1e;
        }
    }
    if (t<512){
        int qq=t>>8, rr=t&255, e=rr&127, hf=rr>>7;
        const HT* eb = enc + (size_t)(b0+qq)*NN*EE;
        float s=0.0f;
        for (int n=hf*75;n<hf*75+75;n++) s += h_load(eb + (size_t)n*EE+e);
        smf[DGTS + qq*256 + hf*128 + e] = s;
    }
    __syncthreads();
    float c_reg = 0.0f;
    if (t<256){
        int qq=t>>7, e=t&127;
        float mean = (smf[DGTS+qq*256+e]+smf[DGTS+qq*256+128+e])*(1.0f/150.0f);
        c_reg = fmaf(smf[D_SCS+e], mean, smf[D_SHS+e]);
    }
    __syncthreads();

    float llacc=0.0f;
    const float4* wip = (const float4*)wih_p + t;
    for (int step=0; step<NN; step++){
        {
            float a0=0.0f, a1=0.0f;
            const float* d0 = &smf[D_DD + kh*64];
            const float* d1 = &smf[D_DD + 128 + kh*64];
            const float* h0 = &smf[D_HH + kh*64];
            const float* h1 = &smf[D_HH + 128 + kh*64];
            #pragma unroll 8
            for (int i=0;i<16;i++){
                float4 wv = wip[(size_t)i*1024];
                float4 wh = whr[i];
                float4 x0 = *(const float4*)(d0 + 4*i);
                float4 x1 = *(const float4*)(d1 + 4*i);
                float4 y0 = *(const float4*)(h0 + 4*i);
                float4 y1 = *(const float4*)(h1 + 4*i);
                a0 = fmaf(wv.w,x0.w,fmaf(wv.z,x0.z,fmaf(wv.y,x0.y,fmaf(wv.x,x0.x,a0))));
                a0 = fmaf(wh.w,y0.w,fmaf(wh.z,y0.z,fmaf(wh.y,y0.y,fmaf(wh.x,y0.x,a0))));
                a1 = fmaf(wv.w,x1.w,fmaf(wv.z,x1.z,fmaf(wv.y,x1.y,fmaf(wv.x,x1.x,a1))));
                a1 = fmaf(wh.w,y1.w,fmaf(wh.z,y1.z,fmaf(wh.y,y1.y,fmaf(wh.x,y1.x,a1))));
            }
            a0 += __shfl_xor(a0,1);
            a1 += __shfl_xor(a1,1);
            if (kh==0){
                smf[DGTS + g]       = a0 + bsum;
                smf[DGTS + 512 + g] = a1 + bsum;
            }
        }
        __syncthreads();
        if (t<256){
            int qq=t>>7, e=t&127;
            const float* gt = &smf[DGTS + qq*512];
            float gi=fsig(gt[e]), gf=fsig(gt[128+e]), gg=ftanh(gt[256+e]), go=fsig(gt[384+e]);
            c_reg = gf*c_reg + gi*gg;
            smf[D_HH + qq*128 + e] = go*ftanh(c_reg);
        }
        __syncthreads();
        if (t<256){
            int qq=t>>7, e=t&127;
            float s2=0.0f;
            #pragma unroll 4
            for (int e2=0;e2<EE;e2++)
                s2 = fmaf(pw2T[e2*EE + e], smf[D_HH + qq*128 + e2], s2);
            smf[D_HW2 + qq*128 + e] = s2 + pb2r;
        }
        __syncthreads();
        {
            int half = r>>8, n = r&255;
            if (n<150){
                float p=0.0f;
                const float* ewn = &smf[q*EWQ + n*128];
                const float* hwq = &smf[D_HW2 + q*128];
                int sw = n&31;
                #pragma unroll 8
                for (int e2=0;e2<64;e2++){
                    int e = half*64+e2;
                    p = fmaf(ftanh(ewn[e ^ sw] + hwq[e]), smf[D_PVS+e], p);
                }
                smf[DGTS + (q*2+half)*152 + n] = p;
            }
        }
        __syncthreads();
        if (t<128){
            int qq=t>>6, l=t&63;
            const unsigned char* sc_ = &schna[qq*304];
            const float* pp = &smf[DGTS + qq*2*152];
            int n0=l, n1=l+64, n2=l+128;
            float a0 = pp[n0]+pp[152+n0]+pbvr;
            float a1 = pp[n1]+pp[152+n1]+pbvr;
            float v0 = (sc_[n0]|sc_[152+n0]) ? -10000.0f : a0;
            float v1 = (sc_[n1]|sc_[152+n1]) ? -10000.0f : a1;
            float v2 = -1e30f;
            if (n2<NN){
                float a2 = pp[n2]+pp[152+n2]+pbvr;
                v2 = (sc_[n2]|sc_[152+n2]) ? -10000.0f : a2;
            }
            float m=v0; int mi=n0;
            if (v1>m){ m=v1; mi=n1; }
            if (n2<NN && v2>m){ m=v2; mi=n2; }
            #pragma unroll
            for (int off=1; off<64; off<<=1){
                float om=__shfl_xor(m,off); int oi=__shfl_xor(mi,off);
                if (om>m || (om==m && oi<mi)){ m=om; mi=oi; }
            }
            float se = __expf(v0-m)+__expf(v1-m) + ((n2<NN)? __expf(v2-m):0.0f);
            #pragma unroll
            for (int off=1; off<64; off<<=1) se += __shfl_xor(se,off);
            const HT* eb = enc + (size_t)(b0+qq)*NN*EE;
            if (l==0){
                llacc -= logf(se);
                schna[qq*304+mi]=1;
                int nn2 = mi+1; if (nn2>NN-1) nn2=NN-1;
                schna[qq*304+152+nn2]=0;
                float4 rowv = *(const float4*)(inp + ((size_t)(b0+qq)*NN+mi)*4);
                *(float4*)(out + ((size_t)(b0+qq)*NN+step)*4) = rowv;
            }
            float eva = h_load(eb + (size_t)mi*EE + l);
            float evb = h_load(eb + (size_t)mi*EE + l + 64);
            smf[D_DD + qq*128 + l]      = fmaf(smf[D_SCS+l],    eva, smf[D_SHS+l]);
            smf[D_DD + qq*128 + l + 64] = fmaf(smf[D_SCS+l+64], evb, smf[D_SHS+l+64]);
        }
        __syncthreads();
    }
    if (t==0)  out[(size_t)BB*NN*4 + b0]   = llacc;
    if (t==64) out[(size_t)BB*NN*4 + b0+1] = llacc;
}

// ---------------- decoder G5: 1024 threads (decoder2 structure), G-lookup, streamed Whh only ----------------
template<typename HT>
__launch_bounds__(1024,4)
__global__ void k_decoderG5(const HT* __restrict__ enc, const float* __restrict__ inp,
        const float* __restrict__ whh_p, const float* __restrict__ Gih,
        const float* __restrict__ bih, const float* __restrict__ bhh,
        const float* __restrict__ pw1T, const float* __restrict__ pb1,
        const float* __restrict__ pw2T, const float* __restrict__ pb2,
        const float* __restrict__ pv, const float* __restrict__ pbv,
        const float* __restrict__ scal, const float* __restrict__ shft,
        float* __restrict__ out, int passb0){
    __shared__ float smf[D_TOT];
    __shared__ unsigned char schna[608];
    __shared__ int predS2[2];
    const int t = threadIdx.x;
    const int q = t>>9, r = t&511;
    const int b0 = passb0 + blockIdx.x*2;
    const HT* encq = enc + (size_t)(b0+q)*NN*EE;

    if (t<128){ smf[D_PVS+t]=pv[t]; smf[D_SCS+t]=scal[t]; smf[D_SHS+t]=shft[t]; }
    if (t<256) smf[D_HH+t]=0.0f;
    if (t<304){
        int qq=t/152, n=t-qq*152;
        schna[qq*304+n]=0;
        unsigned char nav=1;
        if (n<150) nav = (inp[((size_t)(b0+qq)*NN+n)*4+1] != 0.0f) ? 1 : 0;
        schna[qq*304+152+n]=nav;
    }
    if (t<2) predS2[t]=-1;
    const int g = t>>1, kh = t&1;
    const float bsum = bih[g] + bhh[g];
    const float pb2r = (t<256) ? pb2[t&127] : 0.0f;
    const float pbvr = pbv[0];
    __syncthreads();

    // ew = bn(enc) @ pw1^T + pb1 (XOR-swizzled)
    {
        const int e = r&127, ng = r>>7;
        const float pb1e = pb1[e];
        for (int n1 = ng; n1 < 150; n1 += 8){
            int n2 = n1+4;
            bool has2 = (n2<150);
            int n2c = has2 ? n2 : n1;
            float a1=0.0f, a2=0.0f;
            #pragma unroll 4
            for (int e2=0;e2<EE;e2++){
                float w = pw1T[e2*EE + e];
                float x1 = fmaf(smf[D_SCS+e2], h_load(encq + (size_t)n1*EE + e2), smf[D_SHS+e2]);
                float x2 = fmaf(smf[D_SCS+e2], h_load(encq + (size_t)n2c*EE + e2), smf[D_SHS+e2]);
                a1 = fmaf(x1, w, a1);
                a2 = fmaf(x2, w, a2);
            }
            smf[q*EWQ + n1*128 + (e ^ (n1&31))] = a1 + pb1e;
            if (has2) smf[q*EWQ + n2*128 + (e ^ (n2&31))] = a2 + pb1e;
        }
    }
    if (t<512){
        int qq=t>>8, rr=t&255, e=rr&127, hf=rr>>7;
        const HT* eb = enc + (size_t)(b0+qq)*NN*EE;
        float s=0.0f;
        for (int n=hf*75;n<hf*75+75;n++) s += h_load(eb + (size_t)n*EE+e);
        smf[DGTS + qq*256 + hf*128 + e] = s;
    }
    __syncthreads();
    float c_reg = 0.0f;
    if (t<256){
        int qq=t>>7, e=t&127;
        float mean = (smf[DGTS+qq*256+e]+smf[DGTS+qq*256+128+e])*(1.0f/150.0f);
        c_reg = fmaf(smf[D_SCS+e], mean, smf[D_SHS+e]);
    }
    __syncthreads();

    float llacc=0.0f;
    const float* Gb0 = Gih + (size_t)(blockIdx.x*2)*NN*512;
    const float* Gb1 = Gih + (size_t)(blockIdx.x*2+1)*NN*512;
    const float4* whp = (const float4*)whh_p + t;
    for (int step=0; step<NN; step++){
        // A. gates: streamed Whh half-dot x hh (both batches), shfl-combine; kh==0 adds G lookup
        {
            float a0=0.0f, a1=0.0f;
            const float* h0 = &smf[D_HH + kh*64];
            const float* h1 = &smf[D_HH + 128 + kh*64];
            #pragma unroll 8
            for (int i=0;i<16;i++){
                float4 wh = whp[(size_t)i*1024];
                float4 y0 = *(const float4*)(h0 + 4*i);
                float4 y1 = *(const float4*)(h1 + 4*i);
                a0 = fmaf(wh.w,y0.w,fmaf(wh.z,y0.z,fmaf(wh.y,y0.y,fmaf(wh.x,y0.x,a0))));
                a1 = fmaf(wh.w,y1.w,fmaf(wh.z,y1.z,fmaf(wh.y,y1.y,fmaf(wh.x,y1.x,a1))));
            }
            a0 += __shfl_xor(a0,1);
            a1 += __shfl_xor(a1,1);
            if (kh==0){
                int p0=predS2[0], p1=predS2[1];
                float ga = (p0>=0) ? Gb0[(size_t)p0*512 + g] : 0.0f;
                float gb = (p1>=0) ? Gb1[(size_t)p1*512 + g] : 0.0f;
                smf[DGTS + g]       = a0 + bsum + ga;
                smf[DGTS + 512 + g] = a1 + bsum + gb;
            }
        }
        __syncthreads();
        // B. LSTM cell
        if (t<256){
            int qq=t>>7, e=t&127;
            const float* gt = &smf[DGTS + qq*512];
            float gi=fsig(gt[e]), gf=fsig(gt[128+e]), gg=ftanh(gt[256+e]), go=fsig(gt[384+e]);
            c_reg = gf*c_reg + gi*gg;
            smf[D_HH + qq*128 + e] = go*ftanh(c_reg);
        }
        __syncthreads();
        // C. hw2 = hh @ pw2^T + pb2
        if (t<256){
            int qq=t>>7, e=t&127;
            float s2=0.0f;
            #pragma unroll 4
            for (int e2=0;e2<EE;e2++)
                s2 = fmaf(pw2T[e2*EE + e], smf[D_HH + qq*128 + e2], s2);
            smf[D_HW2 + qq*128 + e] = s2 + pb2r;
        }
        __syncthreads();
        // D. pointer logits
        {
            int half = r>>8, n = r&255;
            if (n<150){
                float p=0.0f;
                const float* ewn = &smf[q*EWQ + n*128];
                const float* hwq = &smf[D_HW2 + q*128];
                int sw = n&31;
                #pragma unroll 8
                for (int e2=0;e2<64;e2++){
                    int e = half*64+e2;
                    p = fmaf(ftanh(ewn[e ^ sw] + hwq[e]), smf[D_PVS+e], p);
                }
                smf[DGTS + (q*2+half)*152 + n] = p;
            }
        }
        __syncthreads();
        // E. argmax + lse + state update (no dd gather; record pred)
        if (t<128){
            int qq=t>>6, l=t&63;
            const unsigned char* sc_ = &schna[qq*304];
            const float* pp = &smf[DGTS + qq*2*152];
            int n0=l, n1=l+64, n2=l+128;
            float a0 = pp[n0]+pp[152+n0]+pbvr;
            float a1 = pp[n1]+pp[152+n1]+pbvr;
            float v0 = (sc_[n0]|sc_[152+n0]) ? -10000.0f : a0;
            float v1 = (sc_[n1]|sc_[152+n1]) ? -10000.0f : a1;
            float v2 = -1e30f;
            if (n2<NN){
                float a2 = pp[n2]+pp[152+n2]+pbvr;
                v2 = (sc_[n2]|sc_[152+n2]) ? -10000.0f : a2;
            }
            float m=v0; int mi=n0;
            if (v1>m){ m=v1; mi=n1; }
            if (n2<NN && v2>m){ m=v2; mi=n2; }
            #pragma unroll
            for (int off=1; off<64; off<<=1){
                float om=__shfl_xor(m,off); int oi=__shfl_xor(mi,off);
                if (om>m || (om==m && oi<mi)){ m=om; mi=oi; }
            }
            float se = __expf(v0-m)+__expf(v1-m) + ((n2<NN)? __expf(v2-m):0.0f);
            #pragma unroll
            for (int off=1; off<64; off<<=1) se += __shfl_xor(se,off);
            if (l==0){
                llacc -= logf(se);
                predS2[qq]=mi;
                schna[qq*304+mi]=1;
                int nn2 = mi+1; if (nn2>NN-1) nn2=NN-1;
                schna[qq*304+152+nn2]=0;
                float4 rowv = *(const float4*)(inp + ((size_t)(b0+qq)*NN+mi)*4);
                *(float4*)(out + ((size_t)(b0+qq)*NN+step)*4) = rowv;
            }
        }
        __syncthreads();
    }
    if (t==0)  out[(size_t)BB*NN*4 + b0]   = llacc;
    if (t==64) out[(size_t)BB*NN*4 + b0+1] = llacc;
}

// ---------------- host schedule ----------------
template<typename HT>
static void run_model(void* const* d_in, void* d_out, void* d_ws, bool big, hipStream_t stream){
    const float* inp   = (const float*)d_in[0];
    const float* opg   = (const float*)d_in[1];
    const float* opb   = (const float*)d_in[2];
    const float* opW   = (const float*)d_in[3];
    const float* opB   = (const float*)d_in[4];
    const float* mtg   = (const float*)d_in[5];
    const float* mtb   = (const float*)d_in[6];
    const float* mtW   = (const float*)d_in[7];
    const float* mtB   = (const float*)d_in[8];
    const float* e0g   = (const float*)d_in[9];
    const float* e0b   = (const float*)d_in[10];
    const float* in_w  = (const float*)d_in[11];
    const float* in_b  = (const float*)d_in[12];
    const float* out_w = (const float*)d_in[13];
    const float* out_b = (const float*)d_in[14];
    const float* bn1g  = (const float*)d_in[15];
    const float* bn1b  = (const float*)d_in[16];
    const float* ffw1  = (const float*)d_in[17];
    const float* ffb1  = (const float*)d_in[18];
    const float* ffw2  = (const float*)d_in[19];
    const float* ffb2  = (const float*)d_in[20];
    const float* bn2g  = (const float*)d_in[21];
    const float* bn2b  = (const float*)d_in[22];
    const float* Wih   = (const float*)d_in[23];
    const float* Whh   = (const float*)d_in[24];
    const float* bihp  = (const float*)d_in[25];
    const float* bhhp  = (const float*)d_in[26];
    const float* pw1   = (const float*)d_in[27];
    const float* pb1   = (const float*)d_in[28];
    const float* pw2   = (const float*)d_in[29];
    const float* pb2   = (const float*)d_in[30];
    const float* pv    = (const float*)d_in[31];
    const float* pbv   = (const float*)d_in[32];
    float* out = (float*)d_out;

    HT* h = (HT*)d_ws;
    float* Xf = (float*)((char*)d_ws + (size_t)RTOT*EE*sizeof(HT));
    float* part  = Xf;                    // 2457600
    float* cwcb  = Xf + 2457600;          // 640
    float* scal  = cwcb + 640;
    float* shft  = scal + 128;
    float* wih_p = shft + 128;            // 65536
    float* whh_p = wih_p + 65536;         // 65536
    float* pw1T  = whh_p + 65536;         // 16384
    float* pw2Tg = pw1T + 16384;          // 16384
    float* owT   = pw2Tg + 16384;         // 49152
    float* part2 = owT + 49152;           // 15360
    float* wihT  = part2 + 15360;         // 65536 (big only)
    float* G     = wihT + 65536;          // 39,321,600 (big only)

    k_prep2<<<256,256,0,stream>>>(Wih, Whh, pw1, pw2, out_w, wih_p, whh_p, pw1T, pw2Tg, owT);
    if (big) k_prep3<<<256,256,0,stream>>>(Wih, wihT);
    k_inp_stats<<<600,256,0,stream>>>(inp, part);
    k_inp_final<<<1,128,0,stream>>>(part, opg,opb,opW,opB, mtg,mtb,mtW,mtB, cwcb);
    k_embed<HT><<<2400,256,0,stream>>>(inp, cwcb, h, part);
    k_bn_mid<<<60,256,0,stream>>>(part, 2400, part2);
    k_bn_fin<<<1,256,0,stream>>>(part2, e0g, e0b, scal, shft);
    for (int l=0;l<NL;l++){
        k_mha<HT><<<1024,512,0,stream>>>(h, in_w, in_b, owT, out_b, l, part, scal, shft);
        k_bn_mid<<<60,256,0,stream>>>(part, 1024, part2);
        k_bn_fin<<<1,256,0,stream>>>(part2, bn1g + l*EE, bn1b + l*EE, scal, shft);
        k_ff<HT><<<9600,256,0,stream>>>(h, ffw1, ffb1, ffw2, ffb2, l, part, scal, shft);
        k_bn_mid<<<60,256,0,stream>>>(part, 9600, part2);
        k_bn_fin<<<1,256,0,stream>>>(part2, bn2g + l*EE, bn2b + l*EE, scal, shft);
    }
    if (big){
        for (int pass=0; pass<2; pass++){
            k_gih<HT><<<512,512,0,stream>>>(h, wihT, scal, shft, G, pass*512);
            k_decoderG5<HT><<<256,1024,0,stream>>>(h, inp, whh_p, G, bihp, bhhp,
                                                   pw1T, pb1, pw2Tg, pb2, pv, pbv,
                                                   scal, shft, out, pass*512);
        }
    } else {
        k_decoder2<HT><<<512,1024,0,stream>>>(h, inp, wih_p, whh_p, bihp, bhhp,
                                              pw1T, pb1, pw2Tg, pb2, pv, pbv,
                                              scal, shft, out);
    }
}

extern "C" void kernel_launch(void* const* d_in, const int* in_sizes, int n_in,
                              void* d_out, int out_size, void* d_ws, size_t ws_size,
                              hipStream_t stream){
    const size_t xf_floats = 2457600u + 640 + 128 + 128 + 65536 + 65536 + 16384 + 16384 + 49152 + 15360;
    const size_t need_A   = (size_t)RTOT*EE*4 + xf_floats*4ull;
    const size_t need_big = need_A + (size_t)(65536 + 39321600)*4ull;
    if (ws_size >= need_big){
        run_model<float>(d_in, d_out, d_ws, true, stream);
    } else if (ws_size >= need_A){
        run_model<float>(d_in, d_out, d_ws, false, stream);
    } else {
        run_model<f16>(d_in, d_out, d_ws, false, stream);
    }
    (void)in_sizes; (void)n_in; (void)out_size; (void)ws_size;
}

// Round 13
// 9880.903 us; speedup vs baseline: 1.2632x; 1.1804x over previous
//
#include <hip/hip_runtime.h>
#include <math.h>

#define BB 1024
#define NN 150
#define RTOT (BB*NN)
#define EE 128
#define FFD 512
#define NL 3

typedef unsigned short u16;
typedef unsigned int u32;
typedef _Float16 f16;
typedef _Float16 f16x4 __attribute__((ext_vector_type(4)));

__device__ __forceinline__ float fsig(float x){ return __builtin_amdgcn_rcpf(1.0f + __expf(-x)); }
__device__ __forceinline__ float ftanh(float x){ return 1.0f - 2.0f*__builtin_amdgcn_rcpf(1.0f + __expf(2.0f*x)); }

// ---- h storage accessors ----
__device__ __forceinline__ float4 h_load4(const float* p){ return *(const float4*)p; }
__device__ __forceinline__ float4 h_load4(const f16* p){
    f16x4 v = *(const f16x4*)p;
    return make_float4((float)v.x,(float)v.y,(float)v.z,(float)v.w);
}
__device__ __forceinline__ void h_store4(float* p, float4 v){ *(float4*)p = v; }
__device__ __forceinline__ void h_store4(f16* p, float4 v){
    f16x4 o; o.x=(f16)v.x; o.y=(f16)v.y; o.z=(f16)v.z; o.w=(f16)v.w;
    *(f16x4*)p = o;
}
__device__ __forceinline__ float h_load(const float* p){ return *p; }
__device__ __forceinline__ float h_load(const f16* p){ return (float)*p; }
__device__ __forceinline__ void h_store(float* p, float v){ *p = v; }
__device__ __forceinline__ void h_store(f16* p, float v){ *p = (f16)v; }

// ---------------- prep: weight transposes/packs ----------------
__global__ void k_prep2(const float* __restrict__ Wih, const float* __restrict__ Whh,
                        const float* __restrict__ pw1, const float* __restrict__ pw2,
                        const float* __restrict__ out_w,
                        float* __restrict__ wih_p, float* __restrict__ whh_p,
                        float* __restrict__ pw1T, float* __restrict__ pw2T,
                        float* __restrict__ owT){
    int idx = blockIdx.x*256 + threadIdx.x;   // 65536 total
    {
        int f4 = idx>>2, c = idx&3;
        int i = f4>>10, tt = f4&1023;
        int g = tt>>1, kh = tt&1;
        int col = kh*64 + i*4 + c;
        wih_p[idx] = Wih[(size_t)g*128 + col];
        whh_p[idx] = Whh[(size_t)g*128 + col];
    }
    if (idx < 16384){
        int e = idx>>7, e2 = idx&127;
        pw1T[e2*128+e] = pw1[idx];
        pw2T[e2*128+e] = pw2[idx];
    }
    if (idx < 49152){
        int l = idx>>14, r = (idx>>7)&127, d = idx&127;
        owT[(size_t)l*16384 + d*128 + r] = out_w[idx];
    }
}

// big-ws extra: wihT[e][g] for the G GEMM
__global__ void k_prep3(const float* __restrict__ Wih, float* __restrict__ wihT){
    int idx = blockIdx.x*256 + threadIdx.x;   // 65536
    int g = idx>>7, e = idx&127;
    wihT[(size_t)e*512 + g] = Wih[idx];
}

// big-ws extra: FFN weight transposes into the (currently dead) G region
// w1T[l][e][f] = ffw1[l][f][e];  w2Tg[l][fl][e] = ffw2[l][e][fl]
__global__ void k_prep4(const float* __restrict__ ffw1, const float* __restrict__ ffw2,
                        float* __restrict__ w1T, float* __restrict__ w2Tg){
    int idx = blockIdx.x*256 + threadIdx.x;   // 196608
    int l = idx >> 16, r = idx & 65535;
    {
        int e = r>>9, f = r&511;
        w1T[idx] = ffw1[(size_t)l*65536 + (size_t)f*128 + e];
    }
    {
        int fl = r>>7, e2 = r&127;
        w2Tg[idx] = ffw2[(size_t)l*65536 + (size_t)e2*512 + fl];
    }
}

// ---------------- input 4-channel stats ----------------
__global__ void k_inp_stats(const float* __restrict__ inp, float* __restrict__ part){
    int t = threadIdx.x;
    int row = blockIdx.x*256 + t;
    float4 u = *(const float4*)(inp + (size_t)row*4);
    __shared__ float red[256][8];
    red[t][0]=u.x; red[t][1]=u.y; red[t][2]=u.z; red[t][3]=u.w;
    red[t][4]=u.x*u.x; red[t][5]=u.y*u.y; red[t][6]=u.z*u.z; red[t][7]=u.w*u.w;
    __syncthreads();
    for (int s=128;s>0;s>>=1){
        if (t<s){
            #pragma unroll
            for (int c=0;c<8;c++) red[t][c]+=red[t+s][c];
        }
        __syncthreads();
    }
    if (t<8) part[blockIdx.x*8+t] = red[0][t];
}

__global__ void k_inp_final(const float* __restrict__ part,
    const float* __restrict__ opg, const float* __restrict__ opb,
    const float* __restrict__ opW, const float* __restrict__ opB,
    const float* __restrict__ mtg, const float* __restrict__ mtb,
    const float* __restrict__ mtW, const float* __restrict__ mtB,
    float* __restrict__ cwcb){
    int t = threadIdx.x; // 128
    __shared__ float sc[4], oc[4];
    if (t<4){
        float s=0.0f,q=0.0f;
        for (int i=0;i<600;i++){ s+=part[i*8+t]; q+=part[i*8+4+t]; }
        float mean = s/(float)RTOT;
        float var  = q/(float)RTOT - mean*mean;
        float rstd = 1.0f/sqrtf(var+1e-5f);
        float g = (t<2)?opg[t]:mtg[t-2];
        float b = (t<2)?opb[t]:mtb[t-2];
        sc[t]=g*rstd; oc[t]=b-mean*g*rstd;
    }
    __syncthreads();
    float w0=opW[t*2], w1=opW[t*2+1];
    float w2=mtW[t*2], w3=mtW[t*2+1];
    float* o = cwcb + t*5;
    o[0]=sc[0]*w0; o[1]=sc[1]*w1; o[2]=sc[2]*w2; o[3]=sc[3]*w3;
    o[4]=opB[t]+mtB[t] + oc[0]*w0+oc[1]*w1+oc[2]*w2+oc[3]*w3;
}

// ---------------- embed + enc0 stats ----------------
template<typename HT>
__global__ void k_embed(const float* __restrict__ inp, const float* __restrict__ cwcb,
                        HT* __restrict__ h, float* __restrict__ part){
    int bx=blockIdx.x, t=threadIdx.x;
    int row0 = bx*64;
    __shared__ float xin[64][4];
    if (t<64){
        float4 u = *(const float4*)(inp + (size_t)(row0+t)*4);
        xin[t][0]=u.x; xin[t][1]=u.y; xin[t][2]=u.z; xin[t][3]=u.w;
    }
    int e=t&127, rh=t>>7;
    float c0=cwcb[e*5],c1=cwcb[e*5+1],c2=cwcb[e*5+2],c3=cwcb[e*5+3],cb=cwcb[e*5+4];
    __syncthreads();
    float s=0.0f,q=0.0f;
    for (int r=rh; r<64; r+=2){
        float x = cb + xin[r][0]*c0 + xin[r][1]*c1 + xin[r][2]*c2 + xin[r][3]*c3;
        h_store(h + (size_t)(row0+r)*EE + e, x);
        s+=x; q+=x*x;
    }
    __shared__ float rs[256], rq[256];
    rs[t]=s; rq[t]=q;
    __syncthreads();
    if (rh==0){
        part[(size_t)bx*256 + e]       = rs[t]+rs[t+128];
        part[(size_t)bx*256 + 128 + e] = rq[t]+rq[t+128];
    }
}

// ---------------- BN reduce cascade ----------------
__global__ void k_bn_mid(const float* __restrict__ part, int nblk, float* __restrict__ part2){
    int j=blockIdx.x, t=threadIdx.x;   // 60 blocks x 256
    float s=0.0f;
    for (int i=j;i<nblk;i+=60) s += part[(size_t)i*256+t];
    part2[j*256+t]=s;
}

__global__ void k_bn_fin(const float* __restrict__ part2,
                         const float* __restrict__ g, const float* __restrict__ b,
                         float* __restrict__ scale, float* __restrict__ shift){
    int t=threadIdx.x;  // 256
    float s=0.0f;
    for (int j=0;j<60;j++) s += part2[j*256+t];
    __shared__ float red[256];
    red[t]=s; __syncthreads();
    if (t<128){
        float ss=red[t], qq=red[128+t];
        float mean=ss/(float)RTOT, var=qq/(float)RTOT-mean*mean;
        float rstd=1.0f/sqrtf(var+1e-5f);
        float gg=g[t];
        scale[t]=gg*rstd; shift[t]=b[t]-mean*gg*rstd;
    }
}

// ---------------- fused MHA + out-proj + residual + bn1 stats ----------------
#define HS0   0
#define WS0   19800
#define QKV0  26136
#define OH0   33336
#define OWS0  35886
#define BIA0  37998
#define SMTOT 38046
#define PS0   QKV0
#define PQ0   (QKV0+3840)
#define RS0   OWS0
#define RQ0   (OWS0+256)

template<typename HT>
__launch_bounds__(512,1)
__global__ void k_mha(HT* __restrict__ h, const float* __restrict__ in_w,
                      const float* __restrict__ in_b, const float* __restrict__ owT,
                      const float* __restrict__ out_b, int l, float* __restrict__ part,
                      const float* __restrict__ scal, const float* __restrict__ shft){
    __shared__ float sm[SMTOT];
    int b = blockIdx.x, t = threadIdx.x;
    const size_t hbase = (size_t)b*NN*EE;

    for (int j=t; j<NN*32; j+=512){
        int r=j>>5, e4=(j&31)*4;
        float4 x = h_load4(h + hbase + (size_t)r*EE + e4);
        float4 sc4 = *(const float4*)(scal + e4);
        float4 sh4 = *(const float4*)(shft + e4);
        x.x = fmaf(x.x, sc4.x, sh4.x); x.y = fmaf(x.y, sc4.y, sh4.y);
        x.z = fmaf(x.z, sc4.z, sh4.z); x.w = fmaf(x.w, sc4.w, sh4.w);
        *(float4*)&sm[HS0 + r*132 + e4] = x;
    }
    float hacc[5][8];
    #pragma unroll
    for (int i=0;i<5;i++){
        #pragma unroll
        for (int k=0;k<8;k++) hacc[i][k]=0.0f;
    }

    const float* Wl = in_w + (size_t)l*384*EE;
    const float* Bl = in_b + (size_t)l*384;
    const float* OwTl = owT + (size_t)l*EE*EE;
    int nb = t/12, cb = t - nb*12;
    int wv_ = t>>6, lw = t&63;
    int g3 = lw/3, th3 = lw - g3*3;
    int rA = wv_*21 + g3;
    bool actA = (lw<63) && (rA<150);
    int nb5 = t>>4, ebx = t&15;

    for (int hd=0; hd<8; hd++){
        __syncthreads();
        for (int j=t; j<48*32; j+=512){
            int row=j>>5, e4=(j&31)*4;
            int which=row>>4, d=row&15;
            int grow = which*EE + hd*16 + d;
            float4 w4 = *(const float4*)(Wl + (size_t)grow*EE + e4);
            *(float4*)&sm[WS0 + row*132 + e4] = w4;
        }
        for (int j=t; j<16*32; j+=512){
            int d=j>>5, e4=(j&31)*4;
            float4 o4 = *(const float4*)(OwTl + (size_t)(hd*16+d)*EE + e4);
            *(float4*)&sm[OWS0 + d*132 + e4] = o4;
        }
        if (t<48){ int which=t>>4, d=t&15; sm[BIA0+t] = Bl[which*EE + hd*16 + d]; }
        __syncthreads();

        if (t<456){
            float acc[4][4];
            #pragma unroll
            for (int i=0;i<4;i++){
                #pragma unroll
                for (int j=0;j<4;j++) acc[i][j]=sm[BIA0+cb*4+j];
            }
            const float* hp0 = &sm[HS0 + nb*4*132];
            const float* wp0 = &sm[WS0 + cb*4*132];
            for (int e2=0;e2<64;e2++){
                float2 h0=*(const float2*)(hp0 + 2*e2);
                float2 h1=*(const float2*)(hp0 + 132 + 2*e2);
                float2 h2=*(const float2*)(hp0 + 264 + 2*e2);
                float2 h3=*(const float2*)(hp0 + 396 + 2*e2);
                float2 w0=*(const float2*)(wp0 + 2*e2);
                float2 w1=*(const float2*)(wp0 + 132 + 2*e2);
                float2 w2=*(const float2*)(wp0 + 264 + 2*e2);
                float2 w3=*(const float2*)(wp0 + 396 + 2*e2);
                acc[0][0]=fmaf(h0.y,w0.y,fmaf(h0.x,w0.x,acc[0][0]));
                acc[0][1]=fmaf(h0.y,w1.y,fmaf(h0.x,w1.x,acc[0][1]));
                acc[0][2]=fmaf(h0.y,w2.y,fmaf(h0.x,w2.x,acc[0][2]));
                acc[0][3]=fmaf(h0.y,w3.y,fmaf(h0.x,w3.x,acc[0][3]));
                acc[1][0]=fmaf(h1.y,w0.y,fmaf(h1.x,w0.x,acc[1][0]));
                acc[1][1]=fmaf(h1.y,w1.y,fmaf(h1.x,w1.x,acc[1][1]));
                acc[1][2]=fmaf(h1.y,w2.y,fmaf(h1.x,w2.x,acc[1][2]));
                acc[1][3]=fmaf(h1.y,w3.y,fmaf(h1.x,w3.x,acc[1][3]));
                acc[2][0]=fmaf(h2.y,w0.y,fmaf(h2.x,w0.x,acc[2][0]));
                acc[2][1]=fmaf(h2.y,w1.y,fmaf(h2.x,w1.x,acc[2][1]));
                acc[2][2]=fmaf(h2.y,w2.y,fmaf(h2.x,w2.x,acc[2][2]));
                acc[2][3]=fmaf(h2.y,w3.y,fmaf(h2.x,w3.x,acc[2][3]));
                acc[3][0]=fmaf(h3.y,w0.y,fmaf(h3.x,w0.x,acc[3][0]));
                acc[3][1]=fmaf(h3.y,w1.y,fmaf(h3.x,w1.x,acc[3][1]));
                acc[3][2]=fmaf(h3.y,w2.y,fmaf(h3.x,w2.x,acc[3][2]));
                acc[3][3]=fmaf(h3.y,w3.y,fmaf(h3.x,w3.x,acc[3][3]));
            }
            #pragma unroll
            for (int i=0;i<4;i++){
                int n=nb*4+i;
                if (n<150){
                    #pragma unroll
                    for (int j=0;j<4;j++){
                        int c=cb*4+j;
                        sm[QKV0 + (c>>4)*2400 + n*16 + (c&15)] = acc[i][j];
                    }
                }
            }
        }
        __syncthreads();

        {
            float o[16];
            #pragma unroll
            for (int i=0;i<16;i++) o[i]=0.0f;
            float ls=0.0f;
            if (actA){
                float4 q0=*(const float4*)&sm[QKV0 + rA*16 + 0];
                float4 q1=*(const float4*)&sm[QKV0 + rA*16 + 4];
                float4 q2=*(const float4*)&sm[QKV0 + rA*16 + 8];
                float4 q3=*(const float4*)&sm[QKV0 + rA*16 + 12];
                int k0=th3*50;
                for (int kk=k0; kk<k0+50; kk++){
                    const float* kb=&sm[QKV0+2400 + kk*16];
                    float4 ka=*(const float4*)kb;
                    float4 kb4=*(const float4*)(kb+4);
                    float4 kc=*(const float4*)(kb+8);
                    float4 kd=*(const float4*)(kb+12);
                    float s = q0.x*ka.x;
                    s=fmaf(q0.y,ka.y,s); s=fmaf(q0.z,ka.z,s); s=fmaf(q0.w,ka.w,s);
                    s=fmaf(q1.x,kb4.x,s); s=fmaf(q1.y,kb4.y,s); s=fmaf(q1.z,kb4.z,s); s=fmaf(q1.w,kb4.w,s);
                    s=fmaf(q2.x,kc.x,s); s=fmaf(q2.y,kc.y,s); s=fmaf(q2.z,kc.z,s); s=fmaf(q2.w,kc.w,s);
                    s=fmaf(q3.x,kd.x,s); s=fmaf(q3.y,kd.y,s); s=fmaf(q3.z,kd.z,s); s=fmaf(q3.w,kd.w,s);
                    float p=__expf(s*0.25f);
                    ls+=p;
                    const float* vb=&sm[QKV0+4800 + kk*16];
                    float4 va=*(const float4*)vb;
                    float4 v1=*(const float4*)(vb+4);
                    float4 v2=*(const float4*)(vb+8);
                    float4 v3=*(const float4*)(vb+12);
                    o[0]=fmaf(p,va.x,o[0]); o[1]=fmaf(p,va.y,o[1]); o[2]=fmaf(p,va.z,o[2]); o[3]=fmaf(p,va.w,o[3]);
                    o[4]=fmaf(p,v1.x,o[4]); o[5]=fmaf(p,v1.y,o[5]); o[6]=fmaf(p,v1.z,o[6]); o[7]=fmaf(p,v1.w,o[7]);
                    o[8]=fmaf(p,v2.x,o[8]); o[9]=fmaf(p,v2.y,o[9]); o[10]=fmaf(p,v2.z,o[10]); o[11]=fmaf(p,v2.w,o[11]);
                    o[12]=fmaf(p,v3.x,o[12]); o[13]=fmaf(p,v3.y,o[13]); o[14]=fmaf(p,v3.z,o[14]); o[15]=fmaf(p,v3.w,o[15]);
                }
            }
            float ls1=__shfl_down(ls,1), ls2=__shfl_down(ls,2);
            float oc[16];
            #pragma unroll
            for (int i=0;i<16;i++){
                float a1=__shfl_down(o[i],1), a2=__shfl_down(o[i],2);
                oc[i]=(o[i]+a1)+a2;
            }
            if (actA && th3==0){
                float inv = 1.0f/((ls+ls1)+ls2);
                #pragma unroll
                for (int d=0;d<16;d++) sm[OH0 + rA*17 + d] = oc[d]*inv;
            }
        }
        __syncthreads();

        if (t<480){
            #pragma unroll
            for (int d=0; d<16; d++){
                float4 w0=*(const float4*)&sm[OWS0 + d*132 + ebx*8];
                float4 w1=*(const float4*)&sm[OWS0 + d*132 + ebx*8 + 4];
                #pragma unroll
                for (int i=0;i<5;i++){
                    float ov = sm[OH0 + (nb5*5+i)*17 + d];
                    hacc[i][0]=fmaf(ov,w0.x,hacc[i][0]);
                    hacc[i][1]=fmaf(ov,w0.y,hacc[i][1]);
                    hacc[i][2]=fmaf(ov,w0.z,hacc[i][2]);
                    hacc[i][3]=fmaf(ov,w0.w,hacc[i][3]);
                    hacc[i][4]=fmaf(ov,w1.x,hacc[i][4]);
                    hacc[i][5]=fmaf(ov,w1.y,hacc[i][5]);
                    hacc[i][6]=fmaf(ov,w1.z,hacc[i][6]);
                    hacc[i][7]=fmaf(ov,w1.w,hacc[i][7]);
                }
            }
        }
    }
    __syncthreads();
    if (t<480){
        float ob[8];
        *(float4*)&ob[0] = *(const float4*)(out_b + l*EE + ebx*8);
        *(float4*)&ob[4] = *(const float4*)(out_b + l*EE + ebx*8 + 4);
        float cs[8], cq[8];
        #pragma unroll
        for (int k=0;k<8;k++){ cs[k]=0.0f; cq[k]=0.0f; }
        #pragma unroll
        for (int i=0;i<5;i++){
            int r=nb5*5+i;
            float x[8];
            #pragma unroll
            for (int k2=0;k2<4;k2++){
                float2 hv=*(const float2*)&sm[HS0 + r*132 + ebx*8 + 2*k2];
                x[2*k2]   = hv.x + ob[2*k2]   + hacc[i][2*k2];
                x[2*k2+1] = hv.y + ob[2*k2+1] + hacc[i][2*k2+1];
            }
            h_store4(h + hbase + (size_t)r*EE + ebx*8,     make_float4(x[0],x[1],x[2],x[3]));
            h_store4(h + hbase + (size_t)r*EE + ebx*8 + 4, make_float4(x[4],x[5],x[6],x[7]));
            #pragma unroll
            for (int k=0;k<8;k++){ cs[k]+=x[k]; cq[k]+=x[k]*x[k]; }
        }
        #pragma unroll
        for (int k=0;k<8;k++){
            sm[PS0 + nb5*128 + ebx*8 + k]=cs[k];
            sm[PQ0 + nb5*128 + ebx*8 + k]=cq[k];
        }
    }
    __syncthreads();
    if (t<256){
        int e=t&127, hf=t>>7;
        float s=0.0f,q=0.0f;
        for (int nb_=hf*15; nb_<hf*15+15; nb_++){
            s+=sm[PS0+nb_*128+e]; q+=sm[PQ0+nb_*128+e];
        }
        sm[RS0+t]=s; sm[RQ0+t]=q;
    }
    __syncthreads();
    if (t<128){
        part[(size_t)b*256 + t]       = sm[RS0+t]+sm[RS0+128+t];
        part[(size_t)b*256 + 128 + t] = sm[RQ0+t]+sm[RQ0+128+t];
    }
}

// ---------------- fused FFN (legacy, fallback paths) ----------------
template<typename HT>
__global__ void k_ff(HT* __restrict__ h,
                     const float* __restrict__ w1, const float* __restrict__ b1,
                     const float* __restrict__ w2, const float* __restrict__ b2,
                     int l, float* __restrict__ part,
                     const float* __restrict__ scal, const float* __restrict__ shft){
    int bx=blockIdx.x, t=threadIdx.x;
    int row0=bx*16;
    __shared__ __align__(16) float xn[16][EE];
    __shared__ __align__(16) float f1[16][FFD];
    __shared__ float w2T[64][EE+1];
    const float* W1 = w1 + (size_t)l*FFD*EE;
    const float* W2 = w2 + (size_t)l*EE*FFD;
    for (int j=t;j<16*EE;j+=256){
        int r=j>>7,e=j&127;
        xn[r][e]=fmaf(h_load(h + (size_t)(row0+r)*EE+e), scal[e], shft[e]);
    }
    __syncthreads();
    for (int fi=0;fi<2;fi++){
        int f=t+fi*256;
        const float4* wr = (const float4*)(W1 + (size_t)f*EE);
        float bias = b1[l*FFD+f];
        float acc[16];
        #pragma unroll
        for (int r=0;r<16;r++) acc[r]=bias;
        for (int e4=0;e4<32;e4++){
            float4 w=wr[e4];
            #pragma unroll
            for (int r=0;r<16;r++){
                float4 x=*(const float4*)&xn[r][4*e4];
                acc[r] += x.x*w.x + x.y*w.y + x.z*w.z + x.w*w.w;
            }
        }
        #pragma unroll
        for (int r=0;r<16;r++) f1[r][f]=fmaxf(acc[r],0.0f);
    }
    int e=t&127, rh=t>>7;
    float acc2[8];
    #pragma unroll
    for (int i=0;i<8;i++) acc2[i]=0.0f;
    for (int fc=0; fc<FFD; fc+=64){
        __syncthreads();
        for (int j=t;j<64*EE;j+=256){ int e_=j>>6, fl=j&63; w2T[fl][e_]=W2[(size_t)e_*FFD+fc+fl]; }
        __syncthreads();
        for (int fl=0;fl<64;fl++){
            float w=w2T[fl][e];
            #pragma unroll
            for (int i=0;i<8;i++) acc2[i] = fmaf(f1[rh*8+i][fc+fl], w, acc2[i]);
        }
    }
    float bias = b2[l*EE+e];
    float s=0.0f,q=0.0f;
    #pragma unroll
    for (int i=0;i<8;i++){
        float x = xn[rh*8+i][e] + bias + acc2[i];
        h_store(h + (size_t)(row0+rh*8+i)*EE+e, x);
        s+=x; q+=x*x;
    }
    __shared__ float rs[256], rq[256];
    rs[t]=s; rq[t]=q; __syncthreads();
    if (rh==0){
        part[(size_t)bx*256+e]=rs[t]+rs[t+128];
        part[(size_t)bx*256+128+e]=rq[t]+rq[t+128];
    }
}

// ---------------- fused FFN v2: transposed weights, coalesced, 2 barriers ----------------
template<typename HT>
__launch_bounds__(256,4)
__global__ void k_ff2(HT* __restrict__ h,
                      const float* __restrict__ w1T, const float* __restrict__ b1,
                      const float* __restrict__ w2Tg, const float* __restrict__ b2,
                      int l, float* __restrict__ part,
                      const float* __restrict__ scal, const float* __restrict__ shft){
    int bx=blockIdx.x, t=threadIdx.x;
    int row0=bx*16;
    __shared__ __align__(16) float xn[16][EE];    // 8 KB
    __shared__ __align__(16) float f1[16][FFD];   // 32 KB
    const float* W1T = w1T + (size_t)l*65536;     // [e][f]
    const float* W2T = w2Tg + (size_t)l*65536;    // [fl][e]
    for (int j=t;j<16*EE;j+=256){
        int r=j>>7,e=j&127;
        xn[r][e]=fmaf(h_load(h + (size_t)(row0+r)*EE+e), scal[e], shft[e]);
    }
    __syncthreads();
    // fc1: thread handles f = t and t+256; coalesced W1T[e][f] loads
    #pragma unroll
    for (int fi=0;fi<2;fi++){
        int f=t+fi*256;
        float bias = b1[l*FFD+f];
        float acc[16];
        #pragma unroll
        for (int r=0;r<16;r++) acc[r]=bias;
        #pragma unroll 4
        for (int e=0;e<EE;e++){
            float w = W1T[(size_t)e*FFD + f];
            #pragma unroll
            for (int r=0;r<16;r++) acc[r]=fmaf(xn[r][e], w, acc[r]);
        }
        #pragma unroll
        for (int r=0;r<16;r++) f1[r][f]=fmaxf(acc[r],0.0f);
    }
    __syncthreads();
    // fc2: thread handles column e=t&127, 8 rows; coalesced W2T[fl][e] loads
    int e=t&127, rh=t>>7;
    float acc2[8];
    #pragma unroll
    for (int i=0;i<8;i++) acc2[i]=0.0f;
    #pragma unroll 4
    for (int fl=0; fl<FFD; fl++){
        float w = W2T[(size_t)fl*EE + e];
        #pragma unroll
        for (int i=0;i<8;i++) acc2[i] = fmaf(f1[rh*8+i][fl], w, acc2[i]);
    }
    float bias = b2[l*EE+e];
    float s=0.0f,q=0.0f;
    #pragma unroll
    for (int i=0;i<8;i++){
        float x = xn[rh*8+i][e] + bias + acc2[i];
        h_store(h + (size_t)(row0+rh*8+i)*EE+e, x);
        s+=x; q+=x*x;
    }
    __shared__ float rs[256], rq[256];
    rs[t]=s; rq[t]=q; __syncthreads();
    if (rh==0){
        part[(size_t)bx*256+e]=rs[t]+rs[t+128];
        part[(size_t)bx*256+128+e]=rq[t]+rq[t+128];
    }
}

// ---------------- G_ih precompute ----------------
template<typename HT>
__launch_bounds__(512)
__global__ void k_gih(const HT* __restrict__ h, const float* __restrict__ wihT,
                      const float* __restrict__ scal, const float* __restrict__ shft,
                      float* __restrict__ G, int b0){
    __shared__ float xn[NN][132];
    int bl = blockIdx.x, t = threadIdx.x;
    const size_t hbase = (size_t)(b0+bl)*NN*EE;
    for (int j=t; j<NN*32; j+=512){
        int r=j>>5, e4=(j&31)*4;
        float4 x = h_load4(h + hbase + (size_t)r*EE + e4);
        float4 sc4=*(const float4*)(scal+e4), sh4=*(const float4*)(shft+e4);
        x.x=fmaf(x.x,sc4.x,sh4.x); x.y=fmaf(x.y,sc4.y,sh4.y);
        x.z=fmaf(x.z,sc4.z,sh4.z); x.w=fmaf(x.w,sc4.w,sh4.w);
        *(float4*)&xn[r][e4]=x;
    }
    __syncthreads();
    float* Gb = G + (size_t)bl*NN*512;
    const float* wcol = wihT + t;
    for (int nb=0; nb<10; nb++){
        float acc[15];
        #pragma unroll
        for (int j=0;j<15;j++) acc[j]=0.0f;
        #pragma unroll 4
        for (int e=0;e<128;e++){
            float w = wcol[(size_t)e*512];
            #pragma unroll
            for (int j=0;j<15;j++) acc[j]=fmaf(xn[nb*15+j][e], w, acc[j]);
        }
        #pragma unroll
        for (int j=0;j<15;j++) Gb[(size_t)(nb*15+j)*512+t]=acc[j];
    }
}

// ---------------- shared decoder LDS layout ----------------
#define EWQ    19200
#define DGTS   38400
#define D_DD   39424
#define D_HH   39680
#define D_HW2  39936
#define D_PVS  40192
#define D_SCS  40320
#define D_SHS  40448
#define D_TOT  40576

// ---------------- decoder v2i (fallback, ws mid) ----------------
template<typename HT>
__launch_bounds__(1024,4)
__global__ void k_decoder2(const HT* __restrict__ enc, const float* __restrict__ inp,
        const float* __restrict__ wih_p, const float* __restrict__ whh_p,
        const float* __restrict__ bih, const float* __restrict__ bhh,
        const float* __restrict__ pw1T, const float* __restrict__ pb1,
        const float* __restrict__ pw2T, const float* __restrict__ pb2,
        const float* __restrict__ pv, const float* __restrict__ pbv,
        const float* __restrict__ scal, const float* __restrict__ shft,
        float* __restrict__ out){
    __shared__ float smf[D_TOT];
    __shared__ unsigned char schna[608];
    const int t = threadIdx.x;
    const int q = t>>9, r = t&511;
    const int b0 = blockIdx.x*2;
    const HT* encq = enc + (size_t)(b0+q)*NN*EE;

    if (t<128){ smf[D_PVS+t]=pv[t]; smf[D_SCS+t]=scal[t]; smf[D_SHS+t]=shft[t]; }
    if (t<512) smf[D_DD+t]=0.0f;
    if (t<304){
        int qq=t/152, n=t-qq*152;
        schna[qq*304+n]=0;
        unsigned char nav=1;
        if (n<150) nav = (inp[((size_t)(b0+qq)*NN+n)*4+1] != 0.0f) ? 1 : 0;
        schna[qq*304+152+n]=nav;
    }
    const int g = t>>1, kh = t&1;
    const float bsum = bih[g] + bhh[g];
    const float pb2r = (t<256) ? pb2[t&127] : 0.0f;
    const float pbvr = pbv[0];

    float4 whr[16];
    {
        const float4* wp = (const float4*)whh_p + t;
        #pragma unroll
        for (int i=0;i<16;i++) whr[i] = wp[(size_t)i*1024];
    }
    __syncthreads();

    {
        const int e = r&127, ng = r>>7;
        const float pb1e = pb1[e];
        for (int n1 = ng; n1 < 150; n1 += 8){
            int n2 = n1+4;
            bool has2 = (n2<150);
            int n2c = has2 ? n2 : n1;
            float a1=0.0f, a2=0.0f;
            #pragma unroll 4
            for (int e2=0;e2<EE;e2++){
                float w = pw1T[e2*EE + e];
                float x1 = fmaf(smf[D_SCS+e2], h_load(encq + (size_t)n1*EE + e2), smf[D_SHS+e2]);
                float x2 = fmaf(smf[D_SCS+e2], h_load(encq + (size_t)n2c*EE + e2), smf[D_SHS+e2]);
                a1 = fmaf(x1, w, a1);
                a2 = fmaf(x2, w, a2);
            }
            smf[q*EWQ + n1*128 + (e ^ (n1&31))] = a1 + pb1e;
            if (has2) smf[q*EWQ + n2*128 + (e ^ (n2&31))] = a2 + pb1e;
        }
    }
    if (t<512){
        int qq=t>>8, rr=t&255, e=rr&127, hf=rr>>7;
        const HT* eb = enc + (size_t)(b0+qq)*NN*EE;
        float s=0.0f;
        for (int n=hf*75;n<hf*75+75;n++) s += h_load(eb + (size_t)n*EE+e);
        smf[DGTS + qq*256 + hf*128 + e] = s;
    }
    __syncthreads();
    float c_reg = 0.0f;
    if (t<256){
        int qq=t>>7, e=t&127;
        float mean = (smf[DGTS+qq*256+e]+smf[DGTS+qq*256+128+e])*(1.0f/150.0f);
        c_reg = fmaf(smf[D_SCS+e], mean, smf[D_SHS+e]);
    }
    __syncthreads();

    float llacc=0.0f;
    const float4* wip = (const float4*)wih_p + t;
    for (int step=0; step<NN; step++){
        {
            float a0=0.0f, a1=0.0f;
            const float* d0 = &smf[D_DD + kh*64];
            const float* d1 = &smf[D_DD + 128 + kh*64];
            const float* h0 = &smf[D_HH + kh*64];
            const float* h1 = &smf[D_HH + 128 + kh*64];
            #pragma unroll 8
            for (int i=0;i<16;i++){
                float4 wv = wip[(size_t)i*1024];
                float4 wh = whr[i];
                float4 x0 = *(const float4*)(d0 + 4*i);
                float4 x1 = *(const float4*)(d1 + 4*i);
                float4 y0 = *(const float4*)(h0 + 4*i);
                float4 y1 = *(const float4*)(h1 + 4*i);
                a0 = fmaf(wv.w,x0.w,fmaf(wv.z,x0.z,fmaf(wv.y,x0.y,fmaf(wv.x,x0.x,a0))));
                a0 = fmaf(wh.w,y0.w,fmaf(wh.z,y0.z,fmaf(wh.y,y0.y,fmaf(wh.x,y0.x,a0))));
                a1 = fmaf(wv.w,x1.w,fmaf(wv.z,x1.z,fmaf(wv.y,x1.y,fmaf(wv.x,x1.x,a1))));
                a1 = fmaf(wh.w,y1.w,fmaf(wh.z,y1.z,fmaf(wh.y,y1.y,fmaf(wh.x,y1.x,a1))));
            }
            a0 += __shfl_xor(a0,1);
            a1 += __shfl_xor(a1,1);
            if (kh==0){
                smf[DGTS + g]       = a0 + bsum;
                smf[DGTS + 512 + g] = a1 + bsum;
            }
        }
        __syncthreads();
        if (t<256){
            int qq=t>>7, e=t&127;
            const float* gt = &smf[DGTS + qq*512];
            float gi=fsig(gt[e]), gf=fsig(gt[128+e]), gg=ftanh(gt[256+e]), go=fsig(gt[384+e]);
            c_reg = gf*c_reg + gi*gg;
            smf[D_HH + qq*128 + e] = go*ftanh(c_reg);
        }
        __syncthreads();
        if (t<256){
            int qq=t>>7, e=t&127;
            float s2=0.0f;
            #pragma unroll 4
            for (int e2=0;e2<EE;e2++)
                s2 = fmaf(pw2T[e2*EE + e], smf[D_HH + qq*128 + e2], s2);
            smf[D_HW2 + qq*128 + e] = s2 + pb2r;
        }
        __syncthreads();
        {
            int half = r>>8, n = r&255;
            if (n<150){
                float p=0.0f;
                const float* ewn = &smf[q*EWQ + n*128];
                const float* hwq = &smf[D_HW2 + q*128];
                int sw = n&31;
                #pragma unroll 8
                for (int e2=0;e2<64;e2++){
                    int e = half*64+e2;
                    p = fmaf(ftanh(ewn[e ^ sw] + hwq[e]), smf[D_PVS+e], p);
                }
                smf[DGTS + (q*2+half)*152 + n] = p;
            }
        }
        __syncthreads();
        if (t<128){
            int qq=t>>6, l=t&63;
            const unsigned char* sc_ = &schna[qq*304];
            const float* pp = &smf[DGTS + qq*2*152];
            int n0=l, n1=l+64, n2=l+128;
            float a0 = pp[n0]+pp[152+n0]+pbvr;
            float a1 = pp[n1]+pp[152+n1]+pbvr;
            float v0 = (sc_[n0]|sc_[152+n0]) ? -10000.0f : a0;
            float v1 = (sc_[n1]|sc_[152+n1]) ? -10000.0f : a1;
            float v2 = -1e30f;
            if (n2<NN){
                float a2 = pp[n2]+pp[152+n2]+pbvr;
                v2 = (sc_[n2]|sc_[152+n2]) ? -10000.0f : a2;
            }
            float m=v0; int mi=n0;
            if (v1>m){ m=v1; mi=n1; }
            if (n2<NN && v2>m){ m=v2; mi=n2; }
            #pragma unroll
            for (int off=1; off<64; off<<=1){
                float om=__shfl_xor(m,off); int oi=__shfl_xor(mi,off);
                if (om>m || (om==m && oi<mi)){ m=om; mi=oi; }
            }
            float se = __expf(v0-m)+__expf(v1-m) + ((n2<NN)? __expf(v2-m):0.0f);
            #pragma unroll
            for (int off=1; off<64; off<<=1) se += __shfl_xor(se,off);
            const HT* eb = enc + (size_t)(b0+qq)*NN*EE;
            if (l==0){
                llacc -= logf(se);
                schna[qq*304+mi]=1;
                int nn2 = mi+1; if (nn2>NN-1) nn2=NN-1;
                schna[qq*304+152+nn2]=0;
                float4 rowv = *(const float4*)(inp + ((size_t)(b0+qq)*NN+mi)*4);
                *(float4*)(out + ((size_t)(b0+qq)*NN+step)*4) = rowv;
            }
            float eva = h_load(eb + (size_t)mi*EE + l);
            float evb = h_load(eb + (size_t)mi*EE + l + 64);
            smf[D_DD + qq*128 + l]      = fmaf(smf[D_SCS+l],    eva, smf[D_SHS+l]);
            smf[D_DD + qq*128 + l + 64] = fmaf(smf[D_SCS+l+64], evb, smf[D_SHS+l+64]);
        }
        __syncthreads();
    }
    if (t==0)  out[(size_t)BB*NN*4 + b0]   = llacc;
    if (t==64) out[(size_t)BB*NN*4 + b0+1] = llacc;
}

// ---------------- decoder G5: 1024 threads, G-lookup, streamed Whh only ----------------
template<typename HT>
__launch_bounds__(1024,4)
__global__ void k_decoderG5(const HT* __restrict__ enc, const float* __restrict__ inp,
        const float* __restrict__ whh_p, const float* __restrict__ Gih,
        const float* __restrict__ bih, const float* __restrict__ bhh,
        const float* __restrict__ pw1T, const float* __restrict__ pb1,
        const float* __restrict__ pw2T, const float* __restrict__ pb2,
        const float* __restrict__ pv, const float* __restrict__ pbv,
        const float* __restrict__ scal, const float* __restrict__ shft,
        float* __restrict__ out, int passb0){
    __shared__ float smf[D_TOT];
    __shared__ unsigned char schna[608];
    __shared__ int predS2[2];
    const int t = threadIdx.x;
    const int q = t>>9, r = t&511;
    const int b0 = passb0 + blockIdx.x*2;
    const HT* encq = enc + (size_t)(b0+q)*NN*EE;

    if (t<128){ smf[D_PVS+t]=pv[t]; smf[D_SCS+t]=scal[t]; smf[D_SHS+t]=shft[t]; }
    if (t<256) smf[D_HH+t]=0.0f;
    if (t<304){
        int qq=t/152, n=t-qq*152;
        schna[qq*304+n]=0;
        unsigned char nav=1;
        if (n<150) nav = (inp[((size_t)(b0+qq)*NN+n)*4+1] != 0.0f) ? 1 : 0;
        schna[qq*304+152+n]=nav;
    }
    if (t<2) predS2[t]=-1;
    const int g = t>>1, kh = t&1;
    const float bsum = bih[g] + bhh[g];
    const float pb2r = (t<256) ? pb2[t&127] : 0.0f;
    const float pbvr = pbv[0];
    __syncthreads();

    {
        const int e = r&127, ng = r>>7;
        const float pb1e = pb1[e];
        for (int n1 = ng; n1 < 150; n1 += 8){
            int n2 = n1+4;
            bool has2 = (n2<150);
            int n2c = has2 ? n2 : n1;
            float a1=0.0f, a2=0.0f;
            #pragma unroll 4
            for (int e2=0;e2<EE;e2++){
                float w = pw1T[e2*EE + e];
                float x1 = fmaf(smf[D_SCS+e2], h_load(encq + (size_t)n1*EE + e2), smf[D_SHS+e2]);
                float x2 = fmaf(smf[D_SCS+e2], h_load(encq + (size_t)n2c*EE + e2), smf[D_SHS+e2]);
                a1 = fmaf(x1, w, a1);
                a2 = fmaf(x2, w, a2);
            }
            smf[q*EWQ + n1*128 + (e ^ (n1&31))] = a1 + pb1e;
            if (has2) smf[q*EWQ + n2*128 + (e ^ (n2&31))] = a2 + pb1e;
        }
    }
    if (t<512){
        int qq=t>>8, rr=t&255, e=rr&127, hf=rr>>7;
        const HT* eb = enc + (size_t)(b0+qq)*NN*EE;
        float s=0.0f;
        for (int n=hf*75;n<hf*75+75;n++) s += h_load(eb + (size_t)n*EE+e);
        smf[DGTS + qq*256 + hf*128 + e] = s;
    }
    __syncthreads();
    float c_reg = 0.0f;
    if (t<256){
        int qq=t>>7, e=t&127;
        float mean = (smf[DGTS+qq*256+e]+smf[DGTS+qq*256+128+e])*(1.0f/150.0f);
        c_reg = fmaf(smf[D_SCS+e], mean, smf[D_SHS+e]);
    }
    __syncthreads();

    float llacc=0.0f;
    const float* Gb0 = Gih + (size_t)(blockIdx.x*2)*NN*512;
    const float* Gb1 = Gih + (size_t)(blockIdx.x*2+1)*NN*512;
    const float4* whp = (const float4*)whh_p + t;
    for (int step=0; step<NN; step++){
        {
            float a0=0.0f, a1=0.0f;
            const float* h0 = &smf[D_HH + kh*64];
            const float* h1 = &smf[D_HH + 128 + kh*64];
            #pragma unroll 8
            for (int i=0;i<16;i++){
                float4 wh = whp[(size_t)i*1024];
                float4 y0 = *(const float4*)(h0 + 4*i);
                float4 y1 = *(const float4*)(h1 + 4*i);
                a0 = fmaf(wh.w,y0.w,fmaf(wh.z,y0.z,fmaf(wh.y,y0.y,fmaf(wh.x,y0.x,a0))));
                a1 = fmaf(wh.w,y1.w,fmaf(wh.z,y1.z,fmaf(wh.y,y1.y,fmaf(wh.x,y1.x,a1))));
            }
            a0 += __shfl_xor(a0,1);
            a1 += __shfl_xor(a1,1);
            if (kh==0){
                int p0=predS2[0], p1=predS2[1];
                float ga = (p0>=0) ? Gb0[(size_t)p0*512 + g] : 0.0f;
                float gb = (p1>=0) ? Gb1[(size_t)p1*512 + g] : 0.0f;
                smf[DGTS + g]       = a0 + bsum + ga;
                smf[DGTS + 512 + g] = a1 + bsum + gb;
            }
        }
        __syncthreads();
        if (t<256){
            int qq=t>>7, e=t&127;
            const float* gt = &smf[DGTS + qq*512];
            float gi=fsig(gt[e]), gf=fsig(gt[128+e]), gg=ftanh(gt[256+e]), go=fsig(gt[384+e]);
            c_reg = gf*c_reg + gi*gg;
            smf[D_HH + qq*128 + e] = go*ftanh(c_reg);
        }
        __syncthreads();
        if (t<256){
            int qq=t>>7, e=t&127;
            float s2=0.0f;
            #pragma unroll 4
            for (int e2=0;e2<EE;e2++)
                s2 = fmaf(pw2T[e2*EE + e], smf[D_HH + qq*128 + e2], s2);
            smf[D_HW2 + qq*128 + e] = s2 + pb2r;
        }
        __syncthreads();
        {
            int half = r>>8, n = r&255;
            if (n<150){
                float p=0.0f;
                const float* ewn = &smf[q*EWQ + n*128];
                const float* hwq = &smf[D_HW2 + q*128];
                int sw = n&31;
                #pragma unroll 8
                for (int e2=0;e2<64;e2++){
                    int e = half*64+e2;
                    p = fmaf(ftanh(ewn[e ^ sw] + hwq[e]), smf[D_PVS+e], p);
                }
                smf[DGTS + (q*2+half)*152 + n] = p;
            }
        }
        __syncthreads();
        if (t<128){
            int qq=t>>6, l=t&63;
            const unsigned char* sc_ = &schna[qq*304];
            const float* pp = &smf[DGTS + qq*2*152];
            int n0=l, n1=l+64, n2=l+128;
            float a0 = pp[n0]+pp[152+n0]+pbvr;
            float a1 = pp[n1]+pp[152+n1]+pbvr;
            float v0 = (sc_[n0]|sc_[152+n0]) ? -10000.0f : a0;
            float v1 = (sc_[n1]|sc_[152+n1]) ? -10000.0f : a1;
            float v2 = -1e30f;
            if (n2<NN){
                float a2 = pp[n2]+pp[152+n2]+pbvr;
                v2 = (sc_[n2]|sc_[152+n2]) ? -10000.0f : a2;
            }
            float m=v0; int mi=n0;
            if (v1>m){ m=v1; mi=n1; }
            if (n2<NN && v2>m){ m=v2; mi=n2; }
            #pragma unroll
            for (int off=1; off<64; off<<=1){
                float om=__shfl_xor(m,off); int oi=__shfl_xor(mi,off);
                if (om>m || (om==m && oi<mi)){ m=om; mi=oi; }
            }
            float se = __expf(v0-m)+__expf(v1-m) + ((n2<NN)? __expf(v2-m):0.0f);
            #pragma unroll
            for (int off=1; off<64; off<<=1) se += __shfl_xor(se,off);
            if (l==0){
                llacc -= logf(se);
                predS2[qq]=mi;
                schna[qq*304+mi]=1;
                int nn2 = mi+1; if (nn2>NN-1) nn2=NN-1;
                schna[qq*304+152+nn2]=0;
                float4 rowv = *(const float4*)(inp + ((size_t)(b0+qq)*NN+mi)*4);
                *(float4*)(out + ((size_t)(b0+qq)*NN+step)*4) = rowv;
            }
        }
        __syncthreads();
    }
    if (t==0)  out[(size_t)BB*NN*4 + b0]   = llacc;
    if (t==64) out[(size_t)BB*NN*4 + b0+1] = llacc;
}

// ---------------- host schedule ----------------
template<typename HT>
static void run_model(void* const* d_in, void* d_out, void* d_ws, bool big, hipStream_t stream){
    const float* inp   = (const float*)d_in[0];
    const float* opg   = (const float*)d_in[1];
    const float* opb   = (const float*)d_in[2];
    const float* opW   = (const float*)d_in[3];
    const float* opB   = (const float*)d_in[4];
    const float* mtg   = (const float*)d_in[5];
    const float* mtb   = (const float*)d_in[6];
    const float* mtW   = (const float*)d_in[7];
    const float* mtB   = (const float*)d_in[8];
    const float* e0g   = (const float*)d_in[9];
    const float* e0b   = (const float*)d_in[10];
    const float* in_w  = (const float*)d_in[11];
    const float* in_b  = (const float*)d_in[12];
    const float* out_w = (const float*)d_in[13];
    const float* out_b = (const float*)d_in[14];
    const float* bn1g  = (const float*)d_in[15];
    const float* bn1b  = (const float*)d_in[16];
    const float* ffw1  = (const float*)d_in[17];
    const float* ffb1  = (const float*)d_in[18];
    const float* ffw2  = (const float*)d_in[19];
    const float* ffb2  = (const float*)d_in[20];
    const float* bn2g  = (const float*)d_in[21];
    const float* bn2b  = (const float*)d_in[22];
    const float* Wih   = (const float*)d_in[23];
    const float* Whh   = (const float*)d_in[24];
    const float* bihp  = (const float*)d_in[25];
    const float* bhhp  = (const float*)d_in[26];
    const float* pw1   = (const float*)d_in[27];
    const float* pb1   = (const float*)d_in[28];
    const float* pw2   = (const float*)d_in[29];
    const float* pb2   = (const float*)d_in[30];
    const float* pv    = (const float*)d_in[31];
    const float* pbv   = (const float*)d_in[32];
    float* out = (float*)d_out;

    HT* h = (HT*)d_ws;
    float* Xf = (float*)((char*)d_ws + (size_t)RTOT*EE*sizeof(HT));
    float* part  = Xf;                    // 2457600
    float* cwcb  = Xf + 2457600;          // 640
    float* scal  = cwcb + 640;
    float* shft  = scal + 128;
    float* wih_p = shft + 128;            // 65536
    float* whh_p = wih_p + 65536;         // 65536
    float* pw1T  = whh_p + 65536;         // 16384
    float* pw2Tg = pw1T + 16384;          // 16384
    float* owT   = pw2Tg + 16384;         // 49152
    float* part2 = owT + 49152;           // 15360
    float* wihT  = part2 + 15360;         // 65536 (big only)
    float* G     = wihT + 65536;          // 39,321,600 (big only)
    // FFN transposes live in the G region (dead until k_gih overwrites after encoder)
    float* w1T   = G;                     // 196608
    float* w2Tg  = G + 196608;            // 196608

    k_prep2<<<256,256,0,stream>>>(Wih, Whh, pw1, pw2, out_w, wih_p, whh_p, pw1T, pw2Tg, owT);
    if (big){
        k_prep3<<<256,256,0,stream>>>(Wih, wihT);
        k_prep4<<<768,256,0,stream>>>(ffw1, ffw2, w1T, w2Tg);
    }
    k_inp_stats<<<600,256,0,stream>>>(inp, part);
    k_inp_final<<<1,128,0,stream>>>(part, opg,opb,opW,opB, mtg,mtb,mtW,mtB, cwcb);
    k_embed<HT><<<2400,256,0,stream>>>(inp, cwcb, h, part);
    k_bn_mid<<<60,256,0,stream>>>(part, 2400, part2);
    k_bn_fin<<<1,256,0,stream>>>(part2, e0g, e0b, scal, shft);
    for (int l=0;l<NL;l++){
        k_mha<HT><<<1024,512,0,stream>>>(h, in_w, in_b, owT, out_b, l, part, scal, shft);
        k_bn_mid<<<60,256,0,stream>>>(part, 1024, part2);
        k_bn_fin<<<1,256,0,stream>>>(part2, bn1g + l*EE, bn1b + l*EE, scal, shft);
        if (big){
            k_ff2<HT><<<9600,256,0,stream>>>(h, w1T, ffb1, w2Tg, ffb2, l, part, scal, shft);
        } else {
            k_ff<HT><<<9600,256,0,stream>>>(h, ffw1, ffb1, ffw2, ffb2, l, part, scal, shft);
        }
        k_bn_mid<<<60,256,0,stream>>>(part, 9600, part2);
        k_bn_fin<<<1,256,0,stream>>>(part2, bn2g + l*EE, bn2b + l*EE, scal, shft);
    }
    if (big){
        for (int pass=0; pass<2; pass++){
            k_gih<HT><<<512,512,0,stream>>>(h, wihT, scal, shft, G, pass*512);
            k_decoderG5<HT><<<256,1024,0,stream>>>(h, inp, whh_p, G, bihp, bhhp,
                                                   pw1T, pb1, pw2Tg, pb2, pv, pbv,
                                                   scal, shft, out, pass*512);
        }
    } else {
        k_decoder2<HT><<<512,1024,0,stream>>>(h, inp, wih_p, whh_p, bihp, bhhp,
                                              pw1T, pb1, pw2Tg, pb2, pv, pbv,
                                              scal, shft, out);
    }
}

extern "C" void kernel_launch(void* const* d_in, const int* in_sizes, int n_in,
                              void* d_out, int out_size, void* d_ws, size_t ws_size,
                              hipStream_t stream){
    const size_t xf_floats = 2457600u + 640 + 128 + 128 + 65536 + 65536 + 16384 + 16384 + 49152 + 15360;
    const size_t need_A   = (size_t)RTOT*EE*4 + xf_floats*4ull;
    const size_t need_big = need_A + (size_t)(65536 + 39321600)*4ull;
    if (ws_size >= need_big){
        run_model<float>(d_in, d_out, d_ws, true, stream);
    } else if (ws_size >= need_A){
        run_model<float>(d_in, d_out, d_ws, false, stream);
    } else {
        run_model<f16>(d_in, d_out, d_ws, false, stream);
    }
    (void)in_sizes; (void)n_in; (void)out_size; (void)ws_size;
}

// Round 14
// 9587.148 us; speedup vs baseline: 1.3019x; 1.0306x over previous
//
#include <hip/hip_runtime.h>
#include <math.h>

#define BB 1024
#define NN 150
#define RTOT (BB*NN)
#define EE 128
#define FFD 512
#define NL 3

typedef unsigned short u16;
typedef unsigned int u32;
typedef _Float16 f16;
typedef _Float16 f16x4 __attribute__((ext_vector_type(4)));

__device__ __forceinline__ float fsig(float x){ return __builtin_amdgcn_rcpf(1.0f + __expf(-x)); }
__device__ __forceinline__ float ftanh(float x){ return 1.0f - 2.0f*__builtin_amdgcn_rcpf(1.0f + __expf(2.0f*x)); }

// ---- h storage accessors ----
__device__ __forceinline__ float4 h_load4(const float* p){ return *(const float4*)p; }
__device__ __forceinline__ float4 h_load4(const f16* p){
    f16x4 v = *(const f16x4*)p;
    return make_float4((float)v.x,(float)v.y,(float)v.z,(float)v.w);
}
__device__ __forceinline__ void h_store4(float* p, float4 v){ *(float4*)p = v; }
__device__ __forceinline__ void h_store4(f16* p, float4 v){
    f16x4 o; o.x=(f16)v.x; o.y=(f16)v.y; o.z=(f16)v.z; o.w=(f16)v.w;
    *(f16x4*)p = o;
}
__device__ __forceinline__ float h_load(const float* p){ return *p; }
__device__ __forceinline__ float h_load(const f16* p){ return (float)*p; }
__device__ __forceinline__ void h_store(float* p, float v){ *p = v; }
__device__ __forceinline__ void h_store(f16* p, float v){ *p = (f16)v; }

// ---------------- prep: weight transposes/packs ----------------
__global__ void k_prep2(const float* __restrict__ Wih, const float* __restrict__ Whh,
                        const float* __restrict__ pw1, const float* __restrict__ pw2,
                        const float* __restrict__ out_w,
                        float* __restrict__ wih_p, float* __restrict__ whh_p,
                        float* __restrict__ pw1T, float* __restrict__ pw2T,
                        float* __restrict__ owT){
    int idx = blockIdx.x*256 + threadIdx.x;   // 65536 total
    {
        int f4 = idx>>2, c = idx&3;
        int i = f4>>10, tt = f4&1023;
        int g = tt>>1, kh = tt&1;
        int col = kh*64 + i*4 + c;
        wih_p[idx] = Wih[(size_t)g*128 + col];
        whh_p[idx] = Whh[(size_t)g*128 + col];
    }
    if (idx < 16384){
        int e = idx>>7, e2 = idx&127;
        pw1T[e2*128+e] = pw1[idx];
        pw2T[e2*128+e] = pw2[idx];
    }
    if (idx < 49152){
        int l = idx>>14, r = (idx>>7)&127, d = idx&127;
        owT[(size_t)l*16384 + d*128 + r] = out_w[idx];
    }
}

// big-ws extra: wihT[e][g] for the G GEMM
__global__ void k_prep3(const float* __restrict__ Wih, float* __restrict__ wihT){
    int idx = blockIdx.x*256 + threadIdx.x;   // 65536
    int g = idx>>7, e = idx&127;
    wihT[(size_t)e*512 + g] = Wih[idx];
}

// big-ws extra: FFN weight transposes into the (currently dead) G region
__global__ void k_prep4(const float* __restrict__ ffw1, const float* __restrict__ ffw2,
                        float* __restrict__ w1T, float* __restrict__ w2Tg){
    int idx = blockIdx.x*256 + threadIdx.x;   // 196608
    int l = idx >> 16, r = idx & 65535;
    {
        int e = r>>9, f = r&511;
        w1T[idx] = ffw1[(size_t)l*65536 + (size_t)f*128 + e];
    }
    {
        int fl = r>>7, e2 = r&127;
        w2Tg[idx] = ffw2[(size_t)l*65536 + (size_t)e2*512 + fl];
    }
}

// ---------------- input 4-channel stats ----------------
__global__ void k_inp_stats(const float* __restrict__ inp, float* __restrict__ part){
    int t = threadIdx.x;
    int row = blockIdx.x*256 + t;
    float4 u = *(const float4*)(inp + (size_t)row*4);
    __shared__ float red[256][8];
    red[t][0]=u.x; red[t][1]=u.y; red[t][2]=u.z; red[t][3]=u.w;
    red[t][4]=u.x*u.x; red[t][5]=u.y*u.y; red[t][6]=u.z*u.z; red[t][7]=u.w*u.w;
    __syncthreads();
    for (int s=128;s>0;s>>=1){
        if (t<s){
            #pragma unroll
            for (int c=0;c<8;c++) red[t][c]+=red[t+s][c];
        }
        __syncthreads();
    }
    if (t<8) part[blockIdx.x*8+t] = red[0][t];
}

__global__ void k_inp_final(const float* __restrict__ part,
    const float* __restrict__ opg, const float* __restrict__ opb,
    const float* __restrict__ opW, const float* __restrict__ opB,
    const float* __restrict__ mtg, const float* __restrict__ mtb,
    const float* __restrict__ mtW, const float* __restrict__ mtB,
    float* __restrict__ cwcb){
    int t = threadIdx.x; // 128
    __shared__ float sc[4], oc[4];
    if (t<4){
        float s=0.0f,q=0.0f;
        for (int i=0;i<600;i++){ s+=part[i*8+t]; q+=part[i*8+4+t]; }
        float mean = s/(float)RTOT;
        float var  = q/(float)RTOT - mean*mean;
        float rstd = 1.0f/sqrtf(var+1e-5f);
        float g = (t<2)?opg[t]:mtg[t-2];
        float b = (t<2)?opb[t]:mtb[t-2];
        sc[t]=g*rstd; oc[t]=b-mean*g*rstd;
    }
    __syncthreads();
    float w0=opW[t*2], w1=opW[t*2+1];
    float w2=mtW[t*2], w3=mtW[t*2+1];
    float* o = cwcb + t*5;
    o[0]=sc[0]*w0; o[1]=sc[1]*w1; o[2]=sc[2]*w2; o[3]=sc[3]*w3;
    o[4]=opB[t]+mtB[t] + oc[0]*w0+oc[1]*w1+oc[2]*w2+oc[3]*w3;
}

// ---------------- embed + enc0 stats ----------------
template<typename HT>
__global__ void k_embed(const float* __restrict__ inp, const float* __restrict__ cwcb,
                        HT* __restrict__ h, float* __restrict__ part){
    int bx=blockIdx.x, t=threadIdx.x;
    int row0 = bx*64;
    __shared__ float xin[64][4];
    if (t<64){
        float4 u = *(const float4*)(inp + (size_t)(row0+t)*4);
        xin[t][0]=u.x; xin[t][1]=u.y; xin[t][2]=u.z; xin[t][3]=u.w;
    }
    int e=t&127, rh=t>>7;
    float c0=cwcb[e*5],c1=cwcb[e*5+1],c2=cwcb[e*5+2],c3=cwcb[e*5+3],cb=cwcb[e*5+4];
    __syncthreads();
    float s=0.0f,q=0.0f;
    for (int r=rh; r<64; r+=2){
        float x = cb + xin[r][0]*c0 + xin[r][1]*c1 + xin[r][2]*c2 + xin[r][3]*c3;
        h_store(h + (size_t)(row0+r)*EE + e, x);
        s+=x; q+=x*x;
    }
    __shared__ float rs[256], rq[256];
    rs[t]=s; rq[t]=q;
    __syncthreads();
    if (rh==0){
        part[(size_t)bx*256 + e]       = rs[t]+rs[t+128];
        part[(size_t)bx*256 + 128 + e] = rq[t]+rq[t+128];
    }
}

// ---------------- BN reduce cascade ----------------
__global__ void k_bn_mid(const float* __restrict__ part, int nblk, float* __restrict__ part2){
    int j=blockIdx.x, t=threadIdx.x;   // 60 blocks x 256
    float s=0.0f;
    for (int i=j;i<nblk;i+=60) s += part[(size_t)i*256+t];
    part2[j*256+t]=s;
}

__global__ void k_bn_fin(const float* __restrict__ part2,
                         const float* __restrict__ g, const float* __restrict__ b,
                         float* __restrict__ scale, float* __restrict__ shift){
    int t=threadIdx.x;  // 256
    float s=0.0f;
    for (int j=0;j<60;j++) s += part2[j*256+t];
    __shared__ float red[256];
    red[t]=s; __syncthreads();
    if (t<128){
        float ss=red[t], qq=red[128+t];
        float mean=ss/(float)RTOT, var=qq/(float)RTOT-mean*mean;
        float rstd=1.0f/sqrtf(var+1e-5f);
        float gg=g[t];
        scale[t]=gg*rstd; shift[t]=b[t]-mean*gg*rstd;
    }
}

// ---------------- fused MHA + out-proj + residual + bn1 stats ----------------
#define HS0   0
#define WS0   19800
#define QKV0  26136
#define OH0   33336
#define OWS0  35886
#define BIA0  37998
#define SMTOT 38046
#define PS0   QKV0
#define PQ0   (QKV0+3840)
#define RS0   OWS0
#define RQ0   (OWS0+256)

template<typename HT>
__launch_bounds__(512,1)
__global__ void k_mha(HT* __restrict__ h, const float* __restrict__ in_w,
                      const float* __restrict__ in_b, const float* __restrict__ owT,
                      const float* __restrict__ out_b, int l, float* __restrict__ part,
                      const float* __restrict__ scal, const float* __restrict__ shft){
    __shared__ float sm[SMTOT];
    int b = blockIdx.x, t = threadIdx.x;
    const size_t hbase = (size_t)b*NN*EE;

    for (int j=t; j<NN*32; j+=512){
        int r=j>>5, e4=(j&31)*4;
        float4 x = h_load4(h + hbase + (size_t)r*EE + e4);
        float4 sc4 = *(const float4*)(scal + e4);
        float4 sh4 = *(const float4*)(shft + e4);
        x.x = fmaf(x.x, sc4.x, sh4.x); x.y = fmaf(x.y, sc4.y, sh4.y);
        x.z = fmaf(x.z, sc4.z, sh4.z); x.w = fmaf(x.w, sc4.w, sh4.w);
        *(float4*)&sm[HS0 + r*132 + e4] = x;
    }
    float hacc[5][8];
    #pragma unroll
    for (int i=0;i<5;i++){
        #pragma unroll
        for (int k=0;k<8;k++) hacc[i][k]=0.0f;
    }

    const float* Wl = in_w + (size_t)l*384*EE;
    const float* Bl = in_b + (size_t)l*384;
    const float* OwTl = owT + (size_t)l*EE*EE;
    int nb = t/12, cb = t - nb*12;
    int wv_ = t>>6, lw = t&63;
    int g3 = lw/3, th3 = lw - g3*3;
    int prA = wv_*21 + g3;                       // pair index (2 rows per thread)
    bool actA = (wv_<4) && (lw<63) && (prA<75);  // 4 waves x 21 pairs covers 75 pairs
    int nb5 = t>>4, ebx = t&15;

    for (int hd=0; hd<8; hd++){
        __syncthreads();
        for (int j=t; j<48*32; j+=512){
            int row=j>>5, e4=(j&31)*4;
            int which=row>>4, d=row&15;
            int grow = which*EE + hd*16 + d;
            float4 w4 = *(const float4*)(Wl + (size_t)grow*EE + e4);
            *(float4*)&sm[WS0 + row*132 + e4] = w4;
        }
        for (int j=t; j<16*32; j+=512){
            int d=j>>5, e4=(j&31)*4;
            float4 o4 = *(const float4*)(OwTl + (size_t)(hd*16+d)*EE + e4);
            *(float4*)&sm[OWS0 + d*132 + e4] = o4;
        }
        if (t<48){ int which=t>>4, d=t&15; sm[BIA0+t] = Bl[which*EE + hd*16 + d]; }
        __syncthreads();

        // qkv: 4n x 4c register tile, float4 K-groups (bit-identical order over e2)
        if (t<456){
            float acc[4][4];
            #pragma unroll
            for (int i=0;i<4;i++){
                #pragma unroll
                for (int j=0;j<4;j++) acc[i][j]=sm[BIA0+cb*4+j];
            }
            const float* hp0 = &sm[HS0 + nb*4*132];
            const float* wp0 = &sm[WS0 + cb*4*132];
            for (int e4=0;e4<32;e4++){
                float4 h0=*(const float4*)(hp0 + 4*e4);
                float4 h1=*(const float4*)(hp0 + 132 + 4*e4);
                float4 h2=*(const float4*)(hp0 + 264 + 4*e4);
                float4 h3=*(const float4*)(hp0 + 396 + 4*e4);
                float4 w0=*(const float4*)(wp0 + 4*e4);
                float4 w1=*(const float4*)(wp0 + 132 + 4*e4);
                float4 w2=*(const float4*)(wp0 + 264 + 4*e4);
                float4 w3=*(const float4*)(wp0 + 396 + 4*e4);
                acc[0][0]=fmaf(h0.w,w0.w,fmaf(h0.z,w0.z,fmaf(h0.y,w0.y,fmaf(h0.x,w0.x,acc[0][0]))));
                acc[0][1]=fmaf(h0.w,w1.w,fmaf(h0.z,w1.z,fmaf(h0.y,w1.y,fmaf(h0.x,w1.x,acc[0][1]))));
                acc[0][2]=fmaf(h0.w,w2.w,fmaf(h0.z,w2.z,fmaf(h0.y,w2.y,fmaf(h0.x,w2.x,acc[0][2]))));
                acc[0][3]=fmaf(h0.w,w3.w,fmaf(h0.z,w3.z,fmaf(h0.y,w3.y,fmaf(h0.x,w3.x,acc[0][3]))));
                acc[1][0]=fmaf(h1.w,w0.w,fmaf(h1.z,w0.z,fmaf(h1.y,w0.y,fmaf(h1.x,w0.x,acc[1][0]))));
                acc[1][1]=fmaf(h1.w,w1.w,fmaf(h1.z,w1.z,fmaf(h1.y,w1.y,fmaf(h1.x,w1.x,acc[1][1]))));
                acc[1][2]=fmaf(h1.w,w2.w,fmaf(h1.z,w2.z,fmaf(h1.y,w2.y,fmaf(h1.x,w2.x,acc[1][2]))));
                acc[1][3]=fmaf(h1.w,w3.w,fmaf(h1.z,w3.z,fmaf(h1.y,w3.y,fmaf(h1.x,w3.x,acc[1][3]))));
                acc[2][0]=fmaf(h2.w,w0.w,fmaf(h2.z,w0.z,fmaf(h2.y,w0.y,fmaf(h2.x,w0.x,acc[2][0]))));
                acc[2][1]=fmaf(h2.w,w1.w,fmaf(h2.z,w1.z,fmaf(h2.y,w1.y,fmaf(h2.x,w1.x,acc[2][1]))));
                acc[2][2]=fmaf(h2.w,w2.w,fmaf(h2.z,w2.z,fmaf(h2.y,w2.y,fmaf(h2.x,w2.x,acc[2][2]))));
                acc[2][3]=fmaf(h2.w,w3.w,fmaf(h2.z,w3.z,fmaf(h2.y,w3.y,fmaf(h2.x,w3.x,acc[2][3]))));
                acc[3][0]=fmaf(h3.w,w0.w,fmaf(h3.z,w0.z,fmaf(h3.y,w0.y,fmaf(h3.x,w0.x,acc[3][0]))));
                acc[3][1]=fmaf(h3.w,w1.w,fmaf(h3.z,w1.z,fmaf(h3.y,w1.y,fmaf(h3.x,w1.x,acc[3][1]))));
                acc[3][2]=fmaf(h3.w,w2.w,fmaf(h3.z,w2.z,fmaf(h3.y,w2.y,fmaf(h3.x,w2.x,acc[3][2]))));
                acc[3][3]=fmaf(h3.w,w3.w,fmaf(h3.z,w3.z,fmaf(h3.y,w3.y,fmaf(h3.x,w3.x,acc[3][3]))));
            }
            #pragma unroll
            for (int i=0;i<4;i++){
                int n=nb*4+i;
                if (n<150){
                    #pragma unroll
                    for (int j=0;j<4;j++){
                        int c=cb*4+j;
                        sm[QKV0 + (c>>4)*2400 + n*16 + (c&15)] = acc[i][j];
                    }
                }
            }
        }
        __syncthreads();

        // attention: 2 rows per thread, kk split in thirds of 50
        {
            float oA[16], oB[16];
            #pragma unroll
            for (int i=0;i<16;i++){ oA[i]=0.0f; oB[i]=0.0f; }
            float lsA=0.0f, lsB=0.0f;
            if (actA){
                int rA0 = prA*2, rA1 = prA*2+1;
                float4 qa0=*(const float4*)&sm[QKV0 + rA0*16 + 0];
                float4 qa1=*(const float4*)&sm[QKV0 + rA0*16 + 4];
                float4 qa2=*(const float4*)&sm[QKV0 + rA0*16 + 8];
                float4 qa3=*(const float4*)&sm[QKV0 + rA0*16 + 12];
                float4 qb0=*(const float4*)&sm[QKV0 + rA1*16 + 0];
                float4 qb1=*(const float4*)&sm[QKV0 + rA1*16 + 4];
                float4 qb2=*(const float4*)&sm[QKV0 + rA1*16 + 8];
                float4 qb3=*(const float4*)&sm[QKV0 + rA1*16 + 12];
                int k0=th3*50;
                for (int kk=k0; kk<k0+50; kk++){
                    const float* kb=&sm[QKV0+2400 + kk*16];
                    float4 ka=*(const float4*)kb;
                    float4 kb4=*(const float4*)(kb+4);
                    float4 kc=*(const float4*)(kb+8);
                    float4 kd=*(const float4*)(kb+12);
                    float sA = qa0.x*ka.x;
                    sA=fmaf(qa0.y,ka.y,sA); sA=fmaf(qa0.z,ka.z,sA); sA=fmaf(qa0.w,ka.w,sA);
                    sA=fmaf(qa1.x,kb4.x,sA); sA=fmaf(qa1.y,kb4.y,sA); sA=fmaf(qa1.z,kb4.z,sA); sA=fmaf(qa1.w,kb4.w,sA);
                    sA=fmaf(qa2.x,kc.x,sA); sA=fmaf(qa2.y,kc.y,sA); sA=fmaf(qa2.z,kc.z,sA); sA=fmaf(qa2.w,kc.w,sA);
                    sA=fmaf(qa3.x,kd.x,sA); sA=fmaf(qa3.y,kd.y,sA); sA=fmaf(qa3.z,kd.z,sA); sA=fmaf(qa3.w,kd.w,sA);
                    float sB = qb0.x*ka.x;
                    sB=fmaf(qb0.y,ka.y,sB); sB=fmaf(qb0.z,ka.z,sB); sB=fmaf(qb0.w,ka.w,sB);
                    sB=fmaf(qb1.x,kb4.x,sB); sB=fmaf(qb1.y,kb4.y,sB); sB=fmaf(qb1.z,kb4.z,sB); sB=fmaf(qb1.w,kb4.w,sB);
                    sB=fmaf(qb2.x,kc.x,sB); sB=fmaf(qb2.y,kc.y,sB); sB=fmaf(qb2.z,kc.z,sB); sB=fmaf(qb2.w,kc.w,sB);
                    sB=fmaf(qb3.x,kd.x,sB); sB=fmaf(qb3.y,kd.y,sB); sB=fmaf(qb3.z,kd.z,sB); sB=fmaf(qb3.w,kd.w,sB);
                    float pA=__expf(sA*0.25f);
                    float pB=__expf(sB*0.25f);
                    lsA+=pA; lsB+=pB;
                    const float* vb=&sm[QKV0+4800 + kk*16];
                    float4 va=*(const float4*)vb;
                    float4 v1=*(const float4*)(vb+4);
                    float4 v2=*(const float4*)(vb+8);
                    float4 v3=*(const float4*)(vb+12);
                    oA[0]=fmaf(pA,va.x,oA[0]); oA[1]=fmaf(pA,va.y,oA[1]); oA[2]=fmaf(pA,va.z,oA[2]); oA[3]=fmaf(pA,va.w,oA[3]);
                    oA[4]=fmaf(pA,v1.x,oA[4]); oA[5]=fmaf(pA,v1.y,oA[5]); oA[6]=fmaf(pA,v1.z,oA[6]); oA[7]=fmaf(pA,v1.w,oA[7]);
                    oA[8]=fmaf(pA,v2.x,oA[8]); oA[9]=fmaf(pA,v2.y,oA[9]); oA[10]=fmaf(pA,v2.z,oA[10]); oA[11]=fmaf(pA,v2.w,oA[11]);
                    oA[12]=fmaf(pA,v3.x,oA[12]); oA[13]=fmaf(pA,v3.y,oA[13]); oA[14]=fmaf(pA,v3.z,oA[14]); oA[15]=fmaf(pA,v3.w,oA[15]);
                    oB[0]=fmaf(pB,va.x,oB[0]); oB[1]=fmaf(pB,va.y,oB[1]); oB[2]=fmaf(pB,va.z,oB[2]); oB[3]=fmaf(pB,va.w,oB[3]);
                    oB[4]=fmaf(pB,v1.x,oB[4]); oB[5]=fmaf(pB,v1.y,oB[5]); oB[6]=fmaf(pB,v1.z,oB[6]); oB[7]=fmaf(pB,v1.w,oB[7]);
                    oB[8]=fmaf(pB,v2.x,oB[8]); oB[9]=fmaf(pB,v2.y,oB[9]); oB[10]=fmaf(pB,v2.z,oB[10]); oB[11]=fmaf(pB,v2.w,oB[11]);
                    oB[12]=fmaf(pB,v3.x,oB[12]); oB[13]=fmaf(pB,v3.y,oB[13]); oB[14]=fmaf(pB,v3.z,oB[14]); oB[15]=fmaf(pB,v3.w,oB[15]);
                }
            }
            float lsA1=__shfl_down(lsA,1), lsA2=__shfl_down(lsA,2);
            float lsB1=__shfl_down(lsB,1), lsB2=__shfl_down(lsB,2);
            float ocA[16], ocB[16];
            #pragma unroll
            for (int i=0;i<16;i++){
                float a1=__shfl_down(oA[i],1), a2=__shfl_down(oA[i],2);
                ocA[i]=(oA[i]+a1)+a2;
                float b1=__shfl_down(oB[i],1), b2=__shfl_down(oB[i],2);
                ocB[i]=(oB[i]+b1)+b2;
            }
            if (actA && th3==0){
                int rA0 = prA*2, rA1 = prA*2+1;
                float invA = 1.0f/((lsA+lsA1)+lsA2);
                float invB = 1.0f/((lsB+lsB1)+lsB2);
                #pragma unroll
                for (int d=0;d<16;d++){
                    sm[OH0 + rA0*17 + d] = ocA[d]*invA;
                    sm[OH0 + rA1*17 + d] = ocB[d]*invB;
                }
            }
        }
        __syncthreads();

        if (t<480){
            #pragma unroll
            for (int d=0; d<16; d++){
                float4 w0=*(const float4*)&sm[OWS0 + d*132 + ebx*8];
                float4 w1=*(const float4*)&sm[OWS0 + d*132 + ebx*8 + 4];
                #pragma unroll
                for (int i=0;i<5;i++){
                    float ov = sm[OH0 + (nb5*5+i)*17 + d];
                    hacc[i][0]=fmaf(ov,w0.x,hacc[i][0]);
                    hacc[i][1]=fmaf(ov,w0.y,hacc[i][1]);
                    hacc[i][2]=fmaf(ov,w0.z,hacc[i][2]);
                    hacc[i][3]=fmaf(ov,w0.w,hacc[i][3]);
                    hacc[i][4]=fmaf(ov,w1.x,hacc[i][4]);
                    hacc[i][5]=fmaf(ov,w1.y,hacc[i][5]);
                    hacc[i][6]=fmaf(ov,w1.z,hacc[i][6]);
                    hacc[i][7]=fmaf(ov,w1.w,hacc[i][7]);
                }
            }
        }
    }
    __syncthreads();
    if (t<480){
        float ob[8];
        *(float4*)&ob[0] = *(const float4*)(out_b + l*EE + ebx*8);
        *(float4*)&ob[4] = *(const float4*)(out_b + l*EE + ebx*8 + 4);
        float cs[8], cq[8];
        #pragma unroll
        for (int k=0;k<8;k++){ cs[k]=0.0f; cq[k]=0.0f; }
        #pragma unroll
        for (int i=0;i<5;i++){
            int r=nb5*5+i;
            float x[8];
            #pragma unroll
            for (int k2=0;k2<4;k2++){
                float2 hv=*(const float2*)&sm[HS0 + r*132 + ebx*8 + 2*k2];
                x[2*k2]   = hv.x + ob[2*k2]   + hacc[i][2*k2];
                x[2*k2+1] = hv.y + ob[2*k2+1] + hacc[i][2*k2+1];
            }
            h_store4(h + hbase + (size_t)r*EE + ebx*8,     make_float4(x[0],x[1],x[2],x[3]));
            h_store4(h + hbase + (size_t)r*EE + ebx*8 + 4, make_float4(x[4],x[5],x[6],x[7]));
            #pragma unroll
            for (int k=0;k<8;k++){ cs[k]+=x[k]; cq[k]+=x[k]*x[k]; }
        }
        #pragma unroll
        for (int k=0;k<8;k++){
            sm[PS0 + nb5*128 + ebx*8 + k]=cs[k];
            sm[PQ0 + nb5*128 + ebx*8 + k]=cq[k];
        }
    }
    __syncthreads();
    if (t<256){
        int e=t&127, hf=t>>7;
        float s=0.0f,q=0.0f;
        for (int nb_=hf*15; nb_<hf*15+15; nb_++){
            s+=sm[PS0+nb_*128+e]; q+=sm[PQ0+nb_*128+e];
        }
        sm[RS0+t]=s; sm[RQ0+t]=q;
    }
    __syncthreads();
    if (t<128){
        part[(size_t)b*256 + t]       = sm[RS0+t]+sm[RS0+128+t];
        part[(size_t)b*256 + 128 + t] = sm[RQ0+t]+sm[RQ0+128+t];
    }
}

// ---------------- fused FFN (legacy, fallback paths) ----------------
template<typename HT>
__global__ void k_ff(HT* __restrict__ h,
                     const float* __restrict__ w1, const float* __restrict__ b1,
                     const float* __restrict__ w2, const float* __restrict__ b2,
                     int l, float* __restrict__ part,
                     const float* __restrict__ scal, const float* __restrict__ shft){
    int bx=blockIdx.x, t=threadIdx.x;
    int row0=bx*16;
    __shared__ __align__(16) float xn[16][EE];
    __shared__ __align__(16) float f1[16][FFD];
    __shared__ float w2T[64][EE+1];
    const float* W1 = w1 + (size_t)l*FFD*EE;
    const float* W2 = w2 + (size_t)l*EE*FFD;
    for (int j=t;j<16*EE;j+=256){
        int r=j>>7,e=j&127;
        xn[r][e]=fmaf(h_load(h + (size_t)(row0+r)*EE+e), scal[e], shft[e]);
    }
    __syncthreads();
    for (int fi=0;fi<2;fi++){
        int f=t+fi*256;
        const float4* wr = (const float4*)(W1 + (size_t)f*EE);
        float bias = b1[l*FFD+f];
        float acc[16];
        #pragma unroll
        for (int r=0;r<16;r++) acc[r]=bias;
        for (int e4=0;e4<32;e4++){
            float4 w=wr[e4];
            #pragma unroll
            for (int r=0;r<16;r++){
                float4 x=*(const float4*)&xn[r][4*e4];
                acc[r] += x.x*w.x + x.y*w.y + x.z*w.z + x.w*w.w;
            }
        }
        #pragma unroll
        for (int r=0;r<16;r++) f1[r][f]=fmaxf(acc[r],0.0f);
    }
    int e=t&127, rh=t>>7;
    float acc2[8];
    #pragma unroll
    for (int i=0;i<8;i++) acc2[i]=0.0f;
    for (int fc=0; fc<FFD; fc+=64){
        __syncthreads();
        for (int j=t;j<64*EE;j+=256){ int e_=j>>6, fl=j&63; w2T[fl][e_]=W2[(size_t)e_*FFD+fc+fl]; }
        __syncthreads();
        for (int fl=0;fl<64;fl++){
            float w=w2T[fl][e];
            #pragma unroll
            for (int i=0;i<8;i++) acc2[i] = fmaf(f1[rh*8+i][fc+fl], w, acc2[i]);
        }
    }
    float bias = b2[l*EE+e];
    float s=0.0f,q=0.0f;
    #pragma unroll
    for (int i=0;i<8;i++){
        float x = xn[rh*8+i][e] + bias + acc2[i];
        h_store(h + (size_t)(row0+rh*8+i)*EE+e, x);
        s+=x; q+=x*x;
    }
    __shared__ float rs[256], rq[256];
    rs[t]=s; rq[t]=q; __syncthreads();
    if (rh==0){
        part[(size_t)bx*256+e]=rs[t]+rs[t+128];
        part[(size_t)bx*256+128+e]=rq[t]+rq[t+128];
    }
}

// ---------------- fused FFN v2: transposed weights, coalesced, 2 barriers ----------------
template<typename HT>
__launch_bounds__(256,4)
__global__ void k_ff2(HT* __restrict__ h,
                      const float* __restrict__ w1T, const float* __restrict__ b1,
                      const float* __restrict__ w2Tg, const float* __restrict__ b2,
                      int l, float* __restrict__ part,
                      const float* __restrict__ scal, const float* __restrict__ shft){
    int bx=blockIdx.x, t=threadIdx.x;
    int row0=bx*16;
    __shared__ __align__(16) float xn[16][EE];    // 8 KB
    __shared__ __align__(16) float f1[16][FFD];   // 32 KB
    const float* W1T = w1T + (size_t)l*65536;     // [e][f]
    const float* W2T = w2Tg + (size_t)l*65536;    // [fl][e]
    for (int j=t;j<16*EE;j+=256){
        int r=j>>7,e=j&127;
        xn[r][e]=fmaf(h_load(h + (size_t)(row0+r)*EE+e), scal[e], shft[e]);
    }
    __syncthreads();
    #pragma unroll
    for (int fi=0;fi<2;fi++){
        int f=t+fi*256;
        float bias = b1[l*FFD+f];
        float acc[16];
        #pragma unroll
        for (int r=0;r<16;r++) acc[r]=bias;
        #pragma unroll 4
        for (int e=0;e<EE;e++){
            float w = W1T[(size_t)e*FFD + f];
            #pragma unroll
            for (int r=0;r<16;r++) acc[r]=fmaf(xn[r][e], w, acc[r]);
        }
        #pragma unroll
        for (int r=0;r<16;r++) f1[r][f]=fmaxf(acc[r],0.0f);
    }
    __syncthreads();
    int e=t&127, rh=t>>7;
    float acc2[8];
    #pragma unroll
    for (int i=0;i<8;i++) acc2[i]=0.0f;
    #pragma unroll 4
    for (int fl=0; fl<FFD; fl++){
        float w = W2T[(size_t)fl*EE + e];
        #pragma unroll
        for (int i=0;i<8;i++) acc2[i] = fmaf(f1[rh*8+i][fl], w, acc2[i]);
    }
    float bias = b2[l*EE+e];
    float s=0.0f,q=0.0f;
    #pragma unroll
    for (int i=0;i<8;i++){
        float x = xn[rh*8+i][e] + bias + acc2[i];
        h_store(h + (size_t)(row0+rh*8+i)*EE+e, x);
        s+=x; q+=x*x;
    }
    __shared__ float rs[256], rq[256];
    rs[t]=s; rq[t]=q; __syncthreads();
    if (rh==0){
        part[(size_t)bx*256+e]=rs[t]+rs[t+128];
        part[(size_t)bx*256+128+e]=rq[t]+rq[t+128];
    }
}

// ---------------- G_ih precompute ----------------
template<typename HT>
__launch_bounds__(512)
__global__ void k_gih(const HT* __restrict__ h, const float* __restrict__ wihT,
                      const float* __restrict__ scal, const float* __restrict__ shft,
                      float* __restrict__ G, int b0){
    __shared__ float xn[NN][132];
    int bl = blockIdx.x, t = threadIdx.x;
    const size_t hbase = (size_t)(b0+bl)*NN*EE;
    for (int j=t; j<NN*32; j+=512){
        int r=j>>5, e4=(j&31)*4;
        float4 x = h_load4(h + hbase + (size_t)r*EE + e4);
        float4 sc4=*(const float4*)(scal+e4), sh4=*(const float4*)(shft+e4);
        x.x=fmaf(x.x,sc4.x,sh4.x); x.y=fmaf(x.y,sc4.y,sh4.y);
        x.z=fmaf(x.z,sc4.z,sh4.z); x.w=fmaf(x.w,sc4.w,sh4.w);
        *(float4*)&xn[r][e4]=x;
    }
    __syncthreads();
    float* Gb = G + (size_t)bl*NN*512;
    const float* wcol = wihT + t;
    for (int nb=0; nb<10; nb++){
        float acc[15];
        #pragma unroll
        for (int j=0;j<15;j++) acc[j]=0.0f;
        #pragma unroll 4
        for (int e=0;e<128;e++){
            float w = wcol[(size_t)e*512];
            #pragma unroll
            for (int j=0;j<15;j++) acc[j]=fmaf(xn[nb*15+j][e], w, acc[j]);
        }
        #pragma unroll
        for (int j=0;j<15;j++) Gb[(size_t)(nb*15+j)*512+t]=acc[j];
    }
}

// ---------------- shared decoder LDS layout ----------------
#define EWQ    19200
#define DGTS   38400
#define D_DD   39424
#define D_HH   39680
#define D_HW2  39936
#define D_PVS  40192
#define D_SCS  40320
#define D_SHS  40448
#define D_TOT  40576

// ---------------- decoder v2i (fallback, ws mid) ----------------
template<typename HT>
__launch_bounds__(1024,4)
__global__ void k_decoder2(const HT* __restrict__ enc, const float* __restrict__ inp,
        const float* __restrict__ wih_p, const float* __restrict__ whh_p,
        const float* __restrict__ bih, const float* __restrict__ bhh,
        const float* __restrict__ pw1T, const float* __restrict__ pb1,
        const float* __restrict__ pw2T, const float* __restrict__ pb2,
        const float* __restrict__ pv, const float* __restrict__ pbv,
        const float* __restrict__ scal, const float* __restrict__ shft,
        float* __restrict__ out){
    __shared__ float smf[D_TOT];
    __shared__ unsigned char schna[608];
    const int t = threadIdx.x;
    const int q = t>>9, r = t&511;
    const int b0 = blockIdx.x*2;
    const HT* encq = enc + (size_t)(b0+q)*NN*EE;

    if (t<128){ smf[D_PVS+t]=pv[t]; smf[D_SCS+t]=scal[t]; smf[D_SHS+t]=shft[t]; }
    if (t<512) smf[D_DD+t]=0.0f;
    if (t<304){
        int qq=t/152, n=t-qq*152;
        schna[qq*304+n]=0;
        unsigned char nav=1;
        if (n<150) nav = (inp[((size_t)(b0+qq)*NN+n)*4+1] != 0.0f) ? 1 : 0;
        schna[qq*304+152+n]=nav;
    }
    const int g = t>>1, kh = t&1;
    const float bsum = bih[g] + bhh[g];
    const float pb2r = (t<256) ? pb2[t&127] : 0.0f;
    const float pbvr = pbv[0];

    float4 whr[16];
    {
        const float4* wp = (const float4*)whh_p + t;
        #pragma unroll
        for (int i=0;i<16;i++) whr[i] = wp[(size_t)i*1024];
    }
    __syncthreads();

    {
        const int e = r&127, ng = r>>7;
        const float pb1e = pb1[e];
        for (int n1 = ng; n1 < 150; n1 += 8){
            int n2 = n1+4;
            bool has2 = (n2<150);
            int n2c = has2 ? n2 : n1;
            float a1=0.0f, a2=0.0f;
            #pragma unroll 4
            for (int e2=0;e2<EE;e2++){
                float w = pw1T[e2*EE + e];
                float x1 = fmaf(smf[D_SCS+e2], h_load(encq + (size_t)n1*EE + e2), smf[D_SHS+e2]);
                float x2 = fmaf(smf[D_SCS+e2], h_load(encq + (size_t)n2c*EE + e2), smf[D_SHS+e2]);
                a1 = fmaf(x1, w, a1);
                a2 = fmaf(x2, w, a2);
            }
            smf[q*EWQ + n1*128 + (e ^ (n1&31))] = a1 + pb1e;
            if (has2) smf[q*EWQ + n2*128 + (e ^ (n2&31))] = a2 + pb1e;
        }
    }
    if (t<512){
        int qq=t>>8, rr=t&255, e=rr&127, hf=rr>>7;
        const HT* eb = enc + (size_t)(b0+qq)*NN*EE;
        float s=0.0f;
        for (int n=hf*75;n<hf*75+75;n++) s += h_load(eb + (size_t)n*EE+e);
        smf[DGTS + qq*256 + hf*128 + e] = s;
    }
    __syncthreads();
    float c_reg = 0.0f;
    if (t<256){
        int qq=t>>7, e=t&127;
        float mean = (smf[DGTS+qq*256+e]+smf[DGTS+qq*256+128+e])*(1.0f/150.0f);
        c_reg = fmaf(smf[D_SCS+e], mean, smf[D_SHS+e]);
    }
    __syncthreads();

    float llacc=0.0f;
    const float4* wip = (const float4*)wih_p + t;
    for (int step=0; step<NN; step++){
        {
            float a0=0.0f, a1=0.0f;
            const float* d0 = &smf[D_DD + kh*64];
            const float* d1 = &smf[D_DD + 128 + kh*64];
            const float* h0 = &smf[D_HH + kh*64];
            const float* h1 = &smf[D_HH + 128 + kh*64];
            #pragma unroll 8
            for (int i=0;i<16;i++){
                float4 wv = wip[(size_t)i*1024];
                float4 wh = whr[i];
                float4 x0 = *(const float4*)(d0 + 4*i);
                float4 x1 = *(const float4*)(d1 + 4*i);
                float4 y0 = *(const float4*)(h0 + 4*i);
                float4 y1 = *(const float4*)(h1 + 4*i);
                a0 = fmaf(wv.w,x0.w,fmaf(wv.z,x0.z,fmaf(wv.y,x0.y,fmaf(wv.x,x0.x,a0))));
                a0 = fmaf(wh.w,y0.w,fmaf(wh.z,y0.z,fmaf(wh.y,y0.y,fmaf(wh.x,y0.x,a0))));
                a1 = fmaf(wv.w,x1.w,fmaf(wv.z,x1.z,fmaf(wv.y,x1.y,fmaf(wv.x,x1.x,a1))));
                a1 = fmaf(wh.w,y1.w,fmaf(wh.z,y1.z,fmaf(wh.y,y1.y,fmaf(wh.x,y1.x,a1))));
            }
            a0 += __shfl_xor(a0,1);
            a1 += __shfl_xor(a1,1);
            if (kh==0){
                smf[DGTS + g]       = a0 + bsum;
                smf[DGTS + 512 + g] = a1 + bsum;
            }
        }
        __syncthreads();
        if (t<256){
            int qq=t>>7, e=t&127;
            const float* gt = &smf[DGTS + qq*512];
            float gi=fsig(gt[e]), gf=fsig(gt[128+e]), gg=ftanh(gt[256+e]), go=fsig(gt[384+e]);
            c_reg = gf*c_reg + gi*gg;
            smf[D_HH + qq*128 + e] = go*ftanh(c_reg);
        }
        __syncthreads();
        if (t<256){
            int qq=t>>7, e=t&127;
            float s2=0.0f;
            #pragma unroll 4
            for (int e2=0;e2<EE;e2++)
                s2 = fmaf(pw2T[e2*EE + e], smf[D_HH + qq*128 + e2], s2);
            smf[D_HW2 + qq*128 + e] = s2 + pb2r;
        }
        __syncthreads();
        {
            int half = r>>8, n = r&255;
            if (n<150){
                float p=0.0f;
                const float* ewn = &smf[q*EWQ + n*128];
                const float* hwq = &smf[D_HW2 + q*128];
                int sw = n&31;
                #pragma unroll 8
                for (int e2=0;e2<64;e2++){
                    int e = half*64+e2;
                    p = fmaf(ftanh(ewn[e ^ sw] + hwq[e]), smf[D_PVS+e], p);
                }
                smf[DGTS + (q*2+half)*152 + n] = p;
            }
        }
        __syncthreads();
        if (t<128){
            int qq=t>>6, l=t&63;
            const unsigned char* sc_ = &schna[qq*304];
            const float* pp = &smf[DGTS + qq*2*152];
            int n0=l, n1=l+64, n2=l+128;
            float a0 = pp[n0]+pp[152+n0]+pbvr;
            float a1 = pp[n1]+pp[152+n1]+pbvr;
            float v0 = (sc_[n0]|sc_[152+n0]) ? -10000.0f : a0;
            float v1 = (sc_[n1]|sc_[152+n1]) ? -10000.0f : a1;
            float v2 = -1e30f;
            if (n2<NN){
                float a2 = pp[n2]+pp[152+n2]+pbvr;
                v2 = (sc_[n2]|sc_[152+n2]) ? -10000.0f : a2;
            }
            float m=v0; int mi=n0;
            if (v1>m){ m=v1; mi=n1; }
            if (n2<NN && v2>m){ m=v2; mi=n2; }
            #pragma unroll
            for (int off=1; off<64; off<<=1){
                float om=__shfl_xor(m,off); int oi=__shfl_xor(mi,off);
                if (om>m || (om==m && oi<mi)){ m=om; mi=oi; }
            }
            float se = __expf(v0-m)+__expf(v1-m) + ((n2<NN)? __expf(v2-m):0.0f);
            #pragma unroll
            for (int off=1; off<64; off<<=1) se += __shfl_xor(se,off);
            const HT* eb = enc + (size_t)(b0+qq)*NN*EE;
            if (l==0){
                llacc -= logf(se);
                schna[qq*304+mi]=1;
                int nn2 = mi+1; if (nn2>NN-1) nn2=NN-1;
                schna[qq*304+152+nn2]=0;
                float4 rowv = *(const float4*)(inp + ((size_t)(b0+qq)*NN+mi)*4);
                *(float4*)(out + ((size_t)(b0+qq)*NN+step)*4) = rowv;
            }
            float eva = h_load(eb + (size_t)mi*EE + l);
            float evb = h_load(eb + (size_t)mi*EE + l + 64);
            smf[D_DD + qq*128 + l]      = fmaf(smf[D_SCS+l],    eva, smf[D_SHS+l]);
            smf[D_DD + qq*128 + l + 64] = fmaf(smf[D_SCS+l+64], evb, smf[D_SHS+l+64]);
        }
        __syncthreads();
    }
    if (t==0)  out[(size_t)BB*NN*4 + b0]   = llacc;
    if (t==64) out[(size_t)BB*NN*4 + b0+1] = llacc;
}

// ---------------- decoder G5: 1024 threads, G-lookup, streamed Whh only ----------------
template<typename HT>
__launch_bounds__(1024,4)
__global__ void k_decoderG5(const HT* __restrict__ enc, const float* __restrict__ inp,
        const float* __restrict__ whh_p, const float* __restrict__ Gih,
        const float* __restrict__ bih, const float* __restrict__ bhh,
        const float* __restrict__ pw1T, const float* __restrict__ pb1,
        const float* __restrict__ pw2T, const float* __restrict__ pb2,
        const float* __restrict__ pv, const float* __restrict__ pbv,
        const float* __restrict__ scal, const float* __restrict__ shft,
        float* __restrict__ out, int passb0){
    __shared__ float smf[D_TOT];
    __shared__ unsigned char schna[608];
    __shared__ int predS2[2];
    const int t = threadIdx.x;
    const int q = t>>9, r = t&511;
    const int b0 = passb0 + blockIdx.x*2;
    const HT* encq = enc + (size_t)(b0+q)*NN*EE;

    if (t<128){ smf[D_PVS+t]=pv[t]; smf[D_SCS+t]=scal[t]; smf[D_SHS+t]=shft[t]; }
    if (t<256) smf[D_HH+t]=0.0f;
    if (t<304){
        int qq=t/152, n=t-qq*152;
        schna[qq*304+n]=0;
        unsigned char nav=1;
        if (n<150) nav = (inp[((size_t)(b0+qq)*NN+n)*4+1] != 0.0f) ? 1 : 0;
        schna[qq*304+152+n]=nav;
    }
    if (t<2) predS2[t]=-1;
    const int g = t>>1, kh = t&1;
    const float bsum = bih[g] + bhh[g];
    const float pb2r = (t<256) ? pb2[t&127] : 0.0f;
    const float pbvr = pbv[0];
    __syncthreads();

    {
        const int e = r&127, ng = r>>7;
        const float pb1e = pb1[e];
        for (int n1 = ng; n1 < 150; n1 += 8){
            int n2 = n1+4;
            bool has2 = (n2<150);
            int n2c = has2 ? n2 : n1;
            float a1=0.0f, a2=0.0f;
            #pragma unroll 4
            for (int e2=0;e2<EE;e2++){
                float w = pw1T[e2*EE + e];
                float x1 = fmaf(smf[D_SCS+e2], h_load(encq + (size_t)n1*EE + e2), smf[D_SHS+e2]);
                float x2 = fmaf(smf[D_SCS+e2], h_load(encq + (size_t)n2c*EE + e2), smf[D_SHS+e2]);
                a1 = fmaf(x1, w, a1);
                a2 = fmaf(x2, w, a2);
            }
            smf[q*EWQ + n1*128 + (e ^ (n1&31))] = a1 + pb1e;
            if (has2) smf[q*EWQ + n2*128 + (e ^ (n2&31))] = a2 + pb1e;
        }
    }
    if (t<512){
        int qq=t>>8, rr=t&255, e=rr&127, hf=rr>>7;
        const HT* eb = enc + (size_t)(b0+qq)*NN*EE;
        float s=0.0f;
        for (int n=hf*75;n<hf*75+75;n++) s += h_load(eb + (size_t)n*EE+e);
        smf[DGTS + qq*256 + hf*128 + e] = s;
    }
    __syncthreads();
    float c_reg = 0.0f;
    if (t<256){
        int qq=t>>7, e=t&127;
        float mean = (smf[DGTS+qq*256+e]+smf[DGTS+qq*256+128+e])*(1.0f/150.0f);
        c_reg = fmaf(smf[D_SCS+e], mean, smf[D_SHS+e]);
    }
    __syncthreads();

    float llacc=0.0f;
    const float* Gb0 = Gih + (size_t)(blockIdx.x*2)*NN*512;
    const float* Gb1 = Gih + (size_t)(blockIdx.x*2+1)*NN*512;
    const float4* whp = (const float4*)whh_p + t;
    for (int step=0; step<NN; step++){
        {
            float a0=0.0f, a1=0.0f;
            const float* h0 = &smf[D_HH + kh*64];
            const float* h1 = &smf[D_HH + 128 + kh*64];
            #pragma unroll 8
            for (int i=0;i<16;i++){
                float4 wh = whp[(size_t)i*1024];
                float4 y0 = *(const float4*)(h0 + 4*i);
                float4 y1 = *(const float4*)(h1 + 4*i);
                a0 = fmaf(wh.w,y0.w,fmaf(wh.z,y0.z,fmaf(wh.y,y0.y,fmaf(wh.x,y0.x,a0))));
                a1 = fmaf(wh.w,y1.w,fmaf(wh.z,y1.z,fmaf(wh.y,y1.y,fmaf(wh.x,y1.x,a1))));
            }
            a0 += __shfl_xor(a0,1);
            a1 += __shfl_xor(a1,1);
            if (kh==0){
                int p0=predS2[0], p1=predS2[1];
                float ga = (p0>=0) ? Gb0[(size_t)p0*512 + g] : 0.0f;
                float gb = (p1>=0) ? Gb1[(size_t)p1*512 + g] : 0.0f;
                smf[DGTS + g]       = a0 + bsum + ga;
                smf[DGTS + 512 + g] = a1 + bsum + gb;
            }
        }
        __syncthreads();
        if (t<256){
            int qq=t>>7, e=t&127;
            const float* gt = &smf[DGTS + qq*512];
            float gi=fsig(gt[e]), gf=fsig(gt[128+e]), gg=ftanh(gt[256+e]), go=fsig(gt[384+e]);
            c_reg = gf*c_reg + gi*gg;
            smf[D_HH + qq*128 + e] = go*ftanh(c_reg);
        }
        __syncthreads();
        if (t<256){
            int qq=t>>7, e=t&127;
            float s2=0.0f;
            #pragma unroll 4
            for (int e2=0;e2<EE;e2++)
                s2 = fmaf(pw2T[e2*EE + e], smf[D_HH + qq*128 + e2], s2);
            smf[D_HW2 + qq*128 + e] = s2 + pb2r;
        }
        __syncthreads();
        {
            int half = r>>8, n = r&255;
            if (n<150){
                float p=0.0f;
                const float* ewn = &smf[q*EWQ + n*128];
                const float* hwq = &smf[D_HW2 + q*128];
                int sw = n&31;
                #pragma unroll 8
                for (int e2=0;e2<64;e2++){
                    int e = half*64+e2;
                    p = fmaf(ftanh(ewn[e ^ sw] + hwq[e]), smf[D_PVS+e], p);
                }
                smf[DGTS + (q*2+half)*152 + n] = p;
            }
        }
        __syncthreads();
        if (t<128){
            int qq=t>>6, l=t&63;
            const unsigned char* sc_ = &schna[qq*304];
            const float* pp = &smf[DGTS + qq*2*152];
            int n0=l, n1=l+64, n2=l+128;
            float a0 = pp[n0]+pp[152+n0]+pbvr;
            float a1 = pp[n1]+pp[152+n1]+pbvr;
            float v0 = (sc_[n0]|sc_[152+n0]) ? -10000.0f : a0;
            float v1 = (sc_[n1]|sc_[152+n1]) ? -10000.0f : a1;
            float v2 = -1e30f;
            if (n2<NN){
                float a2 = pp[n2]+pp[152+n2]+pbvr;
                v2 = (sc_[n2]|sc_[152+n2]) ? -10000.0f : a2;
            }
            float m=v0; int mi=n0;
            if (v1>m){ m=v1; mi=n1; }
            if (n2<NN && v2>m){ m=v2; mi=n2; }
            #pragma unroll
            for (int off=1; off<64; off<<=1){
                float om=__shfl_xor(m,off); int oi=__shfl_xor(mi,off);
                if (om>m || (om==m && oi<mi)){ m=om; mi=oi; }
            }
            float se = __expf(v0-m)+__expf(v1-m) + ((n2<NN)? __expf(v2-m):0.0f);
            #pragma unroll
            for (int off=1; off<64; off<<=1) se += __shfl_xor(se,off);
            if (l==0){
                llacc -= logf(se);
                predS2[qq]=mi;
                schna[qq*304+mi]=1;
                int nn2 = mi+1; if (nn2>NN-1) nn2=NN-1;
                schna[qq*304+152+nn2]=0;
                float4 rowv = *(const float4*)(inp + ((size_t)(b0+qq)*NN+mi)*4);
                *(float4*)(out + ((size_t)(b0+qq)*NN+step)*4) = rowv;
            }
        }
        __syncthreads();
    }
    if (t==0)  out[(size_t)BB*NN*4 + b0]   = llacc;
    if (t==64) out[(size_t)BB*NN*4 + b0+1] = llacc;
}

// ---------------- host schedule ----------------
template<typename HT>
static void run_model(void* const* d_in, void* d_out, void* d_ws, bool big, hipStream_t stream){
    const float* inp   = (const float*)d_in[0];
    const float* opg   = (const float*)d_in[1];
    const float* opb   = (const float*)d_in[2];
    const float* opW   = (const float*)d_in[3];
    const float* opB   = (const float*)d_in[4];
    const float* mtg   = (const float*)d_in[5];
    const float* mtb   = (const float*)d_in[6];
    const float* mtW   = (const float*)d_in[7];
    const float* mtB   = (const float*)d_in[8];
    const float* e0g   = (const float*)d_in[9];
    const float* e0b   = (const float*)d_in[10];
    const float* in_w  = (const float*)d_in[11];
    const float* in_b  = (const float*)d_in[12];
    const float* out_w = (const float*)d_in[13];
    const float* out_b = (const float*)d_in[14];
    const float* bn1g  = (const float*)d_in[15];
    const float* bn1b  = (const float*)d_in[16];
    const float* ffw1  = (const float*)d_in[17];
    const float* ffb1  = (const float*)d_in[18];
    const float* ffw2  = (const float*)d_in[19];
    const float* ffb2  = (const float*)d_in[20];
    const float* bn2g  = (const float*)d_in[21];
    const float* bn2b  = (const float*)d_in[22];
    const float* Wih   = (const float*)d_in[23];
    const float* Whh   = (const float*)d_in[24];
    const float* bihp  = (const float*)d_in[25];
    const float* bhhp  = (const float*)d_in[26];
    const float* pw1   = (const float*)d_in[27];
    const float* pb1   = (const float*)d_in[28];
    const float* pw2   = (const float*)d_in[29];
    const float* pb2   = (const float*)d_in[30];
    const float* pv    = (const float*)d_in[31];
    const float* pbv   = (const float*)d_in[32];
    float* out = (float*)d_out;

    HT* h = (HT*)d_ws;
    float* Xf = (float*)((char*)d_ws + (size_t)RTOT*EE*sizeof(HT));
    float* part  = Xf;                    // 2457600
    float* cwcb  = Xf + 2457600;          // 640
    float* scal  = cwcb + 640;
    float* shft  = scal + 128;
    float* wih_p = shft + 128;            // 65536
    float* whh_p = wih_p + 65536;         // 65536
    float* pw1T  = whh_p + 65536;         // 16384
    float* pw2Tg = pw1T + 16384;          // 16384
    float* owT   = pw2Tg + 16384;         // 49152
    float* part2 = owT + 49152;           // 15360
    float* wihT  = part2 + 15360;         // 65536 (big only)
    float* G     = wihT + 65536;          // 39,321,600 (big only)
    float* w1T   = G;                     // 196608 (dead until k_gih)
    float* w2Tg  = G + 196608;            // 196608

    k_prep2<<<256,256,0,stream>>>(Wih, Whh, pw1, pw2, out_w, wih_p, whh_p, pw1T, pw2Tg, owT);
    if (big){
        k_prep3<<<256,256,0,stream>>>(Wih, wihT);
        k_prep4<<<768,256,0,stream>>>(ffw1, ffw2, w1T, w2Tg);
    }
    k_inp_stats<<<600,256,0,stream>>>(inp, part);
    k_inp_final<<<1,128,0,stream>>>(part, opg,opb,opW,opB, mtg,mtb,mtW,mtB, cwcb);
    k_embed<HT><<<2400,256,0,stream>>>(inp, cwcb, h, part);
    k_bn_mid<<<60,256,0,stream>>>(part, 2400, part2);
    k_bn_fin<<<1,256,0,stream>>>(part2, e0g, e0b, scal, shft);
    for (int l=0;l<NL;l++){
        k_mha<HT><<<1024,512,0,stream>>>(h, in_w, in_b, owT, out_b, l, part, scal, shft);
        k_bn_mid<<<60,256,0,stream>>>(part, 1024, part2);
        k_bn_fin<<<1,256,0,stream>>>(part2, bn1g + l*EE, bn1b + l*EE, scal, shft);
        if (big){
            k_ff2<HT><<<9600,256,0,stream>>>(h, w1T, ffb1, w2Tg, ffb2, l, part, scal, shft);
        } else {
            k_ff<HT><<<9600,256,0,stream>>>(h, ffw1, ffb1, ffw2, ffb2, l, part, scal, shft);
        }
        k_bn_mid<<<60,256,0,stream>>>(part, 9600, part2);
        k_bn_fin<<<1,256,0,stream>>>(part2, bn2g + l*EE, bn2b + l*EE, scal, shft);
    }
    if (big){
        for (int pass=0; pass<2; pass++){
            k_gih<HT><<<512,512,0,stream>>>(h, wihT, scal, shft, G, pass*512);
            k_decoderG5<HT><<<256,1024,0,stream>>>(h, inp, whh_p, G, bihp, bhhp,
                                                   pw1T, pb1, pw2Tg, pb2, pv, pbv,
                                                   scal, shft, out, pass*512);
        }
    } else {
        k_decoder2<HT><<<512,1024,0,stream>>>(h, inp, wih_p, whh_p, bihp, bhhp,
                                              pw1T, pb1, pw2Tg, pb2, pv, pbv,
                                              scal, shft, out);
    }
}

extern "C" void kernel_launch(void* const* d_in, const int* in_sizes, int n_in,
                              void* d_out, int out_size, void* d_ws, size_t ws_size,
                              hipStream_t stream){
    const size_t xf_floats = 2457600u + 640 + 128 + 128 + 65536 + 65536 + 16384 + 16384 + 49152 + 15360;
    const size_t need_A   = (size_t)RTOT*EE*4 + xf_floats*4ull;
    const size_t need_big = need_A + (size_t)(65536 + 39321600)*4ull;
    if (ws_size >= need_big){
        run_model<float>(d_in, d_out, d_ws, true, stream);
    } else if (ws_size >= need_A){
        run_model<float>(d_in, d_out, d_ws, false, stream);
    } else {
        run_model<f16>(d_in, d_out, d_ws, false, stream);
    }
    (void)in_sizes; (void)n_in; (void)out_size; (void)ws_size;
}

// Round 15
// 9224.088 us; speedup vs baseline: 1.3532x; 1.0394x over previous
//
#include <hip/hip_runtime.h>
#include <math.h>

#define BB 1024
#define NN 150
#define RTOT (BB*NN)
#define EE 128
#define FFD 512
#define NL 3

typedef unsigned short u16;
typedef unsigned int u32;
typedef _Float16 f16;
typedef _Float16 f16x4 __attribute__((ext_vector_type(4)));

__device__ __forceinline__ float fsig(float x){ return __builtin_amdgcn_rcpf(1.0f + __expf(-x)); }
__device__ __forceinline__ float ftanh(float x){ return 1.0f - 2.0f*__builtin_amdgcn_rcpf(1.0f + __expf(2.0f*x)); }

// ---- h storage accessors ----
__device__ __forceinline__ float4 h_load4(const float* p){ return *(const float4*)p; }
__device__ __forceinline__ float4 h_load4(const f16* p){
    f16x4 v = *(const f16x4*)p;
    return make_float4((float)v.x,(float)v.y,(float)v.z,(float)v.w);
}
__device__ __forceinline__ void h_store4(float* p, float4 v){ *(float4*)p = v; }
__device__ __forceinline__ void h_store4(f16* p, float4 v){
    f16x4 o; o.x=(f16)v.x; o.y=(f16)v.y; o.z=(f16)v.z; o.w=(f16)v.w;
    *(f16x4*)p = o;
}
__device__ __forceinline__ float h_load(const float* p){ return *p; }
__device__ __forceinline__ float h_load(const f16* p){ return (float)*p; }
__device__ __forceinline__ void h_store(float* p, float v){ *p = v; }
__device__ __forceinline__ void h_store(f16* p, float v){ *p = (f16)v; }

// ---------------- prep: weight transposes/packs ----------------
__global__ void k_prep2(const float* __restrict__ Wih, const float* __restrict__ Whh,
                        const float* __restrict__ pw1, const float* __restrict__ pw2,
                        const float* __restrict__ out_w,
                        float* __restrict__ wih_p, float* __restrict__ whh_p,
                        float* __restrict__ pw1T, float* __restrict__ pw2T,
                        float* __restrict__ owT){
    int idx = blockIdx.x*256 + threadIdx.x;   // 65536 total
    {
        int f4 = idx>>2, c = idx&3;
        int i = f4>>10, tt = f4&1023;
        int g = tt>>1, kh = tt&1;
        int col = kh*64 + i*4 + c;
        wih_p[idx] = Wih[(size_t)g*128 + col];
        whh_p[idx] = Whh[(size_t)g*128 + col];
    }
    if (idx < 16384){
        int e = idx>>7, e2 = idx&127;
        pw1T[e2*128+e] = pw1[idx];
        pw2T[e2*128+e] = pw2[idx];
    }
    if (idx < 49152){
        int l = idx>>14, r = (idx>>7)&127, d = idx&127;
        owT[(size_t)l*16384 + d*128 + r] = out_w[idx];
    }
}

// big-ws extras: wihT[e][g] for the G GEMM; whh_f full-row pack:
// whh_f[(i*512 + g)*4 + c] = Whh[g][i*4+c]  (thread g reads float4 i at stride 512)
__global__ void k_prep3(const float* __restrict__ Wih, const float* __restrict__ Whh,
                        float* __restrict__ wihT, float* __restrict__ whh_f){
    int idx = blockIdx.x*256 + threadIdx.x;   // 65536
    int g = idx>>7, e = idx&127;
    wihT[(size_t)e*512 + g] = Wih[idx];
    whh_f[((size_t)(e>>2)*512 + g)*4 + (e&3)] = Whh[idx];
}

// big-ws extra: FFN weight transposes into the (currently dead) G region
__global__ void k_prep4(const float* __restrict__ ffw1, const float* __restrict__ ffw2,
                        float* __restrict__ w1T, float* __restrict__ w2Tg){
    int idx = blockIdx.x*256 + threadIdx.x;   // 196608
    int l = idx >> 16, r = idx & 65535;
    {
        int e = r>>9, f = r&511;
        w1T[idx] = ffw1[(size_t)l*65536 + (size_t)f*128 + e];
    }
    {
        int fl = r>>7, e2 = r&127;
        w2Tg[idx] = ffw2[(size_t)l*65536 + (size_t)e2*512 + fl];
    }
}

// ---------------- input 4-channel stats ----------------
__global__ void k_inp_stats(const float* __restrict__ inp, float* __restrict__ part){
    int t = threadIdx.x;
    int row = blockIdx.x*256 + t;
    float4 u = *(const float4*)(inp + (size_t)row*4);
    __shared__ float red[256][8];
    red[t][0]=u.x; red[t][1]=u.y; red[t][2]=u.z; red[t][3]=u.w;
    red[t][4]=u.x*u.x; red[t][5]=u.y*u.y; red[t][6]=u.z*u.z; red[t][7]=u.w*u.w;
    __syncthreads();
    for (int s=128;s>0;s>>=1){
        if (t<s){
            #pragma unroll
            for (int c=0;c<8;c++) red[t][c]+=red[t+s][c];
        }
        __syncthreads();
    }
    if (t<8) part[blockIdx.x*8+t] = red[0][t];
}

__global__ void k_inp_final(const float* __restrict__ part,
    const float* __restrict__ opg, const float* __restrict__ opb,
    const float* __restrict__ opW, const float* __restrict__ opB,
    const float* __restrict__ mtg, const float* __restrict__ mtb,
    const float* __restrict__ mtW, const float* __restrict__ mtB,
    float* __restrict__ cwcb){
    int t = threadIdx.x; // 128
    __shared__ float sc[4], oc[4];
    if (t<4){
        float s=0.0f,q=0.0f;
        for (int i=0;i<600;i++){ s+=part[i*8+t]; q+=part[i*8+4+t]; }
        float mean = s/(float)RTOT;
        float var  = q/(float)RTOT - mean*mean;
        float rstd = 1.0f/sqrtf(var+1e-5f);
        float g = (t<2)?opg[t]:mtg[t-2];
        float b = (t<2)?opb[t]:mtb[t-2];
        sc[t]=g*rstd; oc[t]=b-mean*g*rstd;
    }
    __syncthreads();
    float w0=opW[t*2], w1=opW[t*2+1];
    float w2=mtW[t*2], w3=mtW[t*2+1];
    float* o = cwcb + t*5;
    o[0]=sc[0]*w0; o[1]=sc[1]*w1; o[2]=sc[2]*w2; o[3]=sc[3]*w3;
    o[4]=opB[t]+mtB[t] + oc[0]*w0+oc[1]*w1+oc[2]*w2+oc[3]*w3;
}

// ---------------- embed + enc0 stats ----------------
template<typename HT>
__global__ void k_embed(const float* __restrict__ inp, const float* __restrict__ cwcb,
                        HT* __restrict__ h, float* __restrict__ part){
    int bx=blockIdx.x, t=threadIdx.x;
    int row0 = bx*64;
    __shared__ float xin[64][4];
    if (t<64){
        float4 u = *(const float4*)(inp + (size_t)(row0+t)*4);
        xin[t][0]=u.x; xin[t][1]=u.y; xin[t][2]=u.z; xin[t][3]=u.w;
    }
    int e=t&127, rh=t>>7;
    float c0=cwcb[e*5],c1=cwcb[e*5+1],c2=cwcb[e*5+2],c3=cwcb[e*5+3],cb=cwcb[e*5+4];
    __syncthreads();
    float s=0.0f,q=0.0f;
    for (int r=rh; r<64; r+=2){
        float x = cb + xin[r][0]*c0 + xin[r][1]*c1 + xin[r][2]*c2 + xin[r][3]*c3;
        h_store(h + (size_t)(row0+r)*EE + e, x);
        s+=x; q+=x*x;
    }
    __shared__ float rs[256], rq[256];
    rs[t]=s; rq[t]=q;
    __syncthreads();
    if (rh==0){
        part[(size_t)bx*256 + e]       = rs[t]+rs[t+128];
        part[(size_t)bx*256 + 128 + e] = rq[t]+rq[t+128];
    }
}

// ---------------- BN reduce cascade ----------------
__global__ void k_bn_mid(const float* __restrict__ part, int nblk, float* __restrict__ part2){
    int j=blockIdx.x, t=threadIdx.x;   // 60 blocks x 256
    float s=0.0f;
    for (int i=j;i<nblk;i+=60) s += part[(size_t)i*256+t];
    part2[j*256+t]=s;
}

__global__ void k_bn_fin(const float* __restrict__ part2,
                         const float* __restrict__ g, const float* __restrict__ b,
                         float* __restrict__ scale, float* __restrict__ shift){
    int t=threadIdx.x;  // 256
    float s=0.0f;
    for (int j=0;j<60;j++) s += part2[j*256+t];
    __shared__ float red[256];
    red[t]=s; __syncthreads();
    if (t<128){
        float ss=red[t], qq=red[128+t];
        float mean=ss/(float)RTOT, var=qq/(float)RTOT-mean*mean;
        float rstd=1.0f/sqrtf(var+1e-5f);
        float gg=g[t];
        scale[t]=gg*rstd; shift[t]=b[t]-mean*gg*rstd;
    }
}

// ---------------- fused MHA + out-proj + residual + bn1 stats ----------------
#define HS0   0
#define WS0   19800
#define QKV0  26136
#define OH0   33336
#define OWS0  35886
#define BIA0  37998
#define SMTOT 38046
#define PS0   QKV0
#define PQ0   (QKV0+3840)
#define RS0   OWS0
#define RQ0   (OWS0+256)

template<typename HT>
__launch_bounds__(512,1)
__global__ void k_mha(HT* __restrict__ h, const float* __restrict__ in_w,
                      const float* __restrict__ in_b, const float* __restrict__ owT,
                      const float* __restrict__ out_b, int l, float* __restrict__ part,
                      const float* __restrict__ scal, const float* __restrict__ shft){
    __shared__ float sm[SMTOT];
    int b = blockIdx.x, t = threadIdx.x;
    const size_t hbase = (size_t)b*NN*EE;

    for (int j=t; j<NN*32; j+=512){
        int r=j>>5, e4=(j&31)*4;
        float4 x = h_load4(h + hbase + (size_t)r*EE + e4);
        float4 sc4 = *(const float4*)(scal + e4);
        float4 sh4 = *(const float4*)(shft + e4);
        x.x = fmaf(x.x, sc4.x, sh4.x); x.y = fmaf(x.y, sc4.y, sh4.y);
        x.z = fmaf(x.z, sc4.z, sh4.z); x.w = fmaf(x.w, sc4.w, sh4.w);
        *(float4*)&sm[HS0 + r*132 + e4] = x;
    }
    float hacc[5][8];
    #pragma unroll
    for (int i=0;i<5;i++){
        #pragma unroll
        for (int k=0;k<8;k++) hacc[i][k]=0.0f;
    }

    const float* Wl = in_w + (size_t)l*384*EE;
    const float* Bl = in_b + (size_t)l*384;
    const float* OwTl = owT + (size_t)l*EE*EE;
    int nb = t/12, cb = t - nb*12;
    int wv_ = t>>6, lw = t&63;
    int g3 = lw/3, th3 = lw - g3*3;
    int prA = wv_*21 + g3;
    bool actA = (wv_<4) && (lw<63) && (prA<75);
    int nb5 = t>>4, ebx = t&15;

    for (int hd=0; hd<8; hd++){
        __syncthreads();
        for (int j=t; j<48*32; j+=512){
            int row=j>>5, e4=(j&31)*4;
            int which=row>>4, d=row&15;
            int grow = which*EE + hd*16 + d;
            float4 w4 = *(const float4*)(Wl + (size_t)grow*EE + e4);
            *(float4*)&sm[WS0 + row*132 + e4] = w4;
        }
        for (int j=t; j<16*32; j+=512){
            int d=j>>5, e4=(j&31)*4;
            float4 o4 = *(const float4*)(OwTl + (size_t)(hd*16+d)*EE + e4);
            *(float4*)&sm[OWS0 + d*132 + e4] = o4;
        }
        if (t<48){ int which=t>>4, d=t&15; sm[BIA0+t] = Bl[which*EE + hd*16 + d]; }
        __syncthreads();

        if (t<456){
            float acc[4][4];
            #pragma unroll
            for (int i=0;i<4;i++){
                #pragma unroll
                for (int j=0;j<4;j++) acc[i][j]=sm[BIA0+cb*4+j];
            }
            const float* hp0 = &sm[HS0 + nb*4*132];
            const float* wp0 = &sm[WS0 + cb*4*132];
            for (int e4=0;e4<32;e4++){
                float4 h0=*(const float4*)(hp0 + 4*e4);
                float4 h1=*(const float4*)(hp0 + 132 + 4*e4);
                float4 h2=*(const float4*)(hp0 + 264 + 4*e4);
                float4 h3=*(const float4*)(hp0 + 396 + 4*e4);
                float4 w0=*(const float4*)(wp0 + 4*e4);
                float4 w1=*(const float4*)(wp0 + 132 + 4*e4);
                float4 w2=*(const float4*)(wp0 + 264 + 4*e4);
                float4 w3=*(const float4*)(wp0 + 396 + 4*e4);
                acc[0][0]=fmaf(h0.w,w0.w,fmaf(h0.z,w0.z,fmaf(h0.y,w0.y,fmaf(h0.x,w0.x,acc[0][0]))));
                acc[0][1]=fmaf(h0.w,w1.w,fmaf(h0.z,w1.z,fmaf(h0.y,w1.y,fmaf(h0.x,w1.x,acc[0][1]))));
                acc[0][2]=fmaf(h0.w,w2.w,fmaf(h0.z,w2.z,fmaf(h0.y,w2.y,fmaf(h0.x,w2.x,acc[0][2]))));
                acc[0][3]=fmaf(h0.w,w3.w,fmaf(h0.z,w3.z,fmaf(h0.y,w3.y,fmaf(h0.x,w3.x,acc[0][3]))));
                acc[1][0]=fmaf(h1.w,w0.w,fmaf(h1.z,w0.z,fmaf(h1.y,w0.y,fmaf(h1.x,w0.x,acc[1][0]))));
                acc[1][1]=fmaf(h1.w,w1.w,fmaf(h1.z,w1.z,fmaf(h1.y,w1.y,fmaf(h1.x,w1.x,acc[1][1]))));
                acc[1][2]=fmaf(h1.w,w2.w,fmaf(h1.z,w2.z,fmaf(h1.y,w2.y,fmaf(h1.x,w2.x,acc[1][2]))));
                acc[1][3]=fmaf(h1.w,w3.w,fmaf(h1.z,w3.z,fmaf(h1.y,w3.y,fmaf(h1.x,w3.x,acc[1][3]))));
                acc[2][0]=fmaf(h2.w,w0.w,fmaf(h2.z,w0.z,fmaf(h2.y,w0.y,fmaf(h2.x,w0.x,acc[2][0]))));
                acc[2][1]=fmaf(h2.w,w1.w,fmaf(h2.z,w1.z,fmaf(h2.y,w1.y,fmaf(h2.x,w1.x,acc[2][1]))));
                acc[2][2]=fmaf(h2.w,w2.w,fmaf(h2.z,w2.z,fmaf(h2.y,w2.y,fmaf(h2.x,w2.x,acc[2][2]))));
                acc[2][3]=fmaf(h2.w,w3.w,fmaf(h2.z,w3.z,fmaf(h2.y,w3.y,fmaf(h2.x,w3.x,acc[2][3]))));
                acc[3][0]=fmaf(h3.w,w0.w,fmaf(h3.z,w0.z,fmaf(h3.y,w0.y,fmaf(h3.x,w0.x,acc[3][0]))));
                acc[3][1]=fmaf(h3.w,w1.w,fmaf(h3.z,w1.z,fmaf(h3.y,w1.y,fmaf(h3.x,w1.x,acc[3][1]))));
                acc[3][2]=fmaf(h3.w,w2.w,fmaf(h3.z,w2.z,fmaf(h3.y,w2.y,fmaf(h3.x,w2.x,acc[3][2]))));
                acc[3][3]=fmaf(h3.w,w3.w,fmaf(h3.z,w3.z,fmaf(h3.y,w3.y,fmaf(h3.x,w3.x,acc[3][3]))));
            }
            #pragma unroll
            for (int i=0;i<4;i++){
                int n=nb*4+i;
                if (n<150){
                    #pragma unroll
                    for (int j=0;j<4;j++){
                        int c=cb*4+j;
                        sm[QKV0 + (c>>4)*2400 + n*16 + (c&15)] = acc[i][j];
                    }
                }
            }
        }
        __syncthreads();

        {
            float oA[16], oB[16];
            #pragma unroll
            for (int i=0;i<16;i++){ oA[i]=0.0f; oB[i]=0.0f; }
            float lsA=0.0f, lsB=0.0f;
            if (actA){
                int rA0 = prA*2, rA1 = prA*2+1;
                float4 qa0=*(const float4*)&sm[QKV0 + rA0*16 + 0];
                float4 qa1=*(const float4*)&sm[QKV0 + rA0*16 + 4];
                float4 qa2=*(const float4*)&sm[QKV0 + rA0*16 + 8];
                float4 qa3=*(const float4*)&sm[QKV0 + rA0*16 + 12];
                float4 qb0=*(const float4*)&sm[QKV0 + rA1*16 + 0];
                float4 qb1=*(const float4*)&sm[QKV0 + rA1*16 + 4];
                float4 qb2=*(const float4*)&sm[QKV0 + rA1*16 + 8];
                float4 qb3=*(const float4*)&sm[QKV0 + rA1*16 + 12];
                int k0=th3*50;
                for (int kk=k0; kk<k0+50; kk++){
                    const float* kb=&sm[QKV0+2400 + kk*16];
                    float4 ka=*(const float4*)kb;
                    float4 kb4=*(const float4*)(kb+4);
                    float4 kc=*(const float4*)(kb+8);
                    float4 kd=*(const float4*)(kb+12);
                    float sA = qa0.x*ka.x;
                    sA=fmaf(qa0.y,ka.y,sA); sA=fmaf(qa0.z,ka.z,sA); sA=fmaf(qa0.w,ka.w,sA);
                    sA=fmaf(qa1.x,kb4.x,sA); sA=fmaf(qa1.y,kb4.y,sA); sA=fmaf(qa1.z,kb4.z,sA); sA=fmaf(qa1.w,kb4.w,sA);
                    sA=fmaf(qa2.x,kc.x,sA); sA=fmaf(qa2.y,kc.y,sA); sA=fmaf(qa2.z,kc.z,sA); sA=fmaf(qa2.w,kc.w,sA);
                    sA=fmaf(qa3.x,kd.x,sA); sA=fmaf(qa3.y,kd.y,sA); sA=fmaf(qa3.z,kd.z,sA); sA=fmaf(qa3.w,kd.w,sA);
                    float sB = qb0.x*ka.x;
                    sB=fmaf(qb0.y,ka.y,sB); sB=fmaf(qb0.z,ka.z,sB); sB=fmaf(qb0.w,ka.w,sB);
                    sB=fmaf(qb1.x,kb4.x,sB); sB=fmaf(qb1.y,kb4.y,sB); sB=fmaf(qb1.z,kb4.z,sB); sB=fmaf(qb1.w,kb4.w,sB);
                    sB=fmaf(qb2.x,kc.x,sB); sB=fmaf(qb2.y,kc.y,sB); sB=fmaf(qb2.z,kc.z,sB); sB=fmaf(qb2.w,kc.w,sB);
                    sB=fmaf(qb3.x,kd.x,sB); sB=fmaf(qb3.y,kd.y,sB); sB=fmaf(qb3.z,kd.z,sB); sB=fmaf(qb3.w,kd.w,sB);
                    float pA=__expf(sA*0.25f);
                    float pB=__expf(sB*0.25f);
                    lsA+=pA; lsB+=pB;
                    const float* vb=&sm[QKV0+4800 + kk*16];
                    float4 va=*(const float4*)vb;
                    float4 v1=*(const float4*)(vb+4);
                    float4 v2=*(const float4*)(vb+8);
                    float4 v3=*(const float4*)(vb+12);
                    oA[0]=fmaf(pA,va.x,oA[0]); oA[1]=fmaf(pA,va.y,oA[1]); oA[2]=fmaf(pA,va.z,oA[2]); oA[3]=fmaf(pA,va.w,oA[3]);
                    oA[4]=fmaf(pA,v1.x,oA[4]); oA[5]=fmaf(pA,v1.y,oA[5]); oA[6]=fmaf(pA,v1.z,oA[6]); oA[7]=fmaf(pA,v1.w,oA[7]);
                    oA[8]=fmaf(pA,v2.x,oA[8]); oA[9]=fmaf(pA,v2.y,oA[9]); oA[10]=fmaf(pA,v2.z,oA[10]); oA[11]=fmaf(pA,v2.w,oA[11]);
                    oA[12]=fmaf(pA,v3.x,oA[12]); oA[13]=fmaf(pA,v3.y,oA[13]); oA[14]=fmaf(pA,v3.z,oA[14]); oA[15]=fmaf(pA,v3.w,oA[15]);
                    oB[0]=fmaf(pB,va.x,oB[0]); oB[1]=fmaf(pB,va.y,oB[1]); oB[2]=fmaf(pB,va.z,oB[2]); oB[3]=fmaf(pB,va.w,oB[3]);
                    oB[4]=fmaf(pB,v1.x,oB[4]); oB[5]=fmaf(pB,v1.y,oB[5]); oB[6]=fmaf(pB,v1.z,oB[6]); oB[7]=fmaf(pB,v1.w,oB[7]);
                    oB[8]=fmaf(pB,v2.x,oB[8]); oB[9]=fmaf(pB,v2.y,oB[9]); oB[10]=fmaf(pB,v2.z,oB[10]); oB[11]=fmaf(pB,v2.w,oB[11]);
                    oB[12]=fmaf(pB,v3.x,oB[12]); oB[13]=fmaf(pB,v3.y,oB[13]); oB[14]=fmaf(pB,v3.z,oB[14]); oB[15]=fmaf(pB,v3.w,oB[15]);
                }
            }
            float lsA1=__shfl_down(lsA,1), lsA2=__shfl_down(lsA,2);
            float lsB1=__shfl_down(lsB,1), lsB2=__shfl_down(lsB,2);
            float ocA[16], ocB[16];
            #pragma unroll
            for (int i=0;i<16;i++){
                float a1=__shfl_down(oA[i],1), a2=__shfl_down(oA[i],2);
                ocA[i]=(oA[i]+a1)+a2;
                float b1=__shfl_down(oB[i],1), b2=__shfl_down(oB[i],2);
                ocB[i]=(oB[i]+b1)+b2;
            }
            if (actA && th3==0){
                int rA0 = prA*2, rA1 = prA*2+1;
                float invA = 1.0f/((lsA+lsA1)+lsA2);
                float invB = 1.0f/((lsB+lsB1)+lsB2);
                #pragma unroll
                for (int d=0;d<16;d++){
                    sm[OH0 + rA0*17 + d] = ocA[d]*invA;
                    sm[OH0 + rA1*17 + d] = ocB[d]*invB;
                }
            }
        }
        __syncthreads();

        if (t<480){
            #pragma unroll
            for (int d=0; d<16; d++){
                float4 w0=*(const float4*)&sm[OWS0 + d*132 + ebx*8];
                float4 w1=*(const float4*)&sm[OWS0 + d*132 + ebx*8 + 4];
                #pragma unroll
                for (int i=0;i<5;i++){
                    float ov = sm[OH0 + (nb5*5+i)*17 + d];
                    hacc[i][0]=fmaf(ov,w0.x,hacc[i][0]);
                    hacc[i][1]=fmaf(ov,w0.y,hacc[i][1]);
                    hacc[i][2]=fmaf(ov,w0.z,hacc[i][2]);
                    hacc[i][3]=fmaf(ov,w0.w,hacc[i][3]);
                    hacc[i][4]=fmaf(ov,w1.x,hacc[i][4]);
                    hacc[i][5]=fmaf(ov,w1.y,hacc[i][5]);
                    hacc[i][6]=fmaf(ov,w1.z,hacc[i][6]);
                    hacc[i][7]=fmaf(ov,w1.w,hacc[i][7]);
                }
            }
        }
    }
    __syncthreads();
    if (t<480){
        float ob[8];
        *(float4*)&ob[0] = *(const float4*)(out_b + l*EE + ebx*8);
        *(float4*)&ob[4] = *(const float4*)(out_b + l*EE + ebx*8 + 4);
        float cs[8], cq[8];
        #pragma unroll
        for (int k=0;k<8;k++){ cs[k]=0.0f; cq[k]=0.0f; }
        #pragma unroll
        for (int i=0;i<5;i++){
            int r=nb5*5+i;
            float x[8];
            #pragma unroll
            for (int k2=0;k2<4;k2++){
                float2 hv=*(const float2*)&sm[HS0 + r*132 + ebx*8 + 2*k2];
                x[2*k2]   = hv.x + ob[2*k2]   + hacc[i][2*k2];
                x[2*k2+1] = hv.y + ob[2*k2+1] + hacc[i][2*k2+1];
            }
            h_store4(h + hbase + (size_t)r*EE + ebx*8,     make_float4(x[0],x[1],x[2],x[3]));
            h_store4(h + hbase + (size_t)r*EE + ebx*8 + 4, make_float4(x[4],x[5],x[6],x[7]));
            #pragma unroll
            for (int k=0;k<8;k++){ cs[k]+=x[k]; cq[k]+=x[k]*x[k]; }
        }
        #pragma unroll
        for (int k=0;k<8;k++){
            sm[PS0 + nb5*128 + ebx*8 + k]=cs[k];
            sm[PQ0 + nb5*128 + ebx*8 + k]=cq[k];
        }
    }
    __syncthreads();
    if (t<256){
        int e=t&127, hf=t>>7;
        float s=0.0f,q=0.0f;
        for (int nb_=hf*15; nb_<hf*15+15; nb_++){
            s+=sm[PS0+nb_*128+e]; q+=sm[PQ0+nb_*128+e];
        }
        sm[RS0+t]=s; sm[RQ0+t]=q;
    }
    __syncthreads();
    if (t<128){
        part[(size_t)b*256 + t]       = sm[RS0+t]+sm[RS0+128+t];
        part[(size_t)b*256 + 128 + t] = sm[RQ0+t]+sm[RQ0+128+t];
    }
}

// ---------------- fused FFN (legacy, fallback paths) ----------------
template<typename HT>
__global__ void k_ff(HT* __restrict__ h,
                     const float* __restrict__ w1, const float* __restrict__ b1,
                     const float* __restrict__ w2, const float* __restrict__ b2,
                     int l, float* __restrict__ part,
                     const float* __restrict__ scal, const float* __restrict__ shft){
    int bx=blockIdx.x, t=threadIdx.x;
    int row0=bx*16;
    __shared__ __align__(16) float xn[16][EE];
    __shared__ __align__(16) float f1[16][FFD];
    __shared__ float w2T[64][EE+1];
    const float* W1 = w1 + (size_t)l*FFD*EE;
    const float* W2 = w2 + (size_t)l*EE*FFD;
    for (int j=t;j<16*EE;j+=256){
        int r=j>>7,e=j&127;
        xn[r][e]=fmaf(h_load(h + (size_t)(row0+r)*EE+e), scal[e], shft[e]);
    }
    __syncthreads();
    for (int fi=0;fi<2;fi++){
        int f=t+fi*256;
        const float4* wr = (const float4*)(W1 + (size_t)f*EE);
        float bias = b1[l*FFD+f];
        float acc[16];
        #pragma unroll
        for (int r=0;r<16;r++) acc[r]=bias;
        for (int e4=0;e4<32;e4++){
            float4 w=wr[e4];
            #pragma unroll
            for (int r=0;r<16;r++){
                float4 x=*(const float4*)&xn[r][4*e4];
                acc[r] += x.x*w.x + x.y*w.y + x.z*w.z + x.w*w.w;
            }
        }
        #pragma unroll
        for (int r=0;r<16;r++) f1[r][f]=fmaxf(acc[r],0.0f);
    }
    int e=t&127, rh=t>>7;
    float acc2[8];
    #pragma unroll
    for (int i=0;i<8;i++) acc2[i]=0.0f;
    for (int fc=0; fc<FFD; fc+=64){
        __syncthreads();
        for (int j=t;j<64*EE;j+=256){ int e_=j>>6, fl=j&63; w2T[fl][e_]=W2[(size_t)e_*FFD+fc+fl]; }
        __syncthreads();
        for (int fl=0;fl<64;fl++){
            float w=w2T[fl][e];
            #pragma unroll
            for (int i=0;i<8;i++) acc2[i] = fmaf(f1[rh*8+i][fc+fl], w, acc2[i]);
        }
    }
    float bias = b2[l*EE+e];
    float s=0.0f,q=0.0f;
    #pragma unroll
    for (int i=0;i<8;i++){
        float x = xn[rh*8+i][e] + bias + acc2[i];
        h_store(h + (size_t)(row0+rh*8+i)*EE+e, x);
        s+=x; q+=x*x;
    }
    __shared__ float rs[256], rq[256];
    rs[t]=s; rq[t]=q; __syncthreads();
    if (rh==0){
        part[(size_t)bx*256+e]=rs[t]+rs[t+128];
        part[(size_t)bx*256+128+e]=rq[t]+rq[t+128];
    }
}

// ---------------- fused FFN v2 ----------------
template<typename HT>
__launch_bounds__(256,4)
__global__ void k_ff2(HT* __restrict__ h,
                      const float* __restrict__ w1T, const float* __restrict__ b1,
                      const float* __restrict__ w2Tg, const float* __restrict__ b2,
                      int l, float* __restrict__ part,
                      const float* __restrict__ scal, const float* __restrict__ shft){
    int bx=blockIdx.x, t=threadIdx.x;
    int row0=bx*16;
    __shared__ __align__(16) float xn[16][EE];
    __shared__ __align__(16) float f1[16][FFD];
    const float* W1T = w1T + (size_t)l*65536;
    const float* W2T = w2Tg + (size_t)l*65536;
    for (int j=t;j<16*EE;j+=256){
        int r=j>>7,e=j&127;
        xn[r][e]=fmaf(h_load(h + (size_t)(row0+r)*EE+e), scal[e], shft[e]);
    }
    __syncthreads();
    #pragma unroll
    for (int fi=0;fi<2;fi++){
        int f=t+fi*256;
        float bias = b1[l*FFD+f];
        float acc[16];
        #pragma unroll
        for (int r=0;r<16;r++) acc[r]=bias;
        #pragma unroll 4
        for (int e=0;e<EE;e++){
            float w = W1T[(size_t)e*FFD + f];
            #pragma unroll
            for (int r=0;r<16;r++) acc[r]=fmaf(xn[r][e], w, acc[r]);
        }
        #pragma unroll
        for (int r=0;r<16;r++) f1[r][f]=fmaxf(acc[r],0.0f);
    }
    __syncthreads();
    int e=t&127, rh=t>>7;
    float acc2[8];
    #pragma unroll
    for (int i=0;i<8;i++) acc2[i]=0.0f;
    #pragma unroll 4
    for (int fl=0; fl<FFD; fl++){
        float w = W2T[(size_t)fl*EE + e];
        #pragma unroll
        for (int i=0;i<8;i++) acc2[i] = fmaf(f1[rh*8+i][fl], w, acc2[i]);
    }
    float bias = b2[l*EE+e];
    float s=0.0f,q=0.0f;
    #pragma unroll
    for (int i=0;i<8;i++){
        float x = xn[rh*8+i][e] + bias + acc2[i];
        h_store(h + (size_t)(row0+rh*8+i)*EE+e, x);
        s+=x; q+=x*x;
    }
    __shared__ float rs[256], rq[256];
    rs[t]=s; rq[t]=q; __syncthreads();
    if (rh==0){
        part[(size_t)bx*256+e]=rs[t]+rs[t+128];
        part[(size_t)bx*256+128+e]=rq[t]+rq[t+128];
    }
}

// ---------------- G_ih precompute ----------------
template<typename HT>
__launch_bounds__(512)
__global__ void k_gih(const HT* __restrict__ h, const float* __restrict__ wihT,
                      const float* __restrict__ scal, const float* __restrict__ shft,
                      float* __restrict__ G, int b0){
    __shared__ float xn[NN][132];
    int bl = blockIdx.x, t = threadIdx.x;
    const size_t hbase = (size_t)(b0+bl)*NN*EE;
    for (int j=t; j<NN*32; j+=512){
        int r=j>>5, e4=(j&31)*4;
        float4 x = h_load4(h + hbase + (size_t)r*EE + e4);
        float4 sc4=*(const float4*)(scal+e4), sh4=*(const float4*)(shft+e4);
        x.x=fmaf(x.x,sc4.x,sh4.x); x.y=fmaf(x.y,sc4.y,sh4.y);
        x.z=fmaf(x.z,sc4.z,sh4.z); x.w=fmaf(x.w,sc4.w,sh4.w);
        *(float4*)&xn[r][e4]=x;
    }
    __syncthreads();
    float* Gb = G + (size_t)bl*NN*512;
    const float* wcol = wihT + t;
    for (int nb=0; nb<10; nb++){
        float acc[15];
        #pragma unroll
        for (int j=0;j<15;j++) acc[j]=0.0f;
        #pragma unroll 4
        for (int e=0;e<128;e++){
            float w = wcol[(size_t)e*512];
            #pragma unroll
            for (int j=0;j<15;j++) acc[j]=fmaf(xn[nb*15+j][e], w, acc[j]);
        }
        #pragma unroll
        for (int j=0;j<15;j++) Gb[(size_t)(nb*15+j)*512+t]=acc[j];
    }
}

// ---------------- shared decoder LDS layout (fallback decoder2) ----------------
#define EWQ    19200
#define DGTS   38400
#define D_DD   39424
#define D_HH   39680
#define D_HW2  39936
#define D_PVS  40192
#define D_SCS  40320
#define D_SHS  40448
#define D_TOT  40576

// ---------------- decoder v2i (fallback, ws mid) ----------------
template<typename HT>
__launch_bounds__(1024,4)
__global__ void k_decoder2(const HT* __restrict__ enc, const float* __restrict__ inp,
        const float* __restrict__ wih_p, const float* __restrict__ whh_p,
        const float* __restrict__ bih, const float* __restrict__ bhh,
        const float* __restrict__ pw1T, const float* __restrict__ pb1,
        const float* __restrict__ pw2T, const float* __restrict__ pb2,
        const float* __restrict__ pv, const float* __restrict__ pbv,
        const float* __restrict__ scal, const float* __restrict__ shft,
        float* __restrict__ out){
    __shared__ float smf[D_TOT];
    __shared__ unsigned char schna[608];
    const int t = threadIdx.x;
    const int q = t>>9, r = t&511;
    const int b0 = blockIdx.x*2;
    const HT* encq = enc + (size_t)(b0+q)*NN*EE;

    if (t<128){ smf[D_PVS+t]=pv[t]; smf[D_SCS+t]=scal[t]; smf[D_SHS+t]=shft[t]; }
    if (t<512) smf[D_DD+t]=0.0f;
    if (t<304){
        int qq=t/152, n=t-qq*152;
        schna[qq*304+n]=0;
        unsigned char nav=1;
        if (n<150) nav = (inp[((size_t)(b0+qq)*NN+n)*4+1] != 0.0f) ? 1 : 0;
        schna[qq*304+152+n]=nav;
    }
    const int g = t>>1, kh = t&1;
    const float bsum = bih[g] + bhh[g];
    const float pb2r = (t<256) ? pb2[t&127] : 0.0f;
    const float pbvr = pbv[0];

    float4 whr[16];
    {
        const float4* wp = (const float4*)whh_p + t;
        #pragma unroll
        for (int i=0;i<16;i++) whr[i] = wp[(size_t)i*1024];
    }
    __syncthreads();

    {
        const int e = r&127, ng = r>>7;
        const float pb1e = pb1[e];
        for (int n1 = ng; n1 < 150; n1 += 8){
            int n2 = n1+4;
            bool has2 = (n2<150);
            int n2c = has2 ? n2 : n1;
            float a1=0.0f, a2=0.0f;
            #pragma unroll 4
            for (int e2=0;e2<EE;e2++){
                float w = pw1T[e2*EE + e];
                float x1 = fmaf(smf[D_SCS+e2], h_load(encq + (size_t)n1*EE + e2), smf[D_SHS+e2]);
                float x2 = fmaf(smf[D_SCS+e2], h_load(encq + (size_t)n2c*EE + e2), smf[D_SHS+e2]);
                a1 = fmaf(x1, w, a1);
                a2 = fmaf(x2, w, a2);
            }
            smf[q*EWQ + n1*128 + (e ^ (n1&31))] = a1 + pb1e;
            if (has2) smf[q*EWQ + n2*128 + (e ^ (n2&31))] = a2 + pb1e;
        }
    }
    if (t<512){
        int qq=t>>8, rr=t&255, e=rr&127, hf=rr>>7;
        const HT* eb = enc + (size_t)(b0+qq)*NN*EE;
        float s=0.0f;
        for (int n=hf*75;n<hf*75+75;n++) s += h_load(eb + (size_t)n*EE+e);
        smf[DGTS + qq*256 + hf*128 + e] = s;
    }
    __syncthreads();
    float c_reg = 0.0f;
    if (t<256){
        int qq=t>>7, e=t&127;
        float mean = (smf[DGTS+qq*256+e]+smf[DGTS+qq*256+128+e])*(1.0f/150.0f);
        c_reg = fmaf(smf[D_SCS+e], mean, smf[D_SHS+e]);
    }
    __syncthreads();

    float llacc=0.0f;
    const float4* wip = (const float4*)wih_p + t;
    for (int step=0; step<NN; step++){
        {
            float a0=0.0f, a1=0.0f;
            const float* d0 = &smf[D_DD + kh*64];
            const float* d1 = &smf[D_DD + 128 + kh*64];
            const float* h0 = &smf[D_HH + kh*64];
            const float* h1 = &smf[D_HH + 128 + kh*64];
            #pragma unroll 8
            for (int i=0;i<16;i++){
                float4 wv = wip[(size_t)i*1024];
                float4 wh = whr[i];
                float4 x0 = *(const float4*)(d0 + 4*i);
                float4 x1 = *(const float4*)(d1 + 4*i);
                float4 y0 = *(const float4*)(h0 + 4*i);
                float4 y1 = *(const float4*)(h1 + 4*i);
                a0 = fmaf(wv.w,x0.w,fmaf(wv.z,x0.z,fmaf(wv.y,x0.y,fmaf(wv.x,x0.x,a0))));
                a0 = fmaf(wh.w,y0.w,fmaf(wh.z,y0.z,fmaf(wh.y,y0.y,fmaf(wh.x,y0.x,a0))));
                a1 = fmaf(wv.w,x1.w,fmaf(wv.z,x1.z,fmaf(wv.y,x1.y,fmaf(wv.x,x1.x,a1))));
                a1 = fmaf(wh.w,y1.w,fmaf(wh.z,y1.z,fmaf(wh.y,y1.y,fmaf(wh.x,y1.x,a1))));
            }
            a0 += __shfl_xor(a0,1);
            a1 += __shfl_xor(a1,1);
            if (kh==0){
                smf[DGTS + g]       = a0 + bsum;
                smf[DGTS + 512 + g] = a1 + bsum;
            }
        }
        __syncthreads();
        if (t<256){
            int qq=t>>7, e=t&127;
            const float* gt = &smf[DGTS + qq*512];
            float gi=fsig(gt[e]), gf=fsig(gt[128+e]), gg=ftanh(gt[256+e]), go=fsig(gt[384+e]);
            c_reg = gf*c_reg + gi*gg;
            smf[D_HH + qq*128 + e] = go*ftanh(c_reg);
        }
        __syncthreads();
        if (t<256){
            int qq=t>>7, e=t&127;
            float s2=0.0f;
            #pragma unroll 4
            for (int e2=0;e2<EE;e2++)
                s2 = fmaf(pw2T[e2*EE + e], smf[D_HH + qq*128 + e2], s2);
            smf[D_HW2 + qq*128 + e] = s2 + pb2r;
        }
        __syncthreads();
        {
            int half = r>>8, n = r&255;
            if (n<150){
                float p=0.0f;
                const float* ewn = &smf[q*EWQ + n*128];
                const float* hwq = &smf[D_HW2 + q*128];
                int sw = n&31;
                #pragma unroll 8
                for (int e2=0;e2<64;e2++){
                    int e = half*64+e2;
                    p = fmaf(ftanh(ewn[e ^ sw] + hwq[e]), smf[D_PVS+e], p);
                }
                smf[DGTS + (q*2+half)*152 + n] = p;
            }
        }
        __syncthreads();
        if (t<128){
            int qq=t>>6, l=t&63;
            const unsigned char* sc_ = &schna[qq*304];
            const float* pp = &smf[DGTS + qq*2*152];
            int n0=l, n1=l+64, n2=l+128;
            float a0 = pp[n0]+pp[152+n0]+pbvr;
            float a1 = pp[n1]+pp[152+n1]+pbvr;
            float v0 = (sc_[n0]|sc_[152+n0]) ? -10000.0f : a0;
            float v1 = (sc_[n1]|sc_[152+n1]) ? -10000.0f : a1;
            float v2 = -1e30f;
            if (n2<NN){
                float a2 = pp[n2]+pp[152+n2]+pbvr;
                v2 = (sc_[n2]|sc_[152+n2]) ? -10000.0f : a2;
            }
            float m=v0; int mi=n0;
            if (v1>m){ m=v1; mi=n1; }
            if (n2<NN && v2>m){ m=v2; mi=n2; }
            #pragma unroll
            for (int off=1; off<64; off<<=1){
                float om=__shfl_xor(m,off); int oi=__shfl_xor(mi,off);
                if (om>m || (om==m && oi<mi)){ m=om; mi=oi; }
            }
            float se = __expf(v0-m)+__expf(v1-m) + ((n2<NN)? __expf(v2-m):0.0f);
            #pragma unroll
            for (int off=1; off<64; off<<=1) se += __shfl_xor(se,off);
            const HT* eb = enc + (size_t)(b0+qq)*NN*EE;
            if (l==0){
                llacc -= logf(se);
                schna[qq*304+mi]=1;
                int nn2 = mi+1; if (nn2>NN-1) nn2=NN-1;
                schna[qq*304+152+nn2]=0;
                float4 rowv = *(const float4*)(inp + ((size_t)(b0+qq)*NN+mi)*4);
                *(float4*)(out + ((size_t)(b0+qq)*NN+step)*4) = rowv;
            }
            float eva = h_load(eb + (size_t)mi*EE + l);
            float evb = h_load(eb + (size_t)mi*EE + l + 64);
            smf[D_DD + qq*128 + l]      = fmaf(smf[D_SCS+l],    eva, smf[D_SHS+l]);
            smf[D_DD + qq*128 + l + 64] = fmaf(smf[D_SCS+l+64], evb, smf[D_SHS+l+64]);
        }
        __syncthreads();
    }
    if (t==0)  out[(size_t)BB*NN*4 + b0]   = llacc;
    if (t==64) out[(size_t)BB*NN*4 + b0+1] = llacc;
}

// ---------------- decoder G6: 1 batch/block, 512 threads, <=80KB LDS, 2 blocks/CU ----------------
#define E6_EW   0
#define E6_GTS  19200
#define E6_HH   19712
#define E6_HW2  19840
#define E6_PVS  19968
#define E6_SCS  20096
#define E6_SHS  20224
#define E6_TOT  20352

template<typename HT>
__launch_bounds__(512,4)
__global__ void k_decoderG6(const HT* __restrict__ enc, const float* __restrict__ inp,
        const float* __restrict__ whh_f, const float* __restrict__ Gih,
        const float* __restrict__ bih, const float* __restrict__ bhh,
        const float* __restrict__ pw1T, const float* __restrict__ pb1,
        const float* __restrict__ pw2T, const float* __restrict__ pb2,
        const float* __restrict__ pv, const float* __restrict__ pbv,
        const float* __restrict__ scal, const float* __restrict__ shft,
        float* __restrict__ out, int passb0){
    __shared__ float smf[E6_TOT];
    __shared__ unsigned char schna[304];
    __shared__ int predS;
    const int t = threadIdx.x;
    const int b = passb0 + blockIdx.x;
    const HT* encb = enc + (size_t)b*NN*EE;

    if (t<128){ smf[E6_PVS+t]=pv[t]; smf[E6_SCS+t]=scal[t]; smf[E6_SHS+t]=shft[t]; smf[E6_HH+t]=0.0f; }
    if (t<152) schna[t]=0;
    else if (t<304){
        int n=t-152;
        unsigned char nav=1;
        if (n<150) nav = (inp[((size_t)b*NN+n)*4+1] != 0.0f) ? 1 : 0;
        schna[t]=nav;
    }
    if (t==0) predS=-1;
    const float bsum = bih[t] + bhh[t];
    const float pb2r = (t<128) ? pb2[t] : 0.0f;
    const float pbvr = pbv[0];
    __syncthreads();

    // ew = bn(enc) @ pw1^T + pb1 (XOR-swizzled)
    {
        const int e = t&127, rg = t>>7;   // 4 row-groups
        const float pb1e = pb1[e];
        for (int n=rg; n<150; n+=4){
            const HT* er = encb + (size_t)n*EE;
            float a=0.0f;
            #pragma unroll 4
            for (int e2=0;e2<EE;e2++){
                float x = fmaf(smf[E6_SCS+e2], h_load(er+e2), smf[E6_SHS+e2]);
                a = fmaf(x, pw1T[e2*EE + e], a);
            }
            smf[E6_EW + n*128 + (e ^ (n&31))] = a + pb1e;
        }
    }
    // c0 partials
    if (t<256){
        int e=t&127, hf=t>>7;
        float s=0.0f;
        for (int n=hf*75;n<hf*75+75;n++) s += h_load(encb + (size_t)n*EE+e);
        smf[E6_GTS + hf*128 + e] = s;
    }
    __syncthreads();
    float c_reg = 0.0f;
    if (t<128){
        float mean = (smf[E6_GTS+t]+smf[E6_GTS+128+t])*(1.0f/150.0f);
        c_reg = fmaf(smf[E6_SCS+t], mean, smf[E6_SHS+t]);
    }
    __syncthreads();

    float llacc=0.0f;
    const float* Gb = Gih + (size_t)blockIdx.x*NN*512;
    const float4* wfp = (const float4*)whh_f + t;
    for (int step=0; step<NN; step++){
        // A. gate t: G-lookup + full-row Whh x hh (coalesced whh_f)
        {
            int p = predS;
            float a = bsum + ((p>=0) ? Gb[(size_t)p*512 + t] : 0.0f);
            const float4* hh4 = (const float4*)&smf[E6_HH];
            #pragma unroll 8
            for (int i=0;i<32;i++){
                float4 w = wfp[(size_t)i*512];
                float4 y = hh4[i];
                a = fmaf(w.w,y.w,fmaf(w.z,y.z,fmaf(w.y,y.y,fmaf(w.x,y.x,a))));
            }
            smf[E6_GTS + t] = a;
        }
        __syncthreads();
        // B. LSTM cell (t<128)
        if (t<128){
            const float* gt = &smf[E6_GTS];
            float gi=fsig(gt[t]), gf=fsig(gt[128+t]), gg=ftanh(gt[256+t]), go=fsig(gt[384+t]);
            c_reg = gf*c_reg + gi*gg;
            smf[E6_HH + t] = go*ftanh(c_reg);
        }
        __syncthreads();
        // C. hw2 = hh @ pw2^T + pb2 (t<128, full-K, coalesced pw2T)
        if (t<128){
            float s2=0.0f;
            #pragma unroll 4
            for (int e2=0;e2<EE;e2++)
                s2 = fmaf(pw2T[e2*EE + t], smf[E6_HH + e2], s2);
            smf[E6_HW2 + t] = s2 + pb2r;
        }
        __syncthreads();
        // D. pointer logits: (half, n)
        {
            int half = t>>8, n = t&255;
            if (n<150){
                float p=0.0f;
                const float* ewn = &smf[E6_EW + n*128];
                int sw = n&31;
                #pragma unroll 8
                for (int e2=0;e2<64;e2++){
                    int e = half*64+e2;
                    p = fmaf(ftanh(ewn[e ^ sw] + smf[E6_HW2+e]), smf[E6_PVS+e], p);
                }
                smf[E6_GTS + half*152 + n] = p;
            }
        }
        __syncthreads();
        // E. argmax + lse + state update (wave 0)
        if (t<64){
            const float* pp = &smf[E6_GTS];
            int n0=t, n1=t+64, n2=t+128;
            float a0 = pp[n0]+pp[152+n0]+pbvr;
            float a1 = pp[n1]+pp[152+n1]+pbvr;
            float v0 = (schna[n0]|schna[152+n0]) ? -10000.0f : a0;
            float v1 = (schna[n1]|schna[152+n1]) ? -10000.0f : a1;
            float v2 = -1e30f;
            if (n2<NN){
                float a2 = pp[n2]+pp[152+n2]+pbvr;
                v2 = (schna[n2]|schna[152+n2]) ? -10000.0f : a2;
            }
            float m=v0; int mi=n0;
            if (v1>m){ m=v1; mi=n1; }
            if (n2<NN && v2>m){ m=v2; mi=n2; }
            #pragma unroll
            for (int off=1; off<64; off<<=1){
                float om=__shfl_xor(m,off); int oi=__shfl_xor(mi,off);
                if (om>m || (om==m && oi<mi)){ m=om; mi=oi; }
            }
            float se = __expf(v0-m)+__expf(v1-m) + ((n2<NN)? __expf(v2-m):0.0f);
            #pragma unroll
            for (int off=1; off<64; off<<=1) se += __shfl_xor(se,off);
            if (t==0){
                llacc -= logf(se);
                predS = mi;
                schna[mi]=1;
                int nn2 = mi+1; if (nn2>NN-1) nn2=NN-1;
                schna[152+nn2]=0;
                float4 rowv = *(const float4*)(inp + ((size_t)b*NN+mi)*4);
                *(float4*)(out + ((size_t)b*NN+step)*4) = rowv;
            }
        }
        __syncthreads();
    }
    if (t==0) out[(size_t)BB*NN*4 + b] = llacc;
}

// ---------------- host schedule ----------------
template<typename HT>
static void run_model(void* const* d_in, void* d_out, void* d_ws, bool big, hipStream_t stream){
    const float* inp   = (const float*)d_in[0];
    const float* opg   = (const float*)d_in[1];
    const float* opb   = (const float*)d_in[2];
    const float* opW   = (const float*)d_in[3];
    const float* opB   = (const float*)d_in[4];
    const float* mtg   = (const float*)d_in[5];
    const float* mtb   = (const float*)d_in[6];
    const float* mtW   = (const float*)d_in[7];
    const float* mtB   = (const float*)d_in[8];
    const float* e0g   = (const float*)d_in[9];
    const float* e0b   = (const float*)d_in[10];
    const float* in_w  = (const float*)d_in[11];
    const float* in_b  = (const float*)d_in[12];
    const float* out_w = (const float*)d_in[13];
    const float* out_b = (const float*)d_in[14];
    const float* bn1g  = (const float*)d_in[15];
    const float* bn1b  = (const float*)d_in[16];
    const float* ffw1  = (const float*)d_in[17];
    const float* ffb1  = (const float*)d_in[18];
    const float* ffw2  = (const float*)d_in[19];
    const float* ffb2  = (const float*)d_in[20];
    const float* bn2g  = (const float*)d_in[21];
    const float* bn2b  = (const float*)d_in[22];
    const float* Wih   = (const float*)d_in[23];
    const float* Whh   = (const float*)d_in[24];
    const float* bihp  = (const float*)d_in[25];
    const float* bhhp  = (const float*)d_in[26];
    const float* pw1   = (const float*)d_in[27];
    const float* pb1   = (const float*)d_in[28];
    const float* pw2   = (const float*)d_in[29];
    const float* pb2   = (const float*)d_in[30];
    const float* pv    = (const float*)d_in[31];
    const float* pbv   = (const float*)d_in[32];
    float* out = (float*)d_out;

    HT* h = (HT*)d_ws;
    float* Xf = (float*)((char*)d_ws + (size_t)RTOT*EE*sizeof(HT));
    float* part  = Xf;                    // 2457600
    float* cwcb  = Xf + 2457600;          // 640
    float* scal  = cwcb + 640;
    float* shft  = scal + 128;
    float* wih_p = shft + 128;            // 65536
    float* whh_p = wih_p + 65536;         // 65536
    float* pw1T  = whh_p + 65536;         // 16384
    float* pw2Tg = pw1T + 16384;          // 16384
    float* owT   = pw2Tg + 16384;         // 49152
    float* part2 = owT + 49152;           // 15360
    float* wihT  = part2 + 15360;         // 65536 (big only)
    float* whh_f = wihT + 65536;          // 65536 (big only)
    float* G     = whh_f + 65536;         // 39,321,600 (big only)
    float* w1T   = G;                     // 196608 (dead until k_gih)
    float* w2Tg  = G + 196608;            // 196608

    k_prep2<<<256,256,0,stream>>>(Wih, Whh, pw1, pw2, out_w, wih_p, whh_p, pw1T, pw2Tg, owT);
    if (big){
        k_prep3<<<256,256,0,stream>>>(Wih, Whh, wihT, whh_f);
        k_prep4<<<768,256,0,stream>>>(ffw1, ffw2, w1T, w2Tg);
    }
    k_inp_stats<<<600,256,0,stream>>>(inp, part);
    k_inp_final<<<1,128,0,stream>>>(part, opg,opb,opW,opB, mtg,mtb,mtW,mtB, cwcb);
    k_embed<HT><<<2400,256,0,stream>>>(inp, cwcb, h, part);
    k_bn_mid<<<60,256,0,stream>>>(part, 2400, part2);
    k_bn_fin<<<1,256,0,stream>>>(part2, e0g, e0b, scal, shft);
    for (int l=0;l<NL;l++){
        k_mha<HT><<<1024,512,0,stream>>>(h, in_w, in_b, owT, out_b, l, part, scal, shft);
        k_bn_mid<<<60,256,0,stream>>>(part, 1024, part2);
        k_bn_fin<<<1,256,0,stream>>>(part2, bn1g + l*EE, bn1b + l*EE, scal, shft);
        if (big){
            k_ff2<HT><<<9600,256,0,stream>>>(h, w1T, ffb1, w2Tg, ffb2, l, part, scal, shft);
        } else {
            k_ff<HT><<<9600,256,0,stream>>>(h, ffw1, ffb1, ffw2, ffb2, l, part, scal, shft);
        }
        k_bn_mid<<<60,256,0,stream>>>(part, 9600, part2);
        k_bn_fin<<<1,256,0,stream>>>(part2, bn2g + l*EE, bn2b + l*EE, scal, shft);
    }
    if (big){
        for (int pass=0; pass<2; pass++){
            k_gih<HT><<<512,512,0,stream>>>(h, wihT, scal, shft, G, pass*512);
            k_decoderG6<HT><<<512,512,0,stream>>>(h, inp, whh_f, G, bihp, bhhp,
                                                  pw1T, pb1, pw2Tg, pb2, pv, pbv,
                                                  scal, shft, out, pass*512);
        }
    } else {
        k_decoder2<HT><<<512,1024,0,stream>>>(h, inp, wih_p, whh_p, bihp, bhhp,
                                              pw1T, pb1, pw2Tg, pb2, pv, pbv,
                                              scal, shft, out);
    }
}

extern "C" void kernel_launch(void* const* d_in, const int* in_sizes, int n_in,
                              void* d_out, int out_size, void* d_ws, size_t ws_size,
                              hipStream_t stream){
    const size_t xf_floats = 2457600u + 640 + 128 + 128 + 65536 + 65536 + 16384 + 16384 + 49152 + 15360;
    const size_t need_A   = (size_t)RTOT*EE*4 + xf_floats*4ull;
    const size_t need_big = need_A + (size_t)(65536 + 65536 + 39321600)*4ull;
    if (ws_size >= need_big){
        run_model<float>(d_in, d_out, d_ws, true, stream);
    } else if (ws_size >= need_A){
        run_model<float>(d_in, d_out, d_ws, false, stream);
    } else {
        run_model<f16>(d_in, d_out, d_ws, false, stream);
    }
    (void)in_sizes; (void)n_in; (void)out_size; (void)ws_size;
}